// Round 1
// baseline (607.469 us; speedup 1.0000x reference)
//
#include <hip/hip_runtime.h>
#include <hip/hip_bf16.h>

// Sizes (fixed by the problem)
#define BATCH 16
#define D0 1024
#define D1 1024
#define D2 1024
#define D3 512
#define KSL 8          // K slices per weight
#define MAXP 64        // paths kept
#define NPATH 512      // paths before prune (8*8*8)

__device__ __forceinline__ float fast_tanh(float x) {
  // stable: 1 - 2/(e^{2x}+1);  +inf -> 1, -inf -> -1
  float e = __expf(2.f * x);
  return 1.f - 2.f / (e + 1.f);
}

// ---------------------------------------------------------------------------
// x (16,1024) row-major  ->  XT (1024,16)
__global__ void transpose_x(const float* __restrict__ x, float* __restrict__ XT) {
  int idx = blockIdx.x * 256 + threadIdx.x;     // 16384
  int i = idx >> 4, b = idx & 15;
  XT[idx] = x[b * 1024 + i];
}

// ---------------------------------------------------------------------------
// Sigma network + per-batch prune/collapse coefficients.
// coeff[b*4 + {0,1,2,3}] = sw/tot, pw/tot, dw/tot, alpha
__global__ void sigma_net(const float* __restrict__ x,
                          const float* __restrict__ sW1, const float* __restrict__ sb1,
                          const float* __restrict__ sW2, const float* __restrict__ sb2,
                          const float* __restrict__ sW3, const float* __restrict__ sb3,
                          float* __restrict__ sigma_out, float* __restrict__ coeff) {
  __shared__ float h1[BATCH * 64];
  __shared__ float h2[BATCH * 32];
  __shared__ float sg[BATCH * 16];
  int tid = threadIdx.x;                        // 1024 threads
  {
    int b = tid >> 6, u = tid & 63;
    const float* xr = x + b * 1024;
    const float* wr = sW1 + u * 1024;
    float s = sb1[u];
    for (int i = 0; i < 1024; i += 4) {
      float4 xv = *(const float4*)(xr + i);
      float4 wv = *(const float4*)(wr + i);
      s = fmaf(xv.x, wv.x, s); s = fmaf(xv.y, wv.y, s);
      s = fmaf(xv.z, wv.z, s); s = fmaf(xv.w, wv.w, s);
    }
    h1[b * 64 + u] = fmaxf(s, 0.f);
  }
  __syncthreads();
  if (tid < 512) {
    int b = tid >> 5, u = tid & 31;
    const float* wr = sW2 + u * 64;
    float s = sb2[u];
    #pragma unroll 8
    for (int i = 0; i < 64; ++i) s = fmaf(h1[b * 64 + i], wr[i], s);
    h2[b * 32 + u] = fmaxf(s, 0.f);
  }
  __syncthreads();
  if (tid < 256) {
    int b = tid >> 4, u = tid & 15;
    const float* wr = sW3 + u * 32;
    float s = sb3[u];
    #pragma unroll 8
    for (int i = 0; i < 32; ++i) s = fmaf(h2[b * 32 + i], wr[i], s);
    float t = tanhf(s);
    sg[b * 16 + u] = t;
    sigma_out[b * 16 + u] = t;
  }
  __syncthreads();
  if (tid < BATCH) {
    int b = tid;
    float sw = 0.f, pw = 0.f, dw = 0.f;
    for (int i = 0; i < 5; ++i) {
      sw += sg[b * 16 + i];
      pw += sg[b * 16 + 5 + i];
      dw += sg[b * 16 + 10 + i];
    }
    sw *= 0.2f; pw *= 0.2f; dw *= 0.2f;
    float tot = fabsf(sw) + fabsf(pw) + fabsf(dw) + 1e-8f;
    coeff[b * 4 + 0] = sw / tot;
    coeff[b * 4 + 1] = pw / tot;
    coeff[b * 4 + 2] = dw / tot;
    coeff[b * 4 + 3] = (sg[b * 16 + 15] + 1.f) * 0.5f;
  }
}

// ---------------------------------------------------------------------------
// Generic f32 GEMM: C_out[(m % RPS)*ldc + (m / RPS)*colblk + n] = act(sum_k A[m][k]*B[k][n])
// A row-major lda=K. B row-major (ldb). grid = (N/BN, M/BM), 256 threads.
template <int BM, int BN, int BK, int TM, int TN, bool TANH>
__global__ __launch_bounds__(256) void gemm_kernel(
    const float* __restrict__ A, const float* __restrict__ B, float* __restrict__ C,
    int K, int ldb, int RPS, int ldc, int colblk) {
  __shared__ float Ast[BK][BM + 1];   // transposed, +1 pad: conflict-free ds r/w
  __shared__ float Bs[BK][BN];
  const int tid = threadIdx.x;
  constexpr int NTX = BN / TN;
  const int tx = tid % NTX;
  const int ty = tid / NTX;
  const int m0 = blockIdx.y * BM;
  const int n0 = blockIdx.x * BN;
  float acc[TM][TN] = {};

  constexpr int A_LOADS = (BM * BK) / (4 * 256);
  constexpr int B_LOADS = (BK * BN) / (4 * 256);
  static_assert(A_LOADS >= 1 && B_LOADS >= 1, "tile too small");

  for (int k0 = 0; k0 < K; k0 += BK) {
    #pragma unroll
    for (int l = 0; l < A_LOADS; ++l) {
      int idx = l * 256 + tid;
      int i = idx / (BK / 4);
      int j4 = (idx % (BK / 4)) * 4;
      float4 v = *(const float4*)(A + (size_t)(m0 + i) * K + k0 + j4);
      Ast[j4 + 0][i] = v.x; Ast[j4 + 1][i] = v.y;
      Ast[j4 + 2][i] = v.z; Ast[j4 + 3][i] = v.w;
    }
    #pragma unroll
    for (int l = 0; l < B_LOADS; ++l) {
      int idx = l * 256 + tid;
      int kk = idx / (BN / 4);
      int j4 = (idx % (BN / 4)) * 4;
      *(float4*)(&Bs[kk][j4]) = *(const float4*)(B + (size_t)(k0 + kk) * ldb + n0 + j4);
    }
    __syncthreads();
    #pragma unroll
    for (int kk = 0; kk < BK; ++kk) {
      float a[TM], b[TN];
      #pragma unroll
      for (int i = 0; i < TM; ++i) a[i] = Ast[kk][ty * TM + i];
      #pragma unroll
      for (int j = 0; j < TN; ++j) b[j] = Bs[kk][tx * TN + j];
      #pragma unroll
      for (int i = 0; i < TM; ++i)
        #pragma unroll
        for (int j = 0; j < TN; ++j)
          acc[i][j] = fmaf(a[i], b[j], acc[i][j]);
    }
    __syncthreads();
  }
  #pragma unroll
  for (int i = 0; i < TM; ++i) {
    int m = m0 + ty * TM + i;
    size_t rowoff = (size_t)(m % RPS) * ldc + (size_t)(m / RPS) * colblk;
    #pragma unroll
    for (int j = 0; j < TN; ++j) {
      float v = acc[i][j];
      if (TANH) v = fast_tanh(v);
      C[rowoff + n0 + tx * TN + j] = v;
    }
  }
}

// ---------------------------------------------------------------------------
// Per-(b,path) stats over o3 (512 rows) -> quality.
// Y layout: Y[k3][o3][c2], c2 = k2*128 + k1*16 + b.  grid = (16 coltiles, 8 k3)
__global__ void stats_kernel(const float* __restrict__ Y, const float* __restrict__ coeff,
                             float* __restrict__ Q) {
  int k3 = blockIdx.y;
  int c0 = blockIdx.x * 64;
  int cl = threadIdx.x & 63;
  int rg = threadIdx.x >> 6;                    // 0..3
  const float* base = Y + (size_t)k3 * D3 * 1024 + c0 + cl;
  float s1 = 0.f, s2 = 0.f;
  int cnt = 0;
  for (int r = rg * 128; r < rg * 128 + 128; ++r) {
    float v = base[(size_t)r * 1024];
    s1 += v;
    s2 = fmaf(v, v, s2);
    cnt += (fabsf(v) < 0.1f);
  }
  __shared__ float ls1[256], ls2[256];
  __shared__ int lc[256];
  ls1[threadIdx.x] = s1; ls2[threadIdx.x] = s2; lc[threadIdx.x] = cnt;
  __syncthreads();
  if (threadIdx.x < 64) {
    float S1 = ls1[cl] + ls1[64 + cl] + ls1[128 + cl] + ls1[192 + cl];
    float S2 = ls2[cl] + ls2[64 + cl] + ls2[128 + cl] + ls2[192 + cl];
    int C = lc[cl] + lc[64 + cl] + lc[128 + cl] + lc[192 + cl];
    int c2 = c0 + cl;
    int b = c2 & 15, k1 = (c2 >> 4) & 7, k2 = c2 >> 7;
    float strength = sqrtf(S2);
    float sparsity = (float)C * (1.f / 512.f);
    float diversity = (S2 - S1 * S1 * (1.f / 512.f)) * (1.f / 511.f);
    float q = coeff[b * 4 + 0] * strength + coeff[b * 4 + 1] * sparsity +
              coeff[b * 4 + 2] * diversity;
    Q[b * NPATH + (k3 * 64 + k2 * 8 + k1)] = q;
  }
}

// ---------------------------------------------------------------------------
// Exact top-64 SET per batch via rank counting (jax tie-break: lower index wins).
__global__ void select64(const float* __restrict__ Q, int* __restrict__ sel) {
  int b = blockIdx.x;
  __shared__ float q[NPATH];
  __shared__ int cnt;
  int tid = threadIdx.x;                        // 256
  if (tid == 0) cnt = 0;
  q[tid] = Q[b * NPATH + tid];
  q[tid + 256] = Q[b * NPATH + tid + 256];
  __syncthreads();
  for (int p = tid; p < NPATH; p += 256) {
    float qp = q[p];
    int rank = 0;
    #pragma unroll 8
    for (int j = 0; j < NPATH; ++j) {
      float qj = q[j];
      rank += (qj > qp) || (qj == qp && j < p);
    }
    if (rank < MAXP) {
      int s = atomicAdd(&cnt, 1);
      sel[b * MAXP + s] = p;
    }
  }
}

// ---------------------------------------------------------------------------
// Collapse: out[b][o3] = (1-alpha)*mean + alpha*signed-maxabs over selected paths.
// grid = 32 blocks * 256 threads = 8192 = (b,o3); each block covers one b.
__global__ void collapse_kernel(const float* __restrict__ Y, const int* __restrict__ sel,
                                const float* __restrict__ coeff, float* __restrict__ out) {
  int idx = blockIdx.x * 256 + threadIdx.x;
  int b = idx >> 9, o3 = idx & 511;
  __shared__ int ls[MAXP];
  if (threadIdx.x < MAXP) ls[threadIdx.x] = sel[b * MAXP + threadIdx.x];
  __syncthreads();
  float sum = 0.f, best = 0.f, besta = -1.f;
  #pragma unroll 8
  for (int j = 0; j < MAXP; ++j) {
    int p = ls[j];
    int k3 = p >> 6, k2 = (p >> 3) & 7, k1 = p & 7;
    int col = k2 * 128 + k1 * 16 + b;
    float v = Y[((size_t)(k3 * D3 + o3)) * 1024 + col];
    sum += v;
    float a = fabsf(v);
    if (a > besta) { besta = a; best = v; }
  }
  float alpha = coeff[b * 4 + 3];
  out[idx] = (1.f - alpha) * (sum * (1.f / 64.f)) + alpha * best;
}

// ---------------------------------------------------------------------------
extern "C" void kernel_launch(void* const* d_in, const int* in_sizes, int n_in,
                              void* d_out, int out_size, void* d_ws, size_t ws_size,
                              hipStream_t stream) {
  const float* x   = (const float*)d_in[0];
  const float* W1  = (const float*)d_in[1];
  const float* W2  = (const float*)d_in[2];
  const float* W3  = (const float*)d_in[3];
  const float* sW1 = (const float*)d_in[4];
  const float* sb1 = (const float*)d_in[5];
  const float* sW2 = (const float*)d_in[6];
  const float* sb2 = (const float*)d_in[7];
  const float* sW3 = (const float*)d_in[8];
  const float* sb3 = (const float*)d_in[9];
  float* out = (float*)d_out;                   // 16*512 outputs + 16*16 sigma

  float* XT    = (float*)d_ws;                  // 1024*16
  float* X2    = XT + 16384;                    // 1024*128  (o, k1*16+b)
  float* X3    = X2 + 131072;                   // 1024*1024 (o, k2*128+k1*16+b)
  float* Y     = X3 + 1048576;                  // 8*512*1024
  float* coeff = Y + 4194304;                   // 16*4
  float* Q     = coeff + 64;                    // 16*512
  int*   sel   = (int*)(Q + 8192);              // 16*64

  transpose_x<<<64, 256, 0, stream>>>(x, XT);
  sigma_net<<<1, 1024, 0, stream>>>(x, sW1, sb1, sW2, sb2, sW3, sb3, out + 8192, coeff);

  // L1: M=8192 (k1*1024+o), N=16, K=1024 -> X2[o][k1*16+b], tanh
  gemm_kernel<32, 16, 64, 2, 1, true>
      <<<dim3(1, 8192 / 32), 256, 0, stream>>>(W1, XT, X2, 1024, 16, 1024, 128, 16);
  // L2: M=8192 (k2*1024+o), N=128, K=1024 -> X3[o][k2*128+c], tanh
  gemm_kernel<64, 64, 32, 4, 4, true>
      <<<dim3(2, 8192 / 64), 256, 0, stream>>>(W2, X2, X3, 1024, 128, 1024, 1024, 128);
  // L3: M=4096 (k3*512+o3), N=1024, K=1024 -> Y[k3][o3][c], no act
  gemm_kernel<128, 64, 32, 8, 4, false>
      <<<dim3(16, 4096 / 128), 256, 0, stream>>>(W3, X3, Y, 1024, 1024, 4096, 1024, 0);

  stats_kernel<<<dim3(16, 8), 256, 0, stream>>>(Y, coeff, Q);
  select64<<<16, 256, 0, stream>>>(Q, sel);
  collapse_kernel<<<32, 256, 0, stream>>>(Y, sel, coeff, out);
}

// Round 3
// 477.535 us; speedup vs baseline: 1.2721x; 1.2721x over previous
//
#include <hip/hip_runtime.h>
#include <hip/hip_bf16.h>

// Sizes (fixed by the problem)
#define BATCH 16
#define D0 1024
#define D1 1024
#define D2 1024
#define D3 512
#define KSL 8          // K slices per weight
#define MAXP 64        // paths kept
#define NPATH 512      // paths before prune (8*8*8)

__device__ __forceinline__ float fast_tanh(float x) {
  // stable: 1 - 2/(e^{2x}+1);  +inf -> 1, -inf -> -1
  float e = __expf(2.f * x);
  return 1.f - 2.f / (e + 1.f);
}

// ---------------------------------------------------------------------------
// x (16,1024) row-major  ->  XT (1024,16)
__global__ void transpose_x(const float* __restrict__ x, float* __restrict__ XT) {
  int idx = blockIdx.x * 256 + threadIdx.x;     // 16384
  int i = idx >> 4, b = idx & 15;
  XT[idx] = x[b * 1024 + i];
}

// ---------------------------------------------------------------------------
// Sigma stage 1: h1[b][u] = relu(x[b] . sW1[u] + sb1[u]); 1024 outputs,
// one wave per output (256 blocks x 4 waves).
__global__ __launch_bounds__(256) void sigma_stage1(
    const float* __restrict__ x, const float* __restrict__ sW1,
    const float* __restrict__ sb1, float* __restrict__ h1) {
  int wv = threadIdx.x >> 6, lane = threadIdx.x & 63;
  int idx = blockIdx.x * 4 + wv;                // 0..1023
  int b = idx >> 6, u = idx & 63;
  const float* xr = x + b * 1024;
  const float* wr = sW1 + u * 1024;
  float s = 0.f;
  #pragma unroll
  for (int i = 0; i < 4; ++i) {
    int k = i * 256 + lane * 4;
    float4 xv = *(const float4*)(xr + k);
    float4 wv4 = *(const float4*)(wr + k);
    s = fmaf(xv.x, wv4.x, s); s = fmaf(xv.y, wv4.y, s);
    s = fmaf(xv.z, wv4.z, s); s = fmaf(xv.w, wv4.w, s);
  }
  #pragma unroll
  for (int off = 32; off > 0; off >>= 1) s += __shfl_down(s, off);
  if (lane == 0) h1[b * 64 + u] = fmaxf(s + sb1[u], 0.f);
}

// ---------------------------------------------------------------------------
// Sigma stage 2: h2, sigma (tanh), coeff. Tiny — one block of 512 threads.
__global__ void sigma_stage2(const float* __restrict__ h1,
                             const float* __restrict__ sW2, const float* __restrict__ sb2,
                             const float* __restrict__ sW3, const float* __restrict__ sb3,
                             float* __restrict__ sigma_out, float* __restrict__ coeff) {
  __shared__ float lh1[BATCH * 64];
  __shared__ float h2[BATCH * 32];
  __shared__ float sg[BATCH * 16];
  int tid = threadIdx.x;                        // 512
  if (tid < BATCH * 64) lh1[tid] = h1[tid];
  if (tid + 512 < BATCH * 64) lh1[tid + 512] = h1[tid + 512];
  __syncthreads();
  {
    int b = tid >> 5, u = tid & 31;
    const float* wr = sW2 + u * 64;
    float s = sb2[u];
    #pragma unroll 8
    for (int i = 0; i < 64; ++i) s = fmaf(lh1[b * 64 + i], wr[i], s);
    h2[b * 32 + u] = fmaxf(s, 0.f);
  }
  __syncthreads();
  if (tid < 256) {
    int b = tid >> 4, u = tid & 15;
    const float* wr = sW3 + u * 32;
    float s = sb3[u];
    #pragma unroll 8
    for (int i = 0; i < 32; ++i) s = fmaf(h2[b * 32 + i], wr[i], s);
    float t = tanhf(s);
    sg[b * 16 + u] = t;
    sigma_out[b * 16 + u] = t;
  }
  __syncthreads();
  if (tid < BATCH) {
    int b = tid;
    float sw = 0.f, pw = 0.f, dw = 0.f;
    for (int i = 0; i < 5; ++i) {
      sw += sg[b * 16 + i];
      pw += sg[b * 16 + 5 + i];
      dw += sg[b * 16 + 10 + i];
    }
    sw *= 0.2f; pw *= 0.2f; dw *= 0.2f;
    float tot = fabsf(sw) + fabsf(pw) + fabsf(dw) + 1e-8f;
    coeff[b * 4 + 0] = sw / tot;
    coeff[b * 4 + 1] = pw / tot;
    coeff[b * 4 + 2] = dw / tot;
    coeff[b * 4 + 3] = (sg[b * 16 + 15] + 1.f) * 0.5f;
  }
}

// ---------------------------------------------------------------------------
// Generic f32 GEMM: C_out[(m % RPS)*ldc + (m / RPS)*colblk + n] = act(sum_k A[m][k]*B[k][n])
// A row-major lda=K. B row-major (ldb). grid = (N/BN, M/BM), 256 threads.
template <int BM, int BN, int BK, int TM, int TN, bool TANH>
__global__ __launch_bounds__(256) void gemm_kernel(
    const float* __restrict__ A, const float* __restrict__ B, float* __restrict__ C,
    int K, int ldb, int RPS, int ldc, int colblk) {
  static_assert(BM * BN == 256 * TM * TN, "thread tile must cover block tile exactly");
  __shared__ float Ast[BK][BM + 1];   // transposed, +1 pad: conflict-free ds r/w
  __shared__ float Bs[BK][BN];
  const int tid = threadIdx.x;
  constexpr int NTX = BN / TN;
  const int tx = tid % NTX;
  const int ty = tid / NTX;
  const int m0 = blockIdx.y * BM;
  const int n0 = blockIdx.x * BN;
  float acc[TM][TN] = {};

  constexpr int A_LOADS = (BM * BK) / (4 * 256);
  constexpr int B_LOADS = (BK * BN) / (4 * 256);
  static_assert(A_LOADS >= 1 && B_LOADS >= 1, "tile too small");

  for (int k0 = 0; k0 < K; k0 += BK) {
    #pragma unroll
    for (int l = 0; l < A_LOADS; ++l) {
      int idx = l * 256 + tid;
      int i = idx / (BK / 4);
      int j4 = (idx % (BK / 4)) * 4;
      float4 v = *(const float4*)(A + (size_t)(m0 + i) * K + k0 + j4);
      Ast[j4 + 0][i] = v.x; Ast[j4 + 1][i] = v.y;
      Ast[j4 + 2][i] = v.z; Ast[j4 + 3][i] = v.w;
    }
    #pragma unroll
    for (int l = 0; l < B_LOADS; ++l) {
      int idx = l * 256 + tid;
      int kk = idx / (BN / 4);
      int j4 = (idx % (BN / 4)) * 4;
      *(float4*)(&Bs[kk][j4]) = *(const float4*)(B + (size_t)(k0 + kk) * ldb + n0 + j4);
    }
    __syncthreads();
    #pragma unroll
    for (int kk = 0; kk < BK; ++kk) {
      float a[TM], b[TN];
      #pragma unroll
      for (int i = 0; i < TM; ++i) a[i] = Ast[kk][ty * TM + i];
      #pragma unroll
      for (int j = 0; j < TN; ++j) b[j] = Bs[kk][tx * TN + j];
      #pragma unroll
      for (int i = 0; i < TM; ++i)
        #pragma unroll
        for (int j = 0; j < TN; ++j)
          acc[i][j] = fmaf(a[i], b[j], acc[i][j]);
    }
    __syncthreads();
  }
  #pragma unroll
  for (int i = 0; i < TM; ++i) {
    int m = m0 + ty * TM + i;
    size_t rowoff = (size_t)(m % RPS) * ldc + (size_t)(m / RPS) * colblk;
    #pragma unroll
    for (int j = 0; j < TN; ++j) {
      float v = acc[i][j];
      if (TANH) v = fast_tanh(v);
      C[rowoff + n0 + tx * TN + j] = v;
    }
  }
}

// ---------------------------------------------------------------------------
// Per-(b,path) stats over o3 (512 rows) -> quality.
// Y layout: Y[k3][o3][c2], c2 = k2*128 + k1*16 + b.  grid = (16 coltiles, 8 k3)
__global__ void stats_kernel(const float* __restrict__ Y, const float* __restrict__ coeff,
                             float* __restrict__ Q) {
  int k3 = blockIdx.y;
  int c0 = blockIdx.x * 64;
  int cl = threadIdx.x & 63;
  int rg = threadIdx.x >> 6;                    // 0..3
  const float* base = Y + (size_t)k3 * D3 * 1024 + c0 + cl;
  float s1 = 0.f, s2 = 0.f;
  int cnt = 0;
  for (int r = rg * 128; r < rg * 128 + 128; ++r) {
    float v = base[(size_t)r * 1024];
    s1 += v;
    s2 = fmaf(v, v, s2);
    cnt += (fabsf(v) < 0.1f);
  }
  __shared__ float ls1[256], ls2[256];
  __shared__ int lc[256];
  ls1[threadIdx.x] = s1; ls2[threadIdx.x] = s2; lc[threadIdx.x] = cnt;
  __syncthreads();
  if (threadIdx.x < 64) {
    float S1 = ls1[cl] + ls1[64 + cl] + ls1[128 + cl] + ls1[192 + cl];
    float S2 = ls2[cl] + ls2[64 + cl] + ls2[128 + cl] + ls2[192 + cl];
    int C = lc[cl] + lc[64 + cl] + lc[128 + cl] + lc[192 + cl];
    int c2 = c0 + cl;
    int b = c2 & 15, k1 = (c2 >> 4) & 7, k2 = c2 >> 7;
    float strength = sqrtf(S2);
    float sparsity = (float)C * (1.f / 512.f);
    float diversity = (S2 - S1 * S1 * (1.f / 512.f)) * (1.f / 511.f);
    float q = coeff[b * 4 + 0] * strength + coeff[b * 4 + 1] * sparsity +
              coeff[b * 4 + 2] * diversity;
    Q[b * NPATH + (k3 * 64 + k2 * 8 + k1)] = q;
  }
}

// ---------------------------------------------------------------------------
// Exact top-64 SET per batch via rank counting (jax tie-break: lower index wins).
__global__ void select64(const float* __restrict__ Q, int* __restrict__ sel) {
  int b = blockIdx.x;
  __shared__ float q[NPATH];
  __shared__ int cnt;
  int tid = threadIdx.x;                        // 256
  if (tid == 0) cnt = 0;
  q[tid] = Q[b * NPATH + tid];
  q[tid + 256] = Q[b * NPATH + tid + 256];
  __syncthreads();
  for (int p = tid; p < NPATH; p += 256) {
    float qp = q[p];
    int rank = 0;
    #pragma unroll 8
    for (int j = 0; j < NPATH; ++j) {
      float qj = q[j];
      rank += (qj > qp) || (qj == qp && j < p);
    }
    if (rank < MAXP) {
      int s = atomicAdd(&cnt, 1);
      sel[b * MAXP + s] = p;
    }
  }
}

// ---------------------------------------------------------------------------
// Collapse: out[b][o3] = (1-alpha)*mean + alpha*signed-maxabs over selected paths.
__global__ void collapse_kernel(const float* __restrict__ Y, const int* __restrict__ sel,
                                const float* __restrict__ coeff, float* __restrict__ out) {
  int idx = blockIdx.x * 256 + threadIdx.x;
  int b = idx >> 9, o3 = idx & 511;
  __shared__ int ls[MAXP];
  if (threadIdx.x < MAXP) ls[threadIdx.x] = sel[b * MAXP + threadIdx.x];
  __syncthreads();
  float sum = 0.f, best = 0.f, besta = -1.f;
  #pragma unroll 8
  for (int j = 0; j < MAXP; ++j) {
    int p = ls[j];
    int k3 = p >> 6, k2 = (p >> 3) & 7, k1 = p & 7;
    int col = k2 * 128 + k1 * 16 + b;
    float v = Y[((size_t)(k3 * D3 + o3)) * 1024 + col];
    sum += v;
    float a = fabsf(v);
    if (a > besta) { besta = a; best = v; }
  }
  float alpha = coeff[b * 4 + 3];
  out[idx] = (1.f - alpha) * (sum * (1.f / 64.f)) + alpha * best;
}

// ---------------------------------------------------------------------------
extern "C" void kernel_launch(void* const* d_in, const int* in_sizes, int n_in,
                              void* d_out, int out_size, void* d_ws, size_t ws_size,
                              hipStream_t stream) {
  const float* x   = (const float*)d_in[0];
  const float* W1  = (const float*)d_in[1];
  const float* W2  = (const float*)d_in[2];
  const float* W3  = (const float*)d_in[3];
  const float* sW1 = (const float*)d_in[4];
  const float* sb1 = (const float*)d_in[5];
  const float* sW2 = (const float*)d_in[6];
  const float* sb2 = (const float*)d_in[7];
  const float* sW3 = (const float*)d_in[8];
  const float* sb3 = (const float*)d_in[9];
  float* out = (float*)d_out;                   // 16*512 outputs + 16*16 sigma

  float* XT    = (float*)d_ws;                  // 1024*16
  float* X2    = XT + 16384;                    // 1024*128  (o, k1*16+b)
  float* X3    = X2 + 131072;                   // 1024*1024 (o, k2*128+k1*16+b)
  float* Y     = X3 + 1048576;                  // 8*512*1024
  float* coeff = Y + 4194304;                   // 16*4
  float* Q     = coeff + 64;                    // 16*512
  int*   sel   = (int*)(Q + 8192);              // 16*64
  float* h1    = (float*)(sel + 1024);          // 16*64

  transpose_x<<<64, 256, 0, stream>>>(x, XT);
  sigma_stage1<<<256, 256, 0, stream>>>(x, sW1, sb1, h1);
  sigma_stage2<<<1, 512, 0, stream>>>(h1, sW2, sb2, sW3, sb3, out + 8192, coeff);

  // L1: M=8192 (k1*1024+o), N=16, K=1024 -> X2[o][k1*16+b], tanh
  gemm_kernel<128, 16, 64, 2, 4, true>
      <<<dim3(1, 8192 / 128), 256, 0, stream>>>(W1, XT, X2, 1024, 16, 1024, 128, 16);
  // L2: M=8192 (k2*1024+o), N=128, K=1024 -> X3[o][k2*128+c], tanh
  gemm_kernel<64, 64, 32, 4, 4, true>
      <<<dim3(2, 8192 / 64), 256, 0, stream>>>(W2, X2, X3, 1024, 128, 1024, 1024, 128);
  // L3: M=4096 (k3*512+o3), N=1024, K=1024 -> Y[k3][o3][c], no act
  gemm_kernel<128, 64, 32, 8, 4, false>
      <<<dim3(16, 4096 / 128), 256, 0, stream>>>(W3, X3, Y, 1024, 1024, 4096, 1024, 0);

  stats_kernel<<<dim3(16, 8), 256, 0, stream>>>(Y, coeff, Q);
  select64<<<16, 256, 0, stream>>>(Q, sel);
  collapse_kernel<<<32, 256, 0, stream>>>(Y, sel, coeff, out);
}

// Round 4
// 424.621 us; speedup vs baseline: 1.4306x; 1.1246x over previous
//
#include <hip/hip_runtime.h>
#include <hip/hip_bf16.h>

#define BATCH 16
#define D3 512
#define MAXP 64
#define NPATH 512

typedef short short8 __attribute__((ext_vector_type(8)));
typedef float floatx16 __attribute__((ext_vector_type(16)));
typedef unsigned short ushort4v __attribute__((ext_vector_type(4)));

__device__ __forceinline__ float fast_tanh(float x) {
  float e = __expf(2.f * x);
  return 1.f - 2.f / (e + 1.f);
}

__device__ __forceinline__ unsigned short f32_to_bf16_rn(float f) {
  unsigned u = __float_as_uint(f);
  u += 0x7fffu + ((u >> 16) & 1u);
  return (unsigned short)(u >> 16);
}
__device__ __forceinline__ float bf16_bits_to_f32(unsigned short s) {
  return __uint_as_float(((unsigned)s) << 16);
}

// ---------------------------------------------------------------------------
// x (16,1024) row-major  ->  XT (1024,16)
__global__ void transpose_x(const float* __restrict__ x, float* __restrict__ XT) {
  int idx = blockIdx.x * 256 + threadIdx.x;     // 16384
  int i = idx >> 4, b = idx & 15;
  XT[idx] = x[b * 1024 + i];
}

// ---------------------------------------------------------------------------
// Sigma stage 1: one wave per output (256 blocks x 4 waves).
__global__ __launch_bounds__(256) void sigma_stage1(
    const float* __restrict__ x, const float* __restrict__ sW1,
    const float* __restrict__ sb1, float* __restrict__ h1) {
  int wv = threadIdx.x >> 6, lane = threadIdx.x & 63;
  int idx = blockIdx.x * 4 + wv;                // 0..1023
  int b = idx >> 6, u = idx & 63;
  const float* xr = x + b * 1024;
  const float* wr = sW1 + u * 1024;
  float s = 0.f;
  #pragma unroll
  for (int i = 0; i < 4; ++i) {
    int k = i * 256 + lane * 4;
    float4 xv = *(const float4*)(xr + k);
    float4 wv4 = *(const float4*)(wr + k);
    s = fmaf(xv.x, wv4.x, s); s = fmaf(xv.y, wv4.y, s);
    s = fmaf(xv.z, wv4.z, s); s = fmaf(xv.w, wv4.w, s);
  }
  #pragma unroll
  for (int off = 32; off > 0; off >>= 1) s += __shfl_down(s, off);
  if (lane == 0) h1[b * 64 + u] = fmaxf(s + sb1[u], 0.f);
}

// ---------------------------------------------------------------------------
// Sigma stage 2: h2, sigma (tanh), coeff. One block of 512 threads.
__global__ void sigma_stage2(const float* __restrict__ h1,
                             const float* __restrict__ sW2, const float* __restrict__ sb2,
                             const float* __restrict__ sW3, const float* __restrict__ sb3,
                             float* __restrict__ sigma_out, float* __restrict__ coeff) {
  __shared__ float lh1[BATCH * 64];
  __shared__ float h2[BATCH * 32];
  __shared__ float sg[BATCH * 16];
  int tid = threadIdx.x;                        // 512
  if (tid < BATCH * 64) lh1[tid] = h1[tid];
  if (tid + 512 < BATCH * 64) lh1[tid + 512] = h1[tid + 512];
  __syncthreads();
  {
    int b = tid >> 5, u = tid & 31;
    const float* wr = sW2 + u * 64;
    float s = sb2[u];
    #pragma unroll 8
    for (int i = 0; i < 64; ++i) s = fmaf(lh1[b * 64 + i], wr[i], s);
    h2[b * 32 + u] = fmaxf(s, 0.f);
  }
  __syncthreads();
  if (tid < 256) {
    int b = tid >> 4, u = tid & 15;
    const float* wr = sW3 + u * 32;
    float s = sb3[u];
    #pragma unroll 8
    for (int i = 0; i < 32; ++i) s = fmaf(h2[b * 32 + i], wr[i], s);
    float t = tanhf(s);
    sg[b * 16 + u] = t;
    sigma_out[b * 16 + u] = t;
  }
  __syncthreads();
  if (tid < BATCH) {
    int b = tid;
    float sw = 0.f, pw = 0.f, dw = 0.f;
    for (int i = 0; i < 5; ++i) {
      sw += sg[b * 16 + i];
      pw += sg[b * 16 + 5 + i];
      dw += sg[b * 16 + 10 + i];
    }
    sw *= 0.2f; pw *= 0.2f; dw *= 0.2f;
    float tot = fabsf(sw) + fabsf(pw) + fabsf(dw) + 1e-8f;
    coeff[b * 4 + 0] = sw / tot;
    coeff[b * 4 + 1] = pw / tot;
    coeff[b * 4 + 2] = dw / tot;
    coeff[b * 4 + 3] = (sg[b * 16 + 15] + 1.f) * 0.5f;
  }
}

// ---------------------------------------------------------------------------
// L1 f32 GEMM: W1 (8192x1024) @ XT (1024x16) -> tanh -> split-bf16 transposed
// X2t[(k1*16+n)][o1], pitch 1024. grid = 256 blocks (BM=32).
__global__ __launch_bounds__(256) void gemm_l1(
    const float* __restrict__ W1, const float* __restrict__ XT,
    unsigned short* __restrict__ X2th, unsigned short* __restrict__ X2tl) {
  __shared__ float Ast[64][33];
  __shared__ float Bs[64][16];
  const int tid = threadIdx.x;
  const int tx = tid & 15, ty = tid >> 4;       // tx: n 0..15, ty: 0..15
  const int m0 = blockIdx.x * 32;
  float acc0 = 0.f, acc1 = 0.f;
  for (int k0 = 0; k0 < 1024; k0 += 64) {
    #pragma unroll
    for (int l = 0; l < 2; ++l) {
      int idx = l * 256 + tid;                  // 0..511
      int i = idx >> 4;                         // row 0..31
      int j4 = (idx & 15) * 4;
      float4 v = *(const float4*)(W1 + (size_t)(m0 + i) * 1024 + k0 + j4);
      Ast[j4 + 0][i] = v.x; Ast[j4 + 1][i] = v.y;
      Ast[j4 + 2][i] = v.z; Ast[j4 + 3][i] = v.w;
    }
    {
      int kk = tid >> 2, j4 = (tid & 3) * 4;
      *(float4*)&Bs[kk][j4] = *(const float4*)(XT + (size_t)(k0 + kk) * 16 + j4);
    }
    __syncthreads();
    #pragma unroll
    for (int kk = 0; kk < 64; ++kk) {
      float b = Bs[kk][tx];
      acc0 = fmaf(Ast[kk][ty * 2 + 0], b, acc0);
      acc1 = fmaf(Ast[kk][ty * 2 + 1], b, acc1);
    }
    __syncthreads();
  }
  #pragma unroll
  for (int i = 0; i < 2; ++i) {
    int m = m0 + ty * 2 + i;
    float v = fast_tanh(i == 0 ? acc0 : acc1);
    unsigned short hi = f32_to_bf16_rn(v);
    unsigned short lo = f32_to_bf16_rn(v - bf16_bits_to_f32(hi));
    int c1 = (m >> 10) * 16 + tx;
    int o1 = m & 1023;
    X2th[c1 * 1024 + o1] = hi;
    X2tl[c1 * 1024 + o1] = lo;
  }
}

// ---------------------------------------------------------------------------
// Split-bf16 MFMA GEMM (32x32x16).
//   A: f32 [M][K] row-major (weights), split hi/lo inline during staging.
//   B: bf16 hi/lo, TRANSPOSED [N][K] row-major.
//   C = A.B^T; EPI=0: outF[m*ldc + n] = v.
//             EPI=1: v=tanh(v); split; outH/outL[((m>>10)*128 + n)*1024 + (m&1023)].
// Block: 256 threads = 4 waves in 2x2; wave tile (BM/2)x(BN/2) of 32x32 MFMA tiles.
template <int BM, int BN, int EPI>
__global__ __launch_bounds__(256) void mfma_gemm(
    const float* __restrict__ A, const unsigned short* __restrict__ Bh,
    const unsigned short* __restrict__ Bl, float* __restrict__ outF,
    unsigned short* __restrict__ outH, unsigned short* __restrict__ outL,
    int K, int ldc) {
  constexpr int TM = BM / 64;                   // 32x32 tiles per wave (m)
  constexpr int TN = BN / 64;                   // (n)
  static_assert(TM >= 1 && TN >= 1, "tile");
  constexpr int PK = 40;                        // padded K pitch (shorts); 80B rows, 16B aligned
  __shared__ __align__(16) unsigned short As[2][BM][PK];
  __shared__ __align__(16) unsigned short Bs[2][BN][PK];
  const int tid = threadIdx.x;
  const int lane = tid & 63, wave = tid >> 6;
  const int wm = wave >> 1, wn = wave & 1;
  const int lr = lane & 31;                     // row/col within 32-tile
  const int kh = lane >> 5;                     // k-half (8 elems each)
  const int m0 = blockIdx.y * BM, n0 = blockIdx.x * BN;

  floatx16 acc[TM][TN];
  #pragma unroll
  for (int i = 0; i < TM; ++i)
    #pragma unroll
    for (int j = 0; j < TN; ++j)
      #pragma unroll
      for (int t = 0; t < 16; ++t) acc[i][j][t] = 0.f;

  for (int k0 = 0; k0 < K; k0 += 32) {
    // stage A (f32 -> hi/lo bf16): BM rows x 8 float4-chunks
    for (int idx = tid; idx < BM * 8; idx += 256) {
      int row = idx >> 3, c4 = (idx & 7) * 4;
      float4 v = *(const float4*)(A + (size_t)(m0 + row) * K + k0 + c4);
      ushort4v h, l;
      float f, hf;
      f = v.x; h[0] = f32_to_bf16_rn(f); hf = bf16_bits_to_f32(h[0]); l[0] = f32_to_bf16_rn(f - hf);
      f = v.y; h[1] = f32_to_bf16_rn(f); hf = bf16_bits_to_f32(h[1]); l[1] = f32_to_bf16_rn(f - hf);
      f = v.z; h[2] = f32_to_bf16_rn(f); hf = bf16_bits_to_f32(h[2]); l[2] = f32_to_bf16_rn(f - hf);
      f = v.w; h[3] = f32_to_bf16_rn(f); hf = bf16_bits_to_f32(h[3]); l[3] = f32_to_bf16_rn(f - hf);
      *(ushort4v*)&As[0][row][c4] = h;
      *(ushort4v*)&As[1][row][c4] = l;
    }
    // stage B (pre-split bf16): BN rows x 4 short8-chunks
    for (int idx = tid; idx < BN * 4; idx += 256) {
      int row = idx >> 2, c8 = (idx & 3) * 8;
      *(short8*)&Bs[0][row][c8] = *(const short8*)(Bh + (size_t)(n0 + row) * K + k0 + c8);
      *(short8*)&Bs[1][row][c8] = *(const short8*)(Bl + (size_t)(n0 + row) * K + k0 + c8);
    }
    __syncthreads();
    #pragma unroll
    for (int ks = 0; ks < 2; ++ks) {
      short8 a[TM][2], b[TN][2];
      #pragma unroll
      for (int i = 0; i < TM; ++i) {
        a[i][0] = *(const short8*)&As[0][wm * (BM / 2) + i * 32 + lr][ks * 16 + kh * 8];
        a[i][1] = *(const short8*)&As[1][wm * (BM / 2) + i * 32 + lr][ks * 16 + kh * 8];
      }
      #pragma unroll
      for (int j = 0; j < TN; ++j) {
        b[j][0] = *(const short8*)&Bs[0][wn * (BN / 2) + j * 32 + lr][ks * 16 + kh * 8];
        b[j][1] = *(const short8*)&Bs[1][wn * (BN / 2) + j * 32 + lr][ks * 16 + kh * 8];
      }
      #pragma unroll
      for (int i = 0; i < TM; ++i)
        #pragma unroll
        for (int j = 0; j < TN; ++j) {
          acc[i][j] = __builtin_amdgcn_mfma_f32_32x32x16_bf16(a[i][0], b[j][0], acc[i][j], 0, 0, 0);
          acc[i][j] = __builtin_amdgcn_mfma_f32_32x32x16_bf16(a[i][0], b[j][1], acc[i][j], 0, 0, 0);
          acc[i][j] = __builtin_amdgcn_mfma_f32_32x32x16_bf16(a[i][1], b[j][0], acc[i][j], 0, 0, 0);
        }
    }
    __syncthreads();
  }
  // epilogue: C/D layout col=lane&31, row=(reg&3)+8*(reg>>2)+4*(lane>>5)
  #pragma unroll
  for (int i = 0; i < TM; ++i)
    #pragma unroll
    for (int j = 0; j < TN; ++j)
      #pragma unroll
      for (int r = 0; r < 16; ++r) {
        int row = wm * (BM / 2) + i * 32 + (r & 3) + 8 * (r >> 2) + 4 * kh;
        int col = wn * (BN / 2) + j * 32 + lr;
        int m = m0 + row, n = n0 + col;
        float v = acc[i][j][r];
        if (EPI == 0) {
          outF[(size_t)m * ldc + n] = v;
        } else {
          v = fast_tanh(v);
          unsigned short hi = f32_to_bf16_rn(v);
          unsigned short lo = f32_to_bf16_rn(v - bf16_bits_to_f32(hi));
          size_t o = (size_t)((m >> 10) * 128 + n) * 1024 + (m & 1023);
          outH[o] = hi;
          outL[o] = lo;
        }
      }
}

// ---------------------------------------------------------------------------
// Per-(b,path) stats over o3 (512 rows) -> quality.
__global__ void stats_kernel(const float* __restrict__ Y, const float* __restrict__ coeff,
                             float* __restrict__ Q) {
  int k3 = blockIdx.y;
  int c0 = blockIdx.x * 64;
  int cl = threadIdx.x & 63;
  int rg = threadIdx.x >> 6;
  const float* base = Y + (size_t)k3 * D3 * 1024 + c0 + cl;
  float s1 = 0.f, s2 = 0.f;
  int cnt = 0;
  for (int r = rg * 128; r < rg * 128 + 128; ++r) {
    float v = base[(size_t)r * 1024];
    s1 += v;
    s2 = fmaf(v, v, s2);
    cnt += (fabsf(v) < 0.1f);
  }
  __shared__ float ls1[256], ls2[256];
  __shared__ int lc[256];
  ls1[threadIdx.x] = s1; ls2[threadIdx.x] = s2; lc[threadIdx.x] = cnt;
  __syncthreads();
  if (threadIdx.x < 64) {
    float S1 = ls1[cl] + ls1[64 + cl] + ls1[128 + cl] + ls1[192 + cl];
    float S2 = ls2[cl] + ls2[64 + cl] + ls2[128 + cl] + ls2[192 + cl];
    int C = lc[cl] + lc[64 + cl] + lc[128 + cl] + lc[192 + cl];
    int c2 = c0 + cl;
    int b = c2 & 15, k1 = (c2 >> 4) & 7, k2 = c2 >> 7;
    float strength = sqrtf(S2);
    float sparsity = (float)C * (1.f / 512.f);
    float diversity = (S2 - S1 * S1 * (1.f / 512.f)) * (1.f / 511.f);
    float q = coeff[b * 4 + 0] * strength + coeff[b * 4 + 1] * sparsity +
              coeff[b * 4 + 2] * diversity;
    Q[b * NPATH + (k3 * 64 + k2 * 8 + k1)] = q;
  }
}

// ---------------------------------------------------------------------------
__global__ void select64(const float* __restrict__ Q, int* __restrict__ sel) {
  int b = blockIdx.x;
  __shared__ float q[NPATH];
  __shared__ int cnt;
  int tid = threadIdx.x;                        // 256
  if (tid == 0) cnt = 0;
  q[tid] = Q[b * NPATH + tid];
  q[tid + 256] = Q[b * NPATH + tid + 256];
  __syncthreads();
  for (int p = tid; p < NPATH; p += 256) {
    float qp = q[p];
    int rank = 0;
    #pragma unroll 8
    for (int j = 0; j < NPATH; ++j) {
      float qj = q[j];
      rank += (qj > qp) || (qj == qp && j < p);
    }
    if (rank < MAXP) {
      int s = atomicAdd(&cnt, 1);
      sel[b * MAXP + s] = p;
    }
  }
}

// ---------------------------------------------------------------------------
__global__ void collapse_kernel(const float* __restrict__ Y, const int* __restrict__ sel,
                                const float* __restrict__ coeff, float* __restrict__ out) {
  int idx = blockIdx.x * 256 + threadIdx.x;
  int b = idx >> 9, o3 = idx & 511;
  __shared__ int ls[MAXP];
  if (threadIdx.x < MAXP) ls[threadIdx.x] = sel[b * MAXP + threadIdx.x];
  __syncthreads();
  float sum = 0.f, best = 0.f, besta = -1.f;
  #pragma unroll 8
  for (int j = 0; j < MAXP; ++j) {
    int p = ls[j];
    int k3 = p >> 6, k2 = (p >> 3) & 7, k1 = p & 7;
    int col = k2 * 128 + k1 * 16 + b;
    float v = Y[((size_t)(k3 * D3 + o3)) * 1024 + col];
    sum += v;
    float a = fabsf(v);
    if (a > besta) { besta = a; best = v; }
  }
  float alpha = coeff[b * 4 + 3];
  out[idx] = (1.f - alpha) * (sum * (1.f / 64.f)) + alpha * best;
}

// ---------------------------------------------------------------------------
extern "C" void kernel_launch(void* const* d_in, const int* in_sizes, int n_in,
                              void* d_out, int out_size, void* d_ws, size_t ws_size,
                              hipStream_t stream) {
  const float* x   = (const float*)d_in[0];
  const float* W1  = (const float*)d_in[1];
  const float* W2  = (const float*)d_in[2];
  const float* W3  = (const float*)d_in[3];
  const float* sW1 = (const float*)d_in[4];
  const float* sb1 = (const float*)d_in[5];
  const float* sW2 = (const float*)d_in[6];
  const float* sb2 = (const float*)d_in[7];
  const float* sW3 = (const float*)d_in[8];
  const float* sb3 = (const float*)d_in[9];
  float* out = (float*)d_out;                   // 16*512 outputs + 16*16 sigma

  char* w = (char*)d_ws;
  float* XT = (float*)w;            w += 65536;      // 1024x16 f32
  unsigned short* X2th = (unsigned short*)w; w += 262144;   // 128x1024 bf16
  unsigned short* X2tl = (unsigned short*)w; w += 262144;
  unsigned short* X3th = (unsigned short*)w; w += 2097152;  // 1024x1024 bf16
  unsigned short* X3tl = (unsigned short*)w; w += 2097152;
  float* Y     = (float*)w;         w += 16777216;   // 4096x1024 f32
  float* coeff = (float*)w;         w += 256;
  float* Q     = (float*)w;         w += 32768;
  int*   sel   = (int*)w;           w += 4096;
  float* h1    = (float*)w;         w += 4096;

  transpose_x<<<64, 256, 0, stream>>>(x, XT);
  sigma_stage1<<<256, 256, 0, stream>>>(x, sW1, sb1, h1);
  sigma_stage2<<<1, 512, 0, stream>>>(h1, sW2, sb2, sW3, sb3, out + 8192, coeff);

  // L1: f32, M=8192, N=16 -> X2t (bf16 hi/lo, [k1*16+b][o1])
  gemm_l1<<<256, 256, 0, stream>>>(W1, XT, X2th, X2tl);

  // L2: MFMA split-bf16, M=8192, N=128, K=1024 -> X3t (bf16 hi/lo, [k2*128+n][o2])
  mfma_gemm<128, 64, 1><<<dim3(2, 64), 256, 0, stream>>>(
      W2, X2th, X2tl, nullptr, X3th, X3tl, 1024, 0);

  // L3: MFMA split-bf16, M=4096, N=1024, K=1024 -> Y f32 [k3*512+o3][c2]
  mfma_gemm<128, 128, 0><<<dim3(8, 32), 256, 0, stream>>>(
      W3, X3th, X3tl, Y, nullptr, nullptr, 1024, 1024);

  stats_kernel<<<dim3(16, 8), 256, 0, stream>>>(Y, coeff, Q);
  select64<<<16, 256, 0, stream>>>(Q, sel);
  collapse_kernel<<<32, 256, 0, stream>>>(Y, sel, coeff, out);
}

// Round 5
// 352.994 us; speedup vs baseline: 1.7209x; 1.2029x over previous
//
#include <hip/hip_runtime.h>
#include <hip/hip_bf16.h>

#define BATCH 16
#define D3 512
#define MAXP 64
#define NPATH 512

typedef short short8 __attribute__((ext_vector_type(8)));
typedef float floatx16 __attribute__((ext_vector_type(16)));

__device__ __forceinline__ float fast_tanh(float x) {
  float e = __expf(2.f * x);
  return 1.f - 2.f / (e + 1.f);
}

__device__ __forceinline__ unsigned short f32_to_bf16_rn(float f) {
  unsigned u = __float_as_uint(f);
  u += 0x7fffu + ((u >> 16) & 1u);
  return (unsigned short)(u >> 16);
}
__device__ __forceinline__ float bf16_bits_to_f32(unsigned short s) {
  return __uint_as_float(((unsigned)s) << 16);
}

// Swizzled-layout index (in short8 units) for element block:
// matrix (R x 1024), tile (tr = r>>5, tk = k>>4), lane = ((k&15)>>3)*32 + (r&31),
// chunk covers k&7 = 0..7.  idx8 = (tr*64 + tk)*64 + lane.
__device__ __forceinline__ size_t swz_idx8(int r, int k) {
  return ((size_t)((r >> 5) * 64 + (k >> 4)) * 64) + ((k >> 3) & 1) * 32 + (r & 31);
}

// ---------------------------------------------------------------------------
// x (16,1024) row-major  ->  XT (1024,16)
__global__ void transpose_x(const float* __restrict__ x, float* __restrict__ XT) {
  int idx = blockIdx.x * 256 + threadIdx.x;     // 16384
  int i = idx >> 4, b = idx & 15;
  XT[idx] = x[b * 1024 + i];
}

// ---------------------------------------------------------------------------
// Split f32 matrix (M x 1024) into hi/lo bf16 in MFMA-fragment-swizzled order.
// One thread per 8 elements; thread t IS the (tile,lane) slot: writes are
// perfectly coalesced 16B; reads are 64B-aligned full cache lines.
__global__ __launch_bounds__(256) void split_swizzle(
    const float* __restrict__ W, unsigned short* __restrict__ Wh,
    unsigned short* __restrict__ Wl) {
  int t = blockIdx.x * 256 + threadIdx.x;
  int lane = t & 63;
  int tile = t >> 6;
  int tm = tile >> 6, tk = tile & 63;           // KT = 64 (K=1024)
  int m = tm * 32 + (lane & 31);
  int kb = tk * 16 + (lane >> 5) * 8;
  const float* src = W + (size_t)m * 1024 + kb;
  float4 v0 = *(const float4*)src;
  float4 v1 = *(const float4*)(src + 4);
  float f[8] = {v0.x, v0.y, v0.z, v0.w, v1.x, v1.y, v1.z, v1.w};
  short8 h, l;
  #pragma unroll
  for (int e = 0; e < 8; ++e) {
    unsigned short hi = f32_to_bf16_rn(f[e]);
    h[e] = (short)hi;
    l[e] = (short)f32_to_bf16_rn(f[e] - bf16_bits_to_f32(hi));
  }
  ((short8*)Wh)[t] = h;
  ((short8*)Wl)[t] = l;
}

// ---------------------------------------------------------------------------
// Sigma stage 1: one wave per output (256 blocks x 4 waves).
__global__ __launch_bounds__(256) void sigma_stage1(
    const float* __restrict__ x, const float* __restrict__ sW1,
    const float* __restrict__ sb1, float* __restrict__ h1) {
  int wv = threadIdx.x >> 6, lane = threadIdx.x & 63;
  int idx = blockIdx.x * 4 + wv;                // 0..1023
  int b = idx >> 6, u = idx & 63;
  const float* xr = x + b * 1024;
  const float* wr = sW1 + u * 1024;
  float s = 0.f;
  #pragma unroll
  for (int i = 0; i < 4; ++i) {
    int k = i * 256 + lane * 4;
    float4 xv = *(const float4*)(xr + k);
    float4 wv4 = *(const float4*)(wr + k);
    s = fmaf(xv.x, wv4.x, s); s = fmaf(xv.y, wv4.y, s);
    s = fmaf(xv.z, wv4.z, s); s = fmaf(xv.w, wv4.w, s);
  }
  #pragma unroll
  for (int off = 32; off > 0; off >>= 1) s += __shfl_down(s, off);
  if (lane == 0) h1[b * 64 + u] = fmaxf(s + sb1[u], 0.f);
}

// ---------------------------------------------------------------------------
// Sigma stage 2: h2, sigma (tanh), coeff. One block of 512 threads.
__global__ void sigma_stage2(const float* __restrict__ h1,
                             const float* __restrict__ sW2, const float* __restrict__ sb2,
                             const float* __restrict__ sW3, const float* __restrict__ sb3,
                             float* __restrict__ sigma_out, float* __restrict__ coeff) {
  __shared__ float lh1[BATCH * 64];
  __shared__ float h2[BATCH * 32];
  __shared__ float sg[BATCH * 16];
  int tid = threadIdx.x;                        // 512
  if (tid < BATCH * 64) lh1[tid] = h1[tid];
  if (tid + 512 < BATCH * 64) lh1[tid + 512] = h1[tid + 512];
  __syncthreads();
  {
    int b = tid >> 5, u = tid & 31;
    const float* wr = sW2 + u * 64;
    float s = sb2[u];
    #pragma unroll 8
    for (int i = 0; i < 64; ++i) s = fmaf(lh1[b * 64 + i], wr[i], s);
    h2[b * 32 + u] = fmaxf(s, 0.f);
  }
  __syncthreads();
  if (tid < 256) {
    int b = tid >> 4, u = tid & 15;
    const float* wr = sW3 + u * 32;
    float s = sb3[u];
    #pragma unroll 8
    for (int i = 0; i < 32; ++i) s = fmaf(h2[b * 32 + i], wr[i], s);
    float t = tanhf(s);
    sg[b * 16 + u] = t;
    sigma_out[b * 16 + u] = t;
  }
  __syncthreads();
  if (tid < BATCH) {
    int b = tid;
    float sw = 0.f, pw = 0.f, dw = 0.f;
    for (int i = 0; i < 5; ++i) {
      sw += sg[b * 16 + i];
      pw += sg[b * 16 + 5 + i];
      dw += sg[b * 16 + 10 + i];
    }
    sw *= 0.2f; pw *= 0.2f; dw *= 0.2f;
    float tot = fabsf(sw) + fabsf(pw) + fabsf(dw) + 1e-8f;
    coeff[b * 4 + 0] = sw / tot;
    coeff[b * 4 + 1] = pw / tot;
    coeff[b * 4 + 2] = dw / tot;
    coeff[b * 4 + 3] = (sg[b * 16 + 15] + 1.f) * 0.5f;
  }
}

// ---------------------------------------------------------------------------
// L1 f32 GEMM: W1 (8192x1024) @ XT (1024x16) -> tanh -> split-bf16, written in
// swizzled B-operand layout for the L2 MFMA GEMM (N=128 rows = k1*16+b, K=1024).
__global__ __launch_bounds__(256) void gemm_l1(
    const float* __restrict__ W1, const float* __restrict__ XT,
    unsigned short* __restrict__ X2th, unsigned short* __restrict__ X2tl) {
  __shared__ float Ast[64][33];
  __shared__ float Bs[64][16];
  const int tid = threadIdx.x;
  const int tx = tid & 15, ty = tid >> 4;       // tx: n 0..15, ty: 0..15
  const int m0 = blockIdx.x * 32;
  float acc0 = 0.f, acc1 = 0.f;
  for (int k0 = 0; k0 < 1024; k0 += 64) {
    #pragma unroll
    for (int l = 0; l < 2; ++l) {
      int idx = l * 256 + tid;                  // 0..511
      int i = idx >> 4;                         // row 0..31
      int j4 = (idx & 15) * 4;
      float4 v = *(const float4*)(W1 + (size_t)(m0 + i) * 1024 + k0 + j4);
      Ast[j4 + 0][i] = v.x; Ast[j4 + 1][i] = v.y;
      Ast[j4 + 2][i] = v.z; Ast[j4 + 3][i] = v.w;
    }
    {
      int kk = tid >> 2, j4 = (tid & 3) * 4;
      *(float4*)&Bs[kk][j4] = *(const float4*)(XT + (size_t)(k0 + kk) * 16 + j4);
    }
    __syncthreads();
    #pragma unroll
    for (int kk = 0; kk < 64; ++kk) {
      float b = Bs[kk][tx];
      acc0 = fmaf(Ast[kk][ty * 2 + 0], b, acc0);
      acc1 = fmaf(Ast[kk][ty * 2 + 1], b, acc1);
    }
    __syncthreads();
  }
  #pragma unroll
  for (int i = 0; i < 2; ++i) {
    int m = m0 + ty * 2 + i;                    // 0..8191 (k1*1024 + o1)
    float v = fast_tanh(i == 0 ? acc0 : acc1);
    unsigned short hi = f32_to_bf16_rn(v);
    unsigned short lo = f32_to_bf16_rn(v - bf16_bits_to_f32(hi));
    int Bn = ((m >> 10) << 4) + tx;             // 0..127
    int Bk = m & 1023;
    size_t o = swz_idx8(Bn, Bk) * 8 + (Bk & 7);
    X2th[o] = hi;
    X2tl[o] = lo;
  }
}

// ---------------------------------------------------------------------------
// LDS-free split-bf16 MFMA GEMM (32x32x16), operands pre-swizzled in fragment
// order. C = A.B^T.  4 waves in 2x2; wave tile = TM x TN of 32x32 tiles.
// EPI=0: outF[m*ldc + n] = v.
// EPI=1: v=tanh(v); split; write swizzled B-operand layout with
//        Bn = (m>>10)*128 + n, Bk = m&1023 (feeds the next MFMA GEMM).
template <int TM, int TN, int EPI>
__global__ __launch_bounds__(256) void mfma_gemm2(
    const unsigned short* __restrict__ Ah, const unsigned short* __restrict__ Al,
    const unsigned short* __restrict__ Bh, const unsigned short* __restrict__ Bl,
    float* __restrict__ outF, unsigned short* __restrict__ outH,
    unsigned short* __restrict__ outL, int KT, int ldc) {
  const int lane = threadIdx.x & 63, wave = threadIdx.x >> 6;
  const int wm = wave >> 1, wn = wave & 1;
  const int tmB = blockIdx.y * (2 * TM) + wm * TM;
  const int tnB = blockIdx.x * (2 * TN) + wn * TN;
  const short8* APh = (const short8*)Ah;
  const short8* APl = (const short8*)Al;
  const short8* BPh = (const short8*)Bh;
  const short8* BPl = (const short8*)Bl;

  floatx16 acc[TM][TN];
  #pragma unroll
  for (int i = 0; i < TM; ++i)
    #pragma unroll
    for (int j = 0; j < TN; ++j)
      #pragma unroll
      for (int t = 0; t < 16; ++t) acc[i][j][t] = 0.f;

  #pragma unroll 4
  for (int tk = 0; tk < KT; ++tk) {
    short8 ah[TM], al[TM], bh[TN], bl[TN];
    #pragma unroll
    for (int i = 0; i < TM; ++i) {
      size_t o = ((size_t)(tmB + i) * KT + tk) * 64 + lane;
      ah[i] = APh[o];
      al[i] = APl[o];
    }
    #pragma unroll
    for (int j = 0; j < TN; ++j) {
      size_t o = ((size_t)(tnB + j) * KT + tk) * 64 + lane;
      bh[j] = BPh[o];
      bl[j] = BPl[o];
    }
    #pragma unroll
    for (int i = 0; i < TM; ++i)
      #pragma unroll
      for (int j = 0; j < TN; ++j) {
        acc[i][j] = __builtin_amdgcn_mfma_f32_32x32x16_bf16(ah[i], bh[j], acc[i][j], 0, 0, 0);
        acc[i][j] = __builtin_amdgcn_mfma_f32_32x32x16_bf16(ah[i], bl[j], acc[i][j], 0, 0, 0);
        acc[i][j] = __builtin_amdgcn_mfma_f32_32x32x16_bf16(al[i], bh[j], acc[i][j], 0, 0, 0);
      }
  }

  // C/D layout: col = lane&31, row = (r&3) + 8*(r>>2) + 4*(lane>>5)
  const int lr = lane & 31, kh = lane >> 5;
  #pragma unroll
  for (int i = 0; i < TM; ++i)
    #pragma unroll
    for (int j = 0; j < TN; ++j)
      #pragma unroll
      for (int r = 0; r < 16; ++r) {
        int row = (r & 3) + 8 * (r >> 2) + 4 * kh;
        int m = (tmB + i) * 32 + row;
        int n = (tnB + j) * 32 + lr;
        float v = acc[i][j][r];
        if (EPI == 0) {
          outF[(size_t)m * ldc + n] = v;
        } else {
          v = fast_tanh(v);
          unsigned short hi = f32_to_bf16_rn(v);
          unsigned short lo = f32_to_bf16_rn(v - bf16_bits_to_f32(hi));
          int Bn = ((m >> 10) << 7) + n;
          int Bk = m & 1023;
          size_t o = swz_idx8(Bn, Bk) * 8 + (Bk & 7);
          outH[o] = hi;
          outL[o] = lo;
        }
      }
}

// ---------------------------------------------------------------------------
// Per-(b,path) stats over o3 (512 rows) -> quality.
__global__ void stats_kernel(const float* __restrict__ Y, const float* __restrict__ coeff,
                             float* __restrict__ Q) {
  int k3 = blockIdx.y;
  int c0 = blockIdx.x * 64;
  int cl = threadIdx.x & 63;
  int rg = threadIdx.x >> 6;
  const float* base = Y + (size_t)k3 * D3 * 1024 + c0 + cl;
  float s1 = 0.f, s2 = 0.f;
  int cnt = 0;
  for (int r = rg * 128; r < rg * 128 + 128; ++r) {
    float v = base[(size_t)r * 1024];
    s1 += v;
    s2 = fmaf(v, v, s2);
    cnt += (fabsf(v) < 0.1f);
  }
  __shared__ float ls1[256], ls2[256];
  __shared__ int lc[256];
  ls1[threadIdx.x] = s1; ls2[threadIdx.x] = s2; lc[threadIdx.x] = cnt;
  __syncthreads();
  if (threadIdx.x < 64) {
    float S1 = ls1[cl] + ls1[64 + cl] + ls1[128 + cl] + ls1[192 + cl];
    float S2 = ls2[cl] + ls2[64 + cl] + ls2[128 + cl] + ls2[192 + cl];
    int C = lc[cl] + lc[64 + cl] + lc[128 + cl] + lc[192 + cl];
    int c2 = c0 + cl;
    int b = c2 & 15, k1 = (c2 >> 4) & 7, k2 = c2 >> 7;
    float strength = sqrtf(S2);
    float sparsity = (float)C * (1.f / 512.f);
    float diversity = (S2 - S1 * S1 * (1.f / 512.f)) * (1.f / 511.f);
    float q = coeff[b * 4 + 0] * strength + coeff[b * 4 + 1] * sparsity +
              coeff[b * 4 + 2] * diversity;
    Q[b * NPATH + (k3 * 64 + k2 * 8 + k1)] = q;
  }
}

// ---------------------------------------------------------------------------
__global__ void select64(const float* __restrict__ Q, int* __restrict__ sel) {
  int b = blockIdx.x;
  __shared__ float q[NPATH];
  __shared__ int cnt;
  int tid = threadIdx.x;                        // 256
  if (tid == 0) cnt = 0;
  q[tid] = Q[b * NPATH + tid];
  q[tid + 256] = Q[b * NPATH + tid + 256];
  __syncthreads();
  for (int p = tid; p < NPATH; p += 256) {
    float qp = q[p];
    int rank = 0;
    #pragma unroll 8
    for (int j = 0; j < NPATH; ++j) {
      float qj = q[j];
      rank += (qj > qp) || (qj == qp && j < p);
    }
    if (rank < MAXP) {
      int s = atomicAdd(&cnt, 1);
      sel[b * MAXP + s] = p;
    }
  }
}

// ---------------------------------------------------------------------------
__global__ void collapse_kernel(const float* __restrict__ Y, const int* __restrict__ sel,
                                const float* __restrict__ coeff, float* __restrict__ out) {
  int idx = blockIdx.x * 256 + threadIdx.x;
  int b = idx >> 9, o3 = idx & 511;
  __shared__ int ls[MAXP];
  if (threadIdx.x < MAXP) ls[threadIdx.x] = sel[b * MAXP + threadIdx.x];
  __syncthreads();
  float sum = 0.f, best = 0.f, besta = -1.f;
  #pragma unroll 8
  for (int j = 0; j < MAXP; ++j) {
    int p = ls[j];
    int k3 = p >> 6, k2 = (p >> 3) & 7, k1 = p & 7;
    int col = k2 * 128 + k1 * 16 + b;
    float v = Y[((size_t)(k3 * D3 + o3)) * 1024 + col];
    sum += v;
    float a = fabsf(v);
    if (a > besta) { besta = a; best = v; }
  }
  float alpha = coeff[b * 4 + 3];
  out[idx] = (1.f - alpha) * (sum * (1.f / 64.f)) + alpha * best;
}

// ---------------------------------------------------------------------------
extern "C" void kernel_launch(void* const* d_in, const int* in_sizes, int n_in,
                              void* d_out, int out_size, void* d_ws, size_t ws_size,
                              hipStream_t stream) {
  const float* x   = (const float*)d_in[0];
  const float* W1  = (const float*)d_in[1];
  const float* W2  = (const float*)d_in[2];
  const float* W3  = (const float*)d_in[3];
  const float* sW1 = (const float*)d_in[4];
  const float* sb1 = (const float*)d_in[5];
  const float* sW2 = (const float*)d_in[6];
  const float* sb2 = (const float*)d_in[7];
  const float* sW3 = (const float*)d_in[8];
  const float* sb3 = (const float*)d_in[9];
  float* out = (float*)d_out;                   // 16*512 outputs + 16*16 sigma

  char* w = (char*)d_ws;
  float* XT = (float*)w;                       w += 65536;     // 1024x16 f32
  unsigned short* W2h = (unsigned short*)w;    w += 16777216;  // 8192x1024 bf16 swz
  unsigned short* W2l = (unsigned short*)w;    w += 16777216;
  unsigned short* W3h = (unsigned short*)w;    w += 8388608;   // 4096x1024 bf16 swz
  unsigned short* W3l = (unsigned short*)w;    w += 8388608;
  unsigned short* X2th = (unsigned short*)w;   w += 262144;    // 128x1024 bf16 swz
  unsigned short* X2tl = (unsigned short*)w;   w += 262144;
  unsigned short* X3th = (unsigned short*)w;   w += 2097152;   // 1024x1024 bf16 swz
  unsigned short* X3tl = (unsigned short*)w;   w += 2097152;
  float* Y     = (float*)w;                    w += 16777216;  // 4096x1024 f32
  float* coeff = (float*)w;                    w += 256;
  float* Q     = (float*)w;                    w += 32768;
  int*   sel   = (int*)w;                      w += 4096;
  float* h1    = (float*)w;                    w += 4096;

  transpose_x<<<64, 256, 0, stream>>>(x, XT);
  sigma_stage1<<<256, 256, 0, stream>>>(x, sW1, sb1, h1);
  sigma_stage2<<<1, 512, 0, stream>>>(h1, sW2, sb2, sW3, sb3, out + 8192, coeff);

  // One-shot weight split+swizzle (memory-bound)
  split_swizzle<<<4096, 256, 0, stream>>>(W2, W2h, W2l);   // 8192x1024
  split_swizzle<<<2048, 256, 0, stream>>>(W3, W3h, W3l);   // 4096x1024

  // L1: f32 vector GEMM, M=8192, N=16 -> X2t (bf16 hi/lo, swizzled, N=128)
  gemm_l1<<<256, 256, 0, stream>>>(W1, XT, X2th, X2tl);

  // L2: MFMA, M=8192, N=128, K=1024; BM=BN=64, grid (2,128)=256 blocks
  mfma_gemm2<1, 1, 1><<<dim3(2, 128), 256, 0, stream>>>(
      W2h, W2l, X2th, X2tl, nullptr, X3th, X3tl, 64, 0);

  // L3: MFMA, M=4096, N=1024, K=1024; BM=128, BN=64, grid (16,32)=512 blocks
  mfma_gemm2<2, 1, 0><<<dim3(16, 32), 256, 0, stream>>>(
      W3h, W3l, X3th, X3tl, Y, nullptr, nullptr, 64, 1024);

  stats_kernel<<<dim3(16, 8), 256, 0, stream>>>(Y, coeff, Q);
  select64<<<16, 256, 0, stream>>>(Q, sel);
  collapse_kernel<<<32, 256, 0, stream>>>(Y, sel, coeff, out);
}

// Round 6
// 318.227 us; speedup vs baseline: 1.9089x; 1.1093x over previous
//
#include <hip/hip_runtime.h>
#include <hip/hip_bf16.h>

#define BATCH 16
#define D3 512
#define MAXP 64
#define NPATH 512

typedef short short8 __attribute__((ext_vector_type(8)));
typedef float floatx16 __attribute__((ext_vector_type(16)));

__device__ __forceinline__ float fast_tanh(float x) {
  float e = __expf(2.f * x);
  return 1.f - 2.f / (e + 1.f);
}

__device__ __forceinline__ unsigned short f32_to_bf16_rn(float f) {
  unsigned u = __float_as_uint(f);
  u += 0x7fffu + ((u >> 16) & 1u);
  return (unsigned short)(u >> 16);
}
__device__ __forceinline__ float bf16_bits_to_f32(unsigned short s) {
  return __uint_as_float(((unsigned)s) << 16);
}

// Swizzled-layout index (in short8 units): matrix (R x 1024),
// tile (tr=r>>5, tk=k>>4), lane = ((k&15)>>3)*32 + (r&31). idx8 = (tr*KT+tk)*64+lane.
__device__ __forceinline__ size_t swz_idx8(int r, int k) {
  return ((size_t)((r >> 5) * 64 + (k >> 4)) * 64) + ((k >> 3) & 1) * 32 + (r & 31);
}

// ---------------------------------------------------------------------------
__global__ void transpose_x(const float* __restrict__ x, float* __restrict__ XT) {
  int idx = blockIdx.x * 256 + threadIdx.x;     // 16384
  int i = idx >> 4, b = idx & 15;
  XT[idx] = x[b * 1024 + i];
}

// ---------------------------------------------------------------------------
// Split f32 matrix (M x 1024) into hi/lo bf16 in MFMA-fragment-swizzled order.
__global__ __launch_bounds__(256) void split_swizzle(
    const float* __restrict__ W, unsigned short* __restrict__ Wh,
    unsigned short* __restrict__ Wl) {
  int t = blockIdx.x * 256 + threadIdx.x;
  int lane = t & 63;
  int tile = t >> 6;
  int tm = tile >> 6, tk = tile & 63;           // KT = 64 (K=1024)
  int m = tm * 32 + (lane & 31);
  int kb = tk * 16 + (lane >> 5) * 8;
  const float* src = W + (size_t)m * 1024 + kb;
  float4 v0 = *(const float4*)src;
  float4 v1 = *(const float4*)(src + 4);
  float f[8] = {v0.x, v0.y, v0.z, v0.w, v1.x, v1.y, v1.z, v1.w};
  short8 h, l;
  #pragma unroll
  for (int e = 0; e < 8; ++e) {
    unsigned short hi = f32_to_bf16_rn(f[e]);
    h[e] = (short)hi;
    l[e] = (short)f32_to_bf16_rn(f[e] - bf16_bits_to_f32(hi));
  }
  ((short8*)Wh)[t] = h;
  ((short8*)Wl)[t] = l;
}

// ---------------------------------------------------------------------------
__global__ __launch_bounds__(256) void sigma_stage1(
    const float* __restrict__ x, const float* __restrict__ sW1,
    const float* __restrict__ sb1, float* __restrict__ h1) {
  int wv = threadIdx.x >> 6, lane = threadIdx.x & 63;
  int idx = blockIdx.x * 4 + wv;                // 0..1023
  int b = idx >> 6, u = idx & 63;
  const float* xr = x + b * 1024;
  const float* wr = sW1 + u * 1024;
  float s = 0.f;
  #pragma unroll
  for (int i = 0; i < 4; ++i) {
    int k = i * 256 + lane * 4;
    float4 xv = *(const float4*)(xr + k);
    float4 wv4 = *(const float4*)(wr + k);
    s = fmaf(xv.x, wv4.x, s); s = fmaf(xv.y, wv4.y, s);
    s = fmaf(xv.z, wv4.z, s); s = fmaf(xv.w, wv4.w, s);
  }
  #pragma unroll
  for (int off = 32; off > 0; off >>= 1) s += __shfl_down(s, off);
  if (lane == 0) h1[b * 64 + u] = fmaxf(s + sb1[u], 0.f);
}

// ---------------------------------------------------------------------------
__global__ void sigma_stage2(const float* __restrict__ h1,
                             const float* __restrict__ sW2, const float* __restrict__ sb2,
                             const float* __restrict__ sW3, const float* __restrict__ sb3,
                             float* __restrict__ sigma_out, float* __restrict__ coeff) {
  __shared__ float lh1[BATCH * 64];
  __shared__ float h2[BATCH * 32];
  __shared__ float sg[BATCH * 16];
  int tid = threadIdx.x;                        // 512
  if (tid < BATCH * 64) lh1[tid] = h1[tid];
  if (tid + 512 < BATCH * 64) lh1[tid + 512] = h1[tid + 512];
  __syncthreads();
  {
    int b = tid >> 5, u = tid & 31;
    const float* wr = sW2 + u * 64;
    float s = sb2[u];
    #pragma unroll 8
    for (int i = 0; i < 64; ++i) s = fmaf(lh1[b * 64 + i], wr[i], s);
    h2[b * 32 + u] = fmaxf(s, 0.f);
  }
  __syncthreads();
  if (tid < 256) {
    int b = tid >> 4, u = tid & 15;
    const float* wr = sW3 + u * 32;
    float s = sb3[u];
    #pragma unroll 8
    for (int i = 0; i < 32; ++i) s = fmaf(h2[b * 32 + i], wr[i], s);
    float t = tanhf(s);
    sg[b * 16 + u] = t;
    sigma_out[b * 16 + u] = t;
  }
  __syncthreads();
  if (tid < BATCH) {
    int b = tid;
    float sw = 0.f, pw = 0.f, dw = 0.f;
    for (int i = 0; i < 5; ++i) {
      sw += sg[b * 16 + i];
      pw += sg[b * 16 + 5 + i];
      dw += sg[b * 16 + 10 + i];
    }
    sw *= 0.2f; pw *= 0.2f; dw *= 0.2f;
    float tot = fabsf(sw) + fabsf(pw) + fabsf(dw) + 1e-8f;
    coeff[b * 4 + 0] = sw / tot;
    coeff[b * 4 + 1] = pw / tot;
    coeff[b * 4 + 2] = dw / tot;
    coeff[b * 4 + 3] = (sg[b * 16 + 15] + 1.f) * 0.5f;
  }
}

// ---------------------------------------------------------------------------
// L1 f32 GEMM: W1 (8192x1024) @ XT (1024x16) -> tanh -> split-bf16, swizzled
// B-operand layout for the L2 MFMA GEMM.
__global__ __launch_bounds__(256) void gemm_l1(
    const float* __restrict__ W1, const float* __restrict__ XT,
    unsigned short* __restrict__ X2th, unsigned short* __restrict__ X2tl) {
  __shared__ float Ast[64][33];
  __shared__ float Bs[64][16];
  const int tid = threadIdx.x;
  const int tx = tid & 15, ty = tid >> 4;       // tx: n 0..15, ty: 0..15
  const int m0 = blockIdx.x * 32;
  float acc0 = 0.f, acc1 = 0.f;
  for (int k0 = 0; k0 < 1024; k0 += 64) {
    #pragma unroll
    for (int l = 0; l < 2; ++l) {
      int idx = l * 256 + tid;                  // 0..511
      int i = idx >> 4;                         // row 0..31
      int j4 = (idx & 15) * 4;
      float4 v = *(const float4*)(W1 + (size_t)(m0 + i) * 1024 + k0 + j4);
      Ast[j4 + 0][i] = v.x; Ast[j4 + 1][i] = v.y;
      Ast[j4 + 2][i] = v.z; Ast[j4 + 3][i] = v.w;
    }
    {
      int kk = tid >> 2, j4 = (tid & 3) * 4;
      *(float4*)&Bs[kk][j4] = *(const float4*)(XT + (size_t)(k0 + kk) * 16 + j4);
    }
    __syncthreads();
    #pragma unroll
    for (int kk = 0; kk < 64; ++kk) {
      float b = Bs[kk][tx];
      acc0 = fmaf(Ast[kk][ty * 2 + 0], b, acc0);
      acc1 = fmaf(Ast[kk][ty * 2 + 1], b, acc1);
    }
    __syncthreads();
  }
  #pragma unroll
  for (int i = 0; i < 2; ++i) {
    int m = m0 + ty * 2 + i;                    // 0..8191 (k1*1024 + o1)
    float v = fast_tanh(i == 0 ? acc0 : acc1);
    unsigned short hi = f32_to_bf16_rn(v);
    unsigned short lo = f32_to_bf16_rn(v - bf16_bits_to_f32(hi));
    int Bn = ((m >> 10) << 4) + tx;             // 0..127
    int Bk = m & 1023;
    size_t o = swz_idx8(Bn, Bk) * 8 + (Bk & 7);
    X2th[o] = hi;
    X2tl[o] = lo;
  }
}

// ---------------------------------------------------------------------------
// LDS-free split-bf16 MFMA GEMM with block-level split-K.
// All 4 waves compute the SAME TM x TN tile block (TM*32 x TN*32 output),
// each over KT/4 K-tiles; chunked LDS reduction + fused epilogue.
// Operands pre-swizzled in fragment order. C = A.B^T.
// EPI=0: outF[m*ldc + n] = v.
// EPI=1: v=tanh(v); split; swizzled write Bn=(m>>10)*128+n, Bk=m&1023.
template <int TM, int TN, int EPI>
__global__ __launch_bounds__(256, 2) void mfma_gemm3(
    const unsigned short* __restrict__ Ah, const unsigned short* __restrict__ Al,
    const unsigned short* __restrict__ Bh, const unsigned short* __restrict__ Bl,
    float* __restrict__ outF, unsigned short* __restrict__ outH,
    unsigned short* __restrict__ outL, int KT, int ldc) {
  const int lane = threadIdx.x & 63, wave = threadIdx.x >> 6;
  const int tmB = blockIdx.y * TM;
  const int tnB = blockIdx.x * TN;
  const short8* APh = (const short8*)Ah;
  const short8* APl = (const short8*)Al;
  const short8* BPh = (const short8*)Bh;
  const short8* BPl = (const short8*)Bl;
  const int KT4 = KT >> 2;
  const int kt0 = wave * KT4;

  floatx16 acc[TM][TN];
  #pragma unroll
  for (int i = 0; i < TM; ++i)
    #pragma unroll
    for (int j = 0; j < TN; ++j)
      #pragma unroll
      for (int t = 0; t < 16; ++t) acc[i][j][t] = 0.f;

  #pragma unroll 2
  for (int t = 0; t < KT4; ++t) {
    int tk = kt0 + t;
    short8 ah[TM], al[TM], bh[TN], bl[TN];
    #pragma unroll
    for (int i = 0; i < TM; ++i) {
      size_t o = ((size_t)(tmB + i) * KT + tk) * 64 + lane;
      ah[i] = APh[o];
      al[i] = APl[o];
    }
    #pragma unroll
    for (int j = 0; j < TN; ++j) {
      size_t o = ((size_t)(tnB + j) * KT + tk) * 64 + lane;
      bh[j] = BPh[o];
      bl[j] = BPl[o];
    }
    #pragma unroll
    for (int i = 0; i < TM; ++i)
      #pragma unroll
      for (int j = 0; j < TN; ++j) {
        acc[i][j] = __builtin_amdgcn_mfma_f32_32x32x16_bf16(ah[i], bh[j], acc[i][j], 0, 0, 0);
        acc[i][j] = __builtin_amdgcn_mfma_f32_32x32x16_bf16(ah[i], bl[j], acc[i][j], 0, 0, 0);
        acc[i][j] = __builtin_amdgcn_mfma_f32_32x32x16_bf16(al[i], bh[j], acc[i][j], 0, 0, 0);
      }
  }

  // Chunked cross-wave reduction (one m-tile at a time) + epilogue.
  __shared__ float red[4][TN][16][64];          // 16 KiB * TN
  #pragma unroll
  for (int i = 0; i < TM; ++i) {
    if (i) __syncthreads();
    #pragma unroll
    for (int j = 0; j < TN; ++j)
      #pragma unroll
      for (int r = 0; r < 16; ++r)
        red[wave][j][r][lane] = acc[i][j][r];
    __syncthreads();
    constexpr int SLOTS = TN * 16 * 64;
    #pragma unroll
    for (int s0 = 0; s0 < SLOTS; s0 += 256) {
      int s = s0 + threadIdx.x;
      int j = s / (16 * 64);
      int r = (s >> 6) & 15;
      int l = s & 63;
      float v = red[0][j][r][l] + red[1][j][r][l] + red[2][j][r][l] + red[3][j][r][l];
      int row = (r & 3) + 8 * (r >> 2) + 4 * (l >> 5);
      int m = (tmB + i) * 32 + row;
      int n = (tnB + j) * 32 + (l & 31);
      if (EPI == 0) {
        outF[(size_t)m * ldc + n] = v;
      } else {
        v = fast_tanh(v);
        unsigned short hi = f32_to_bf16_rn(v);
        unsigned short lo = f32_to_bf16_rn(v - bf16_bits_to_f32(hi));
        int Bn = ((m >> 10) << 7) + n;
        int Bk = m & 1023;
        size_t o = swz_idx8(Bn, Bk) * 8 + (Bk & 7);
        outH[o] = hi;
        outL[o] = lo;
      }
    }
  }
}

// ---------------------------------------------------------------------------
__global__ void stats_kernel(const float* __restrict__ Y, const float* __restrict__ coeff,
                             float* __restrict__ Q) {
  int k3 = blockIdx.y;
  int c0 = blockIdx.x * 64;
  int cl = threadIdx.x & 63;
  int rg = threadIdx.x >> 6;
  const float* base = Y + (size_t)k3 * D3 * 1024 + c0 + cl;
  float s1 = 0.f, s2 = 0.f;
  int cnt = 0;
  for (int r = rg * 128; r < rg * 128 + 128; ++r) {
    float v = base[(size_t)r * 1024];
    s1 += v;
    s2 = fmaf(v, v, s2);
    cnt += (fabsf(v) < 0.1f);
  }
  __shared__ float ls1[256], ls2[256];
  __shared__ int lc[256];
  ls1[threadIdx.x] = s1; ls2[threadIdx.x] = s2; lc[threadIdx.x] = cnt;
  __syncthreads();
  if (threadIdx.x < 64) {
    float S1 = ls1[cl] + ls1[64 + cl] + ls1[128 + cl] + ls1[192 + cl];
    float S2 = ls2[cl] + ls2[64 + cl] + ls2[128 + cl] + ls2[192 + cl];
    int C = lc[cl] + lc[64 + cl] + lc[128 + cl] + lc[192 + cl];
    int c2 = c0 + cl;
    int b = c2 & 15, k1 = (c2 >> 4) & 7, k2 = c2 >> 7;
    float strength = sqrtf(S2);
    float sparsity = (float)C * (1.f / 512.f);
    float diversity = (S2 - S1 * S1 * (1.f / 512.f)) * (1.f / 511.f);
    float q = coeff[b * 4 + 0] * strength + coeff[b * 4 + 1] * sparsity +
              coeff[b * 4 + 2] * diversity;
    Q[b * NPATH + (k3 * 64 + k2 * 8 + k1)] = q;
  }
}

// ---------------------------------------------------------------------------
__global__ void select64(const float* __restrict__ Q, int* __restrict__ sel) {
  int b = blockIdx.x;
  __shared__ float q[NPATH];
  __shared__ int cnt;
  int tid = threadIdx.x;                        // 256
  if (tid == 0) cnt = 0;
  q[tid] = Q[b * NPATH + tid];
  q[tid + 256] = Q[b * NPATH + tid + 256];
  __syncthreads();
  for (int p = tid; p < NPATH; p += 256) {
    float qp = q[p];
    int rank = 0;
    #pragma unroll 8
    for (int j = 0; j < NPATH; ++j) {
      float qj = q[j];
      rank += (qj > qp) || (qj == qp && j < p);
    }
    if (rank < MAXP) {
      int s = atomicAdd(&cnt, 1);
      sel[b * MAXP + s] = p;
    }
  }
}

// ---------------------------------------------------------------------------
__global__ void collapse_kernel(const float* __restrict__ Y, const int* __restrict__ sel,
                                const float* __restrict__ coeff, float* __restrict__ out) {
  int idx = blockIdx.x * 256 + threadIdx.x;
  int b = idx >> 9, o3 = idx & 511;
  __shared__ int ls[MAXP];
  if (threadIdx.x < MAXP) ls[threadIdx.x] = sel[b * MAXP + threadIdx.x];
  __syncthreads();
  float sum = 0.f, best = 0.f, besta = -1.f;
  #pragma unroll 8
  for (int j = 0; j < MAXP; ++j) {
    int p = ls[j];
    int k3 = p >> 6, k2 = (p >> 3) & 7, k1 = p & 7;
    int col = k2 * 128 + k1 * 16 + b;
    float v = Y[((size_t)(k3 * D3 + o3)) * 1024 + col];
    sum += v;
    float a = fabsf(v);
    if (a > besta) { besta = a; best = v; }
  }
  float alpha = coeff[b * 4 + 3];
  out[idx] = (1.f - alpha) * (sum * (1.f / 64.f)) + alpha * best;
}

// ---------------------------------------------------------------------------
extern "C" void kernel_launch(void* const* d_in, const int* in_sizes, int n_in,
                              void* d_out, int out_size, void* d_ws, size_t ws_size,
                              hipStream_t stream) {
  const float* x   = (const float*)d_in[0];
  const float* W1  = (const float*)d_in[1];
  const float* W2  = (const float*)d_in[2];
  const float* W3  = (const float*)d_in[3];
  const float* sW1 = (const float*)d_in[4];
  const float* sb1 = (const float*)d_in[5];
  const float* sW2 = (const float*)d_in[6];
  const float* sb2 = (const float*)d_in[7];
  const float* sW3 = (const float*)d_in[8];
  const float* sb3 = (const float*)d_in[9];
  float* out = (float*)d_out;                   // 16*512 outputs + 16*16 sigma

  char* w = (char*)d_ws;
  float* XT = (float*)w;                       w += 65536;     // 1024x16 f32
  unsigned short* W2h = (unsigned short*)w;    w += 16777216;  // 8192x1024 bf16 swz
  unsigned short* W2l = (unsigned short*)w;    w += 16777216;
  unsigned short* W3h = (unsigned short*)w;    w += 8388608;   // 4096x1024 bf16 swz
  unsigned short* W3l = (unsigned short*)w;    w += 8388608;
  unsigned short* X2th = (unsigned short*)w;   w += 262144;    // 128x1024 bf16 swz
  unsigned short* X2tl = (unsigned short*)w;   w += 262144;
  unsigned short* X3th = (unsigned short*)w;   w += 2097152;   // 1024x1024 bf16 swz
  unsigned short* X3tl = (unsigned short*)w;   w += 2097152;
  float* Y     = (float*)w;                    w += 16777216;  // 4096x1024 f32
  float* coeff = (float*)w;                    w += 256;
  float* Q     = (float*)w;                    w += 32768;
  int*   sel   = (int*)w;                      w += 4096;
  float* h1    = (float*)w;                    w += 4096;

  transpose_x<<<64, 256, 0, stream>>>(x, XT);
  sigma_stage1<<<256, 256, 0, stream>>>(x, sW1, sb1, h1);
  sigma_stage2<<<1, 512, 0, stream>>>(h1, sW2, sb2, sW3, sb3, out + 8192, coeff);

  // One-shot weight split+swizzle (memory-bound)
  split_swizzle<<<4096, 256, 0, stream>>>(W2, W2h, W2l);   // 8192x1024
  split_swizzle<<<2048, 256, 0, stream>>>(W3, W3h, W3l);   // 4096x1024

  // L1: f32 vector GEMM, M=8192, N=16 -> X2t (bf16 hi/lo, swizzled, N=128)
  gemm_l1<<<256, 256, 0, stream>>>(W1, XT, X2th, X2tl);

  // L2: MFMA split-K, block 64x64 (TM=2,TN=2), grid (2,128)=256 blocks
  mfma_gemm3<2, 2, 1><<<dim3(2, 128), 256, 0, stream>>>(
      W2h, W2l, X2th, X2tl, nullptr, X3th, X3tl, 64, 0);

  // L3: MFMA split-K, block 128x64 (TM=4,TN=2), grid (16,32)=512 blocks
  mfma_gemm3<4, 2, 0><<<dim3(16, 32), 256, 0, stream>>>(
      W3h, W3l, X3th, X3tl, Y, nullptr, nullptr, 64, 1024);

  stats_kernel<<<dim3(16, 8), 256, 0, stream>>>(Y, coeff, Q);
  select64<<<16, 256, 0, stream>>>(Q, sel);
  collapse_kernel<<<32, 256, 0, stream>>>(Y, sel, coeff, out);
}

// Round 7
// 268.112 us; speedup vs baseline: 2.2657x; 1.1869x over previous
//
#include <hip/hip_runtime.h>
#include <hip/hip_bf16.h>

#define BATCH 16
#define D3 512
#define MAXP 64
#define NPATH 512

typedef short short8 __attribute__((ext_vector_type(8)));
typedef float floatx16 __attribute__((ext_vector_type(16)));

__device__ __forceinline__ float fast_tanh(float x) {
  float e = __expf(2.f * x);
  return 1.f - 2.f / (e + 1.f);
}

__device__ __forceinline__ unsigned short f32_to_bf16_rn(float f) {
  unsigned u = __float_as_uint(f);
  u += 0x7fffu + ((u >> 16) & 1u);
  return (unsigned short)(u >> 16);
}
__device__ __forceinline__ float bf16_bits_to_f32(unsigned short s) {
  return __uint_as_float(((unsigned)s) << 16);
}

// Swizzled-layout index (in short8 units): matrix (R x 1024),
// tile (tr=r>>5, tk=k>>4), lane = ((k&15)>>3)*32 + (r&31). idx8 = (tr*64+tk)*64+lane.
__device__ __forceinline__ size_t swz_idx8(int r, int k) {
  return ((size_t)((r >> 5) * 64 + (k >> 4)) * 64) + ((k >> 3) & 1) * 32 + (r & 31);
}

// ---------------------------------------------------------------------------
// Sigma stage 1 (one wave per h1 output) + fused x-transpose.
__global__ __launch_bounds__(256) void sigma_stage1(
    const float* __restrict__ x, const float* __restrict__ sW1,
    const float* __restrict__ sb1, float* __restrict__ h1,
    float* __restrict__ XT) {
  // fused transpose: 256 blocks x 64 elems = 16384
  if (threadIdx.x < 64) {
    int e = blockIdx.x * 64 + threadIdx.x;
    int i = e >> 4, b = e & 15;
    XT[e] = x[b * 1024 + i];
  }
  int wv = threadIdx.x >> 6, lane = threadIdx.x & 63;
  int idx = blockIdx.x * 4 + wv;                // 0..1023
  int b = idx >> 6, u = idx & 63;
  const float* xr = x + b * 1024;
  const float* wr = sW1 + u * 1024;
  float s = 0.f;
  #pragma unroll
  for (int i = 0; i < 4; ++i) {
    int k = i * 256 + lane * 4;
    float4 xv = *(const float4*)(xr + k);
    float4 wv4 = *(const float4*)(wr + k);
    s = fmaf(xv.x, wv4.x, s); s = fmaf(xv.y, wv4.y, s);
    s = fmaf(xv.z, wv4.z, s); s = fmaf(xv.w, wv4.w, s);
  }
  #pragma unroll
  for (int off = 32; off > 0; off >>= 1) s += __shfl_down(s, off);
  if (lane == 0) h1[b * 64 + u] = fmaxf(s + sb1[u], 0.f);
}

// ---------------------------------------------------------------------------
__global__ void sigma_stage2(const float* __restrict__ h1,
                             const float* __restrict__ sW2, const float* __restrict__ sb2,
                             const float* __restrict__ sW3, const float* __restrict__ sb3,
                             float* __restrict__ sigma_out, float* __restrict__ coeff) {
  __shared__ float lh1[BATCH * 64];
  __shared__ float h2[BATCH * 32];
  __shared__ float sg[BATCH * 16];
  int tid = threadIdx.x;                        // 512
  if (tid < BATCH * 64) lh1[tid] = h1[tid];
  if (tid + 512 < BATCH * 64) lh1[tid + 512] = h1[tid + 512];
  __syncthreads();
  {
    int b = tid >> 5, u = tid & 31;
    const float* wr = sW2 + u * 64;
    float s = sb2[u];
    #pragma unroll 8
    for (int i = 0; i < 64; ++i) s = fmaf(lh1[b * 64 + i], wr[i], s);
    h2[b * 32 + u] = fmaxf(s, 0.f);
  }
  __syncthreads();
  if (tid < 256) {
    int b = tid >> 4, u = tid & 15;
    const float* wr = sW3 + u * 32;
    float s = sb3[u];
    #pragma unroll 8
    for (int i = 0; i < 32; ++i) s = fmaf(h2[b * 32 + i], wr[i], s);
    float t = tanhf(s);
    sg[b * 16 + u] = t;
    sigma_out[b * 16 + u] = t;
  }
  __syncthreads();
  if (tid < BATCH) {
    int b = tid;
    float sw = 0.f, pw = 0.f, dw = 0.f;
    for (int i = 0; i < 5; ++i) {
      sw += sg[b * 16 + i];
      pw += sg[b * 16 + 5 + i];
      dw += sg[b * 16 + 10 + i];
    }
    sw *= 0.2f; pw *= 0.2f; dw *= 0.2f;
    float tot = fabsf(sw) + fabsf(pw) + fabsf(dw) + 1e-8f;
    coeff[b * 4 + 0] = sw / tot;
    coeff[b * 4 + 1] = pw / tot;
    coeff[b * 4 + 2] = dw / tot;
    coeff[b * 4 + 3] = (sg[b * 16 + 15] + 1.f) * 0.5f;
  }
}

// ---------------------------------------------------------------------------
// Split W2 (8192x1024) and W3 (4096x1024) into hi/lo bf16 swizzled — one launch.
__global__ __launch_bounds__(256) void split_swizzle2(
    const float* __restrict__ W2, unsigned short* __restrict__ W2h,
    unsigned short* __restrict__ W2l, const float* __restrict__ W3,
    unsigned short* __restrict__ W3h, unsigned short* __restrict__ W3l) {
  int bid = blockIdx.x;
  const float* W; unsigned short *Wh, *Wl; int t;
  if (bid < 4096) { W = W2; Wh = W2h; Wl = W2l; t = bid * 256 + threadIdx.x; }
  else { W = W3; Wh = W3h; Wl = W3l; t = (bid - 4096) * 256 + threadIdx.x; }
  int lane = t & 63;
  int tile = t >> 6;
  int tm = tile >> 6, tk = tile & 63;           // KT = 64
  int m = tm * 32 + (lane & 31);
  int kb = tk * 16 + (lane >> 5) * 8;
  const float* src = W + (size_t)m * 1024 + kb;
  float4 v0 = *(const float4*)src;
  float4 v1 = *(const float4*)(src + 4);
  float f[8] = {v0.x, v0.y, v0.z, v0.w, v1.x, v1.y, v1.z, v1.w};
  short8 h, l;
  #pragma unroll
  for (int e = 0; e < 8; ++e) {
    unsigned short hi = f32_to_bf16_rn(f[e]);
    h[e] = (short)hi;
    l[e] = (short)f32_to_bf16_rn(f[e] - bf16_bits_to_f32(hi));
  }
  ((short8*)Wh)[t] = h;
  ((short8*)Wl)[t] = l;
}

// ---------------------------------------------------------------------------
// L1 f32 GEMM: W1 (8192x1024) @ XT (1024x16) -> tanh -> split-bf16, swizzled
// B-operand layout for the L2 MFMA GEMM.
__global__ __launch_bounds__(256) void gemm_l1(
    const float* __restrict__ W1, const float* __restrict__ XT,
    unsigned short* __restrict__ X2th, unsigned short* __restrict__ X2tl) {
  __shared__ float Ast[64][33];
  __shared__ float Bs[64][16];
  const int tid = threadIdx.x;
  const int tx = tid & 15, ty = tid >> 4;
  const int m0 = blockIdx.x * 32;
  float acc0 = 0.f, acc1 = 0.f;
  for (int k0 = 0; k0 < 1024; k0 += 64) {
    #pragma unroll
    for (int l = 0; l < 2; ++l) {
      int idx = l * 256 + tid;
      int i = idx >> 4;
      int j4 = (idx & 15) * 4;
      float4 v = *(const float4*)(W1 + (size_t)(m0 + i) * 1024 + k0 + j4);
      Ast[j4 + 0][i] = v.x; Ast[j4 + 1][i] = v.y;
      Ast[j4 + 2][i] = v.z; Ast[j4 + 3][i] = v.w;
    }
    {
      int kk = tid >> 2, j4 = (tid & 3) * 4;
      *(float4*)&Bs[kk][j4] = *(const float4*)(XT + (size_t)(k0 + kk) * 16 + j4);
    }
    __syncthreads();
    #pragma unroll
    for (int kk = 0; kk < 64; ++kk) {
      float b = Bs[kk][tx];
      acc0 = fmaf(Ast[kk][ty * 2 + 0], b, acc0);
      acc1 = fmaf(Ast[kk][ty * 2 + 1], b, acc1);
    }
    __syncthreads();
  }
  #pragma unroll
  for (int i = 0; i < 2; ++i) {
    int m = m0 + ty * 2 + i;
    float v = fast_tanh(i == 0 ? acc0 : acc1);
    unsigned short hi = f32_to_bf16_rn(v);
    unsigned short lo = f32_to_bf16_rn(v - bf16_bits_to_f32(hi));
    int Bn = ((m >> 10) << 4) + tx;
    int Bk = m & 1023;
    size_t o = swz_idx8(Bn, Bk) * 8 + (Bk & 7);
    X2th[o] = hi;
    X2tl[o] = lo;
  }
}

// ---------------------------------------------------------------------------
// LDS-free split-bf16 MFMA GEMM: block split-K (4 waves share the output tile),
// XCD-aware flat-grid swizzle, explicit depth-1 register prefetch.
// EPI=0: outF[m*ldc+n] = v;  STATS=1 additionally accumulates per-column
//        (s1, s2, cnt|v|<0.1) block-partials into Qp1/Qp2/Qpc[part][k3][c2].
// EPI=1: v=tanh(v); split; swizzled write Bn=(m>>10)*128+n, Bk=m&1023.
template <int TM, int TN, int EPI, int STATS>
__global__ __launch_bounds__(256, 2) void mfma_gemm4(
    const unsigned short* __restrict__ Ah, const unsigned short* __restrict__ Al,
    const unsigned short* __restrict__ Bh, const unsigned short* __restrict__ Bl,
    float* __restrict__ outF, unsigned short* __restrict__ outH,
    unsigned short* __restrict__ outL,
    float* __restrict__ Qp1, float* __restrict__ Qp2, float* __restrict__ Qpc,
    int KT, int ldc, int nby) {
  const int lane = threadIdx.x & 63, wave = threadIdx.x >> 6;
  // XCD swizzle: XCD g (= bid&7, heuristic) gets a (nby/8)-by x all-bx block.
  const int g = blockIdx.x & 7, w = blockIdx.x >> 3;
  const int byPer = nby >> 3;
  const int by = g * byPer + (w % byPer);
  const int bx = w / byPer;
  const int tmB = by * TM, tnB = bx * TN;
  const short8* APh = (const short8*)Ah;
  const short8* APl = (const short8*)Al;
  const short8* BPh = (const short8*)Bh;
  const short8* BPl = (const short8*)Bl;
  const int KT4 = KT >> 2;                      // must be even
  const int kt0 = wave * KT4;

  __shared__ float red[4][TN][16][64];          // TN*16 KiB
  __shared__ float sS1[TN * 32], sS2[TN * 32], sC[TN * 32];
  if (STATS && threadIdx.x < TN * 32) {
    sS1[threadIdx.x] = 0.f; sS2[threadIdx.x] = 0.f; sC[threadIdx.x] = 0.f;
  }

  floatx16 acc[TM][TN];
  #pragma unroll
  for (int i = 0; i < TM; ++i)
    #pragma unroll
    for (int j = 0; j < TN; ++j)
      #pragma unroll
      for (int t = 0; t < 16; ++t) acc[i][j][t] = 0.f;

  short8 ah[2][TM], al[2][TM], bh[2][TN], bl[2][TN];

#define LOADSTEP(T, B) do { int tk_ = kt0 + (T); \
    _Pragma("unroll") for (int i_ = 0; i_ < TM; ++i_) { \
      size_t o_ = ((size_t)(tmB + i_) * KT + tk_) * 64 + lane; \
      ah[B][i_] = APh[o_]; al[B][i_] = APl[o_]; } \
    _Pragma("unroll") for (int j_ = 0; j_ < TN; ++j_) { \
      size_t o_ = ((size_t)(tnB + j_) * KT + tk_) * 64 + lane; \
      bh[B][j_] = BPh[o_]; bl[B][j_] = BPl[o_]; } } while (0)

#define MFMASTEP(B) do { \
    _Pragma("unroll") for (int i_ = 0; i_ < TM; ++i_) \
    _Pragma("unroll") for (int j_ = 0; j_ < TN; ++j_) { \
      acc[i_][j_] = __builtin_amdgcn_mfma_f32_32x32x16_bf16(ah[B][i_], bh[B][j_], acc[i_][j_], 0, 0, 0); \
      acc[i_][j_] = __builtin_amdgcn_mfma_f32_32x32x16_bf16(ah[B][i_], bl[B][j_], acc[i_][j_], 0, 0, 0); \
      acc[i_][j_] = __builtin_amdgcn_mfma_f32_32x32x16_bf16(al[B][i_], bh[B][j_], acc[i_][j_], 0, 0, 0); } } while (0)

  LOADSTEP(0, 0);
  for (int t = 0; t < KT4; t += 2) {
    LOADSTEP(t + 1, 1);
    MFMASTEP(0);
    if (t + 2 < KT4) LOADSTEP(t + 2, 0);
    MFMASTEP(1);
  }
#undef LOADSTEP
#undef MFMASTEP

  float st1[TN], st2[TN], stc[TN];
  #pragma unroll
  for (int j = 0; j < TN; ++j) { st1[j] = 0.f; st2[j] = 0.f; stc[j] = 0.f; }

  // Chunked cross-wave reduction + fused epilogue.
  #pragma unroll
  for (int i = 0; i < TM; ++i) {
    if (i) __syncthreads();
    #pragma unroll
    for (int j = 0; j < TN; ++j)
      #pragma unroll
      for (int r = 0; r < 16; ++r)
        red[wave][j][r][lane] = acc[i][j][r];
    __syncthreads();
    #pragma unroll
    for (int j = 0; j < TN; ++j)
      #pragma unroll
      for (int rr = 0; rr < 4; ++rr) {
        int s = rr * 256 + (int)threadIdx.x;    // 0..1023 within j-plane
        int r = (s >> 6) & 15;
        int l = s & 63;
        float v = red[0][j][r][l] + red[1][j][r][l] + red[2][j][r][l] + red[3][j][r][l];
        if (STATS) {
          st1[j] += v;
          st2[j] = fmaf(v, v, st2[j]);
          stc[j] += (fabsf(v) < 0.1f) ? 1.f : 0.f;
        }
        int row = (r & 3) + 8 * (r >> 2) + 4 * (l >> 5);
        int m = (tmB + i) * 32 + row;
        int n = (tnB + j) * 32 + (l & 31);
        if (EPI == 0) {
          outF[(size_t)m * ldc + n] = v;
        } else {
          float tv = fast_tanh(v);
          unsigned short hi = f32_to_bf16_rn(tv);
          unsigned short lo = f32_to_bf16_rn(tv - bf16_bits_to_f32(hi));
          int Bn = ((m >> 10) << 7) + n;
          int Bk = m & 1023;
          size_t o = swz_idx8(Bn, Bk) * 8 + (Bk & 7);
          outH[o] = hi;
          outL[o] = lo;
        }
      }
  }

  if (STATS) {
    int lc = threadIdx.x & 31;
    #pragma unroll
    for (int j = 0; j < TN; ++j) {
      atomicAdd(&sS1[j * 32 + lc], st1[j]);
      atomicAdd(&sS2[j * 32 + lc], st2[j]);
      atomicAdd(&sC[j * 32 + lc], stc[j]);
    }
    __syncthreads();
    if (threadIdx.x < TN * 32) {
      int m0 = tmB * 32;
      int k3 = m0 >> 9, part = (m0 >> 7) & 3;
      int c2 = tnB * 32 + (int)threadIdx.x;
      size_t qo = ((size_t)part * 8 + k3) * 1024 + c2;
      Qp1[qo] = sS1[threadIdx.x];
      Qp2[qo] = sS2[threadIdx.x];
      Qpc[qo] = sC[threadIdx.x];
    }
  }
}

// ---------------------------------------------------------------------------
// Quality from stats partials + exact top-64 SET (rank counting, jax ties).
__global__ void select64(const float* __restrict__ Qp1, const float* __restrict__ Qp2,
                         const float* __restrict__ Qpc, const float* __restrict__ coeff,
                         int* __restrict__ sel) {
  int b = blockIdx.x;
  __shared__ float q[NPATH];
  __shared__ int cnt;
  int tid = threadIdx.x;                        // 256
  if (tid == 0) cnt = 0;
  float c0 = coeff[b * 4 + 0], c1 = coeff[b * 4 + 1], c2w = coeff[b * 4 + 2];
  for (int p = tid; p < NPATH; p += 256) {
    int k3 = p >> 6, k2 = (p >> 3) & 7, k1 = p & 7;
    int c2 = k2 * 128 + k1 * 16 + b;
    float S1 = 0.f, S2 = 0.f, C = 0.f;
    #pragma unroll
    for (int part = 0; part < 4; ++part) {
      size_t qo = ((size_t)part * 8 + k3) * 1024 + c2;
      S1 += Qp1[qo]; S2 += Qp2[qo]; C += Qpc[qo];
    }
    float strength = sqrtf(S2);
    float sparsity = C * (1.f / 512.f);
    float diversity = (S2 - S1 * S1 * (1.f / 512.f)) * (1.f / 511.f);
    q[p] = c0 * strength + c1 * sparsity + c2w * diversity;
  }
  __syncthreads();
  for (int p = tid; p < NPATH; p += 256) {
    float qp = q[p];
    int rank = 0;
    #pragma unroll 8
    for (int j = 0; j < NPATH; ++j) {
      float qj = q[j];
      rank += (qj > qp) || (qj == qp && j < p);
    }
    if (rank < MAXP) {
      int s = atomicAdd(&cnt, 1);
      sel[b * MAXP + s] = p;
    }
  }
}

// ---------------------------------------------------------------------------
__global__ void collapse_kernel(const float* __restrict__ Y, const int* __restrict__ sel,
                                const float* __restrict__ coeff, float* __restrict__ out) {
  int idx = blockIdx.x * 256 + threadIdx.x;
  int b = idx >> 9, o3 = idx & 511;
  __shared__ int ls[MAXP];
  if (threadIdx.x < MAXP) ls[threadIdx.x] = sel[b * MAXP + threadIdx.x];
  __syncthreads();
  float sum = 0.f, best = 0.f, besta = -1.f;
  #pragma unroll 8
  for (int j = 0; j < MAXP; ++j) {
    int p = ls[j];
    int k3 = p >> 6, k2 = (p >> 3) & 7, k1 = p & 7;
    int col = k2 * 128 + k1 * 16 + b;
    float v = Y[((size_t)(k3 * D3 + o3)) * 1024 + col];
    sum += v;
    float a = fabsf(v);
    if (a > besta) { besta = a; best = v; }
  }
  float alpha = coeff[b * 4 + 3];
  out[idx] = (1.f - alpha) * (sum * (1.f / 64.f)) + alpha * best;
}

// ---------------------------------------------------------------------------
extern "C" void kernel_launch(void* const* d_in, const int* in_sizes, int n_in,
                              void* d_out, int out_size, void* d_ws, size_t ws_size,
                              hipStream_t stream) {
  const float* x   = (const float*)d_in[0];
  const float* W1  = (const float*)d_in[1];
  const float* W2  = (const float*)d_in[2];
  const float* W3  = (const float*)d_in[3];
  const float* sW1 = (const float*)d_in[4];
  const float* sb1 = (const float*)d_in[5];
  const float* sW2 = (const float*)d_in[6];
  const float* sb2 = (const float*)d_in[7];
  const float* sW3 = (const float*)d_in[8];
  const float* sb3 = (const float*)d_in[9];
  float* out = (float*)d_out;                   // 16*512 outputs + 16*16 sigma

  char* w = (char*)d_ws;
  float* XT = (float*)w;                       w += 65536;     // 1024x16 f32
  unsigned short* W2h = (unsigned short*)w;    w += 16777216;  // 8192x1024 bf16 swz
  unsigned short* W2l = (unsigned short*)w;    w += 16777216;
  unsigned short* W3h = (unsigned short*)w;    w += 8388608;   // 4096x1024 bf16 swz
  unsigned short* W3l = (unsigned short*)w;    w += 8388608;
  unsigned short* X2th = (unsigned short*)w;   w += 262144;    // 128x1024 bf16 swz
  unsigned short* X2tl = (unsigned short*)w;   w += 262144;
  unsigned short* X3th = (unsigned short*)w;   w += 2097152;   // 1024x1024 bf16 swz
  unsigned short* X3tl = (unsigned short*)w;   w += 2097152;
  float* Y     = (float*)w;                    w += 16777216;  // 4096x1024 f32
  float* coeff = (float*)w;                    w += 256;
  float* Qp1   = (float*)w;                    w += 131072;    // 4x8x1024 f32
  float* Qp2   = (float*)w;                    w += 131072;
  float* Qpc   = (float*)w;                    w += 131072;
  int*   sel   = (int*)w;                      w += 4096;
  float* h1    = (float*)w;                    w += 4096;

  sigma_stage1<<<256, 256, 0, stream>>>(x, sW1, sb1, h1, XT);
  sigma_stage2<<<1, 512, 0, stream>>>(h1, sW2, sb2, sW3, sb3, out + 8192, coeff);

  // One-shot weight split+swizzle (both weights, one launch)
  split_swizzle2<<<6144, 256, 0, stream>>>(W2, W2h, W2l, W3, W3h, W3l);

  // L1: f32 vector GEMM, M=8192, N=16 -> X2t (bf16 hi/lo, swizzled, N=128)
  gemm_l1<<<256, 256, 0, stream>>>(W1, XT, X2th, X2tl);

  // L2: MFMA split-K, 64x64 tile, flat 256 blocks, XCD-swizzled (nby=128)
  mfma_gemm4<2, 2, 1, 0><<<256, 256, 0, stream>>>(
      W2h, W2l, X2th, X2tl, nullptr, X3th, X3tl,
      nullptr, nullptr, nullptr, 64, 0, 128);

  // L3: MFMA split-K, 128x64 tile, flat 512 blocks, XCD-swizzled (nby=32),
  //     fused column-stats partials
  mfma_gemm4<4, 2, 0, 1><<<512, 256, 0, stream>>>(
      W3h, W3l, X3th, X3tl, Y, nullptr, nullptr,
      Qp1, Qp2, Qpc, 64, 1024, 32);

  select64<<<16, 256, 0, stream>>>(Qp1, Qp2, Qpc, coeff, sel);
  collapse_kernel<<<32, 256, 0, stream>>>(Y, sel, coeff, out);
}

// Round 8
// 244.008 us; speedup vs baseline: 2.4895x; 1.0988x over previous
//
#include <hip/hip_runtime.h>
#include <hip/hip_bf16.h>
#include <stdint.h>

#define BATCH 16
#define D3 512
#define MAXP 64
#define NPATH 512

typedef short short8 __attribute__((ext_vector_type(8)));
typedef float floatx16 __attribute__((ext_vector_type(16)));

__device__ __forceinline__ float fast_tanh(float x) {
  float e = __expf(2.f * x);
  return 1.f - 2.f / (e + 1.f);
}

__device__ __forceinline__ unsigned short f32_to_bf16_rn(float f) {
  unsigned u = __float_as_uint(f);
  u += 0x7fffu + ((u >> 16) & 1u);
  return (unsigned short)(u >> 16);
}
__device__ __forceinline__ float bf16_bits_to_f32(unsigned short s) {
  return __uint_as_float(((unsigned)s) << 16);
}

// Swizzled-layout index (in short8 units): matrix (R x 1024),
// tile (tr=r>>5, tk=k>>4), lane = ((k&15)>>3)*32 + (r&31). idx8 = (tr*64+tk)*64+lane.
__device__ __forceinline__ size_t swz_idx8(int r, int k) {
  return ((size_t)((r >> 5) * 64 + (k >> 4)) * 64) + ((k >> 3) & 1) * 32 + (r & 31);
}

// global -> LDS direct DMA, 16 B per lane; lds base wave-uniform, lane lands at +lane*16.
// CK-style addrspace handling (generic LDS ptr low 32 bits = LDS offset).
__device__ __forceinline__ void gl2lds16(const void* g, void* l) {
  auto* gp = reinterpret_cast<const __attribute__((address_space(1))) uint32_t*>(
      reinterpret_cast<uintptr_t>(g));
  auto* lp = reinterpret_cast<__attribute__((address_space(3))) uint32_t*>(
      (uint32_t)(uintptr_t)l);
  __builtin_amdgcn_global_load_lds(gp, lp, 16, 0, 0);
}

// ---------------------------------------------------------------------------
// Sigma stage 1 (one wave per h1 output) + fused x-transpose.
__global__ __launch_bounds__(256) void sigma_stage1(
    const float* __restrict__ x, const float* __restrict__ sW1,
    const float* __restrict__ sb1, float* __restrict__ h1,
    float* __restrict__ XT) {
  if (threadIdx.x < 64) {
    int e = blockIdx.x * 64 + threadIdx.x;
    int i = e >> 4, b = e & 15;
    XT[e] = x[b * 1024 + i];
  }
  int wv = threadIdx.x >> 6, lane = threadIdx.x & 63;
  int idx = blockIdx.x * 4 + wv;                // 0..1023
  int b = idx >> 6, u = idx & 63;
  const float* xr = x + b * 1024;
  const float* wr = sW1 + u * 1024;
  float s = 0.f;
  #pragma unroll
  for (int i = 0; i < 4; ++i) {
    int k = i * 256 + lane * 4;
    float4 xv = *(const float4*)(xr + k);
    float4 wv4 = *(const float4*)(wr + k);
    s = fmaf(xv.x, wv4.x, s); s = fmaf(xv.y, wv4.y, s);
    s = fmaf(xv.z, wv4.z, s); s = fmaf(xv.w, wv4.w, s);
  }
  #pragma unroll
  for (int off = 32; off > 0; off >>= 1) s += __shfl_down(s, off);
  if (lane == 0) h1[b * 64 + u] = fmaxf(s + sb1[u], 0.f);
}

// ---------------------------------------------------------------------------
__global__ void sigma_stage2(const float* __restrict__ h1,
                             const float* __restrict__ sW2, const float* __restrict__ sb2,
                             const float* __restrict__ sW3, const float* __restrict__ sb3,
                             float* __restrict__ sigma_out, float* __restrict__ coeff) {
  __shared__ float lh1[BATCH * 64];
  __shared__ float h2[BATCH * 32];
  __shared__ float sg[BATCH * 16];
  int tid = threadIdx.x;                        // 512
  if (tid < BATCH * 64) lh1[tid] = h1[tid];
  if (tid + 512 < BATCH * 64) lh1[tid + 512] = h1[tid + 512];
  __syncthreads();
  {
    int b = tid >> 5, u = tid & 31;
    const float* wr = sW2 + u * 64;
    float s = sb2[u];
    #pragma unroll 8
    for (int i = 0; i < 64; ++i) s = fmaf(lh1[b * 64 + i], wr[i], s);
    h2[b * 32 + u] = fmaxf(s, 0.f);
  }
  __syncthreads();
  if (tid < 256) {
    int b = tid >> 4, u = tid & 15;
    const float* wr = sW3 + u * 32;
    float s = sb3[u];
    #pragma unroll 8
    for (int i = 0; i < 32; ++i) s = fmaf(h2[b * 32 + i], wr[i], s);
    float t = tanhf(s);
    sg[b * 16 + u] = t;
    sigma_out[b * 16 + u] = t;
  }
  __syncthreads();
  if (tid < BATCH) {
    int b = tid;
    float sw = 0.f, pw = 0.f, dw = 0.f;
    for (int i = 0; i < 5; ++i) {
      sw += sg[b * 16 + i];
      pw += sg[b * 16 + 5 + i];
      dw += sg[b * 16 + 10 + i];
    }
    sw *= 0.2f; pw *= 0.2f; dw *= 0.2f;
    float tot = fabsf(sw) + fabsf(pw) + fabsf(dw) + 1e-8f;
    coeff[b * 4 + 0] = sw / tot;
    coeff[b * 4 + 1] = pw / tot;
    coeff[b * 4 + 2] = dw / tot;
    coeff[b * 4 + 3] = (sg[b * 16 + 15] + 1.f) * 0.5f;
  }
}

// ---------------------------------------------------------------------------
// Split W2 (8192x1024) and W3 (4096x1024) into hi/lo bf16 swizzled — one launch.
__global__ __launch_bounds__(256) void split_swizzle2(
    const float* __restrict__ W2, unsigned short* __restrict__ W2h,
    unsigned short* __restrict__ W2l, const float* __restrict__ W3,
    unsigned short* __restrict__ W3h, unsigned short* __restrict__ W3l) {
  int bid = blockIdx.x;
  const float* W; unsigned short *Wh, *Wl; int t;
  if (bid < 4096) { W = W2; Wh = W2h; Wl = W2l; t = bid * 256 + threadIdx.x; }
  else { W = W3; Wh = W3h; Wl = W3l; t = (bid - 4096) * 256 + threadIdx.x; }
  int lane = t & 63;
  int tile = t >> 6;
  int tm = tile >> 6, tk = tile & 63;           // KT = 64
  int m = tm * 32 + (lane & 31);
  int kb = tk * 16 + (lane >> 5) * 8;
  const float* src = W + (size_t)m * 1024 + kb;
  float4 v0 = *(const float4*)src;
  float4 v1 = *(const float4*)(src + 4);
  float f[8] = {v0.x, v0.y, v0.z, v0.w, v1.x, v1.y, v1.z, v1.w};
  short8 h, l;
  #pragma unroll
  for (int e = 0; e < 8; ++e) {
    unsigned short hi = f32_to_bf16_rn(f[e]);
    h[e] = (short)hi;
    l[e] = (short)f32_to_bf16_rn(f[e] - bf16_bits_to_f32(hi));
  }
  ((short8*)Wh)[t] = h;
  ((short8*)Wl)[t] = l;
}

// ---------------------------------------------------------------------------
// L1 f32 GEMM: W1 (8192x1024) @ XT (1024x16) -> tanh -> split-bf16, swizzled
// B-operand layout for the L2 MFMA GEMM.
__global__ __launch_bounds__(256) void gemm_l1(
    const float* __restrict__ W1, const float* __restrict__ XT,
    unsigned short* __restrict__ X2th, unsigned short* __restrict__ X2tl) {
  __shared__ float Ast[64][33];
  __shared__ float Bs[64][16];
  const int tid = threadIdx.x;
  const int tx = tid & 15, ty = tid >> 4;
  const int m0 = blockIdx.x * 32;
  float acc0 = 0.f, acc1 = 0.f;
  for (int k0 = 0; k0 < 1024; k0 += 64) {
    #pragma unroll
    for (int l = 0; l < 2; ++l) {
      int idx = l * 256 + tid;
      int i = idx >> 4;
      int j4 = (idx & 15) * 4;
      float4 v = *(const float4*)(W1 + (size_t)(m0 + i) * 1024 + k0 + j4);
      Ast[j4 + 0][i] = v.x; Ast[j4 + 1][i] = v.y;
      Ast[j4 + 2][i] = v.z; Ast[j4 + 3][i] = v.w;
    }
    {
      int kk = tid >> 2, j4 = (tid & 3) * 4;
      *(float4*)&Bs[kk][j4] = *(const float4*)(XT + (size_t)(k0 + kk) * 16 + j4);
    }
    __syncthreads();
    #pragma unroll
    for (int kk = 0; kk < 64; ++kk) {
      float b = Bs[kk][tx];
      acc0 = fmaf(Ast[kk][ty * 2 + 0], b, acc0);
      acc1 = fmaf(Ast[kk][ty * 2 + 1], b, acc1);
    }
    __syncthreads();
  }
  #pragma unroll
  for (int i = 0; i < 2; ++i) {
    int m = m0 + ty * 2 + i;
    float v = fast_tanh(i == 0 ? acc0 : acc1);
    unsigned short hi = f32_to_bf16_rn(v);
    unsigned short lo = f32_to_bf16_rn(v - bf16_bits_to_f32(hi));
    int Bn = ((m >> 10) << 4) + tx;
    int Bk = m & 1023;
    size_t o = swz_idx8(Bn, Bk) * 8 + (Bk & 7);
    X2th[o] = hi;
    X2tl[o] = lo;
  }
}

// ---------------------------------------------------------------------------
// L2 GEMM (R7 structure): LDS-free split-bf16 MFMA, block split-K, XCD swizzle,
// depth-1 register prefetch. EPI=1: tanh -> split -> swizzled X3t write.
template <int TM, int TN>
__global__ __launch_bounds__(256, 2) void mfma_gemm4(
    const unsigned short* __restrict__ Ah, const unsigned short* __restrict__ Al,
    const unsigned short* __restrict__ Bh, const unsigned short* __restrict__ Bl,
    unsigned short* __restrict__ outH, unsigned short* __restrict__ outL,
    int KT, int nby) {
  const int lane = threadIdx.x & 63, wave = threadIdx.x >> 6;
  const int g = blockIdx.x & 7, w = blockIdx.x >> 3;
  const int byPer = nby >> 3;
  const int by = g * byPer + (w % byPer);
  const int bx = w / byPer;
  const int tmB = by * TM, tnB = bx * TN;
  const short8* APh = (const short8*)Ah;
  const short8* APl = (const short8*)Al;
  const short8* BPh = (const short8*)Bh;
  const short8* BPl = (const short8*)Bl;
  const int KT4 = KT >> 2;
  const int kt0 = wave * KT4;

  __shared__ float red[4][TN][16][64];

  floatx16 acc[TM][TN];
  #pragma unroll
  for (int i = 0; i < TM; ++i)
    #pragma unroll
    for (int j = 0; j < TN; ++j)
      #pragma unroll
      for (int t = 0; t < 16; ++t) acc[i][j][t] = 0.f;

  short8 ah[2][TM], al[2][TM], bh[2][TN], bl[2][TN];

#define LOADSTEP(T, B) do { int tk_ = kt0 + (T); \
    _Pragma("unroll") for (int i_ = 0; i_ < TM; ++i_) { \
      size_t o_ = ((size_t)(tmB + i_) * KT + tk_) * 64 + lane; \
      ah[B][i_] = APh[o_]; al[B][i_] = APl[o_]; } \
    _Pragma("unroll") for (int j_ = 0; j_ < TN; ++j_) { \
      size_t o_ = ((size_t)(tnB + j_) * KT + tk_) * 64 + lane; \
      bh[B][j_] = BPh[o_]; bl[B][j_] = BPl[o_]; } } while (0)

#define MFMASTEP(B) do { \
    _Pragma("unroll") for (int i_ = 0; i_ < TM; ++i_) \
    _Pragma("unroll") for (int j_ = 0; j_ < TN; ++j_) { \
      acc[i_][j_] = __builtin_amdgcn_mfma_f32_32x32x16_bf16(ah[B][i_], bh[B][j_], acc[i_][j_], 0, 0, 0); \
      acc[i_][j_] = __builtin_amdgcn_mfma_f32_32x32x16_bf16(ah[B][i_], bl[B][j_], acc[i_][j_], 0, 0, 0); \
      acc[i_][j_] = __builtin_amdgcn_mfma_f32_32x32x16_bf16(al[B][i_], bh[B][j_], acc[i_][j_], 0, 0, 0); } } while (0)

  LOADSTEP(0, 0);
  for (int t = 0; t < KT4; t += 2) {
    LOADSTEP(t + 1, 1);
    MFMASTEP(0);
    if (t + 2 < KT4) LOADSTEP(t + 2, 0);
    MFMASTEP(1);
  }
#undef LOADSTEP
#undef MFMASTEP

  #pragma unroll
  for (int i = 0; i < TM; ++i) {
    if (i) __syncthreads();
    #pragma unroll
    for (int j = 0; j < TN; ++j)
      #pragma unroll
      for (int r = 0; r < 16; ++r)
        red[wave][j][r][lane] = acc[i][j][r];
    __syncthreads();
    #pragma unroll
    for (int j = 0; j < TN; ++j)
      #pragma unroll
      for (int rr = 0; rr < 4; ++rr) {
        int s = rr * 256 + (int)threadIdx.x;
        int r = (s >> 6) & 15;
        int l = s & 63;
        float v = red[0][j][r][l] + red[1][j][r][l] + red[2][j][r][l] + red[3][j][r][l];
        int row = (r & 3) + 8 * (r >> 2) + 4 * (l >> 5);
        int m = (tmB + i) * 32 + row;
        int n = (tnB + j) * 32 + (l & 31);
        float tv = fast_tanh(v);
        unsigned short hi = f32_to_bf16_rn(tv);
        unsigned short lo = f32_to_bf16_rn(tv - bf16_bits_to_f32(hi));
        int Bn = ((m >> 10) << 7) + n;
        int Bk = m & 1023;
        size_t o = swz_idx8(Bn, Bk) * 8 + (Bk & 7);
        outH[o] = hi;
        outL[o] = lo;
      }
  }
}

// ---------------------------------------------------------------------------
// L3: LDS double-buffered split-bf16 MFMA GEMM, 128x128 tile, BK=32 (2 K-tiles
// per stage), global_load_lds(16B) staging into pre-swizzled fragment order.
// 4 waves in 2x2, each owns 64x64 (2x2 of 32x32 tiles). Writes Yt[n][m]
// (transposed, 4096 rows pitch) + fused per-column stats partials Qp[by][c2].
__global__ __launch_bounds__(256, 1) void mfma_l3(
    const unsigned short* __restrict__ Ah, const unsigned short* __restrict__ Al,
    const unsigned short* __restrict__ Bh, const unsigned short* __restrict__ Bl,
    float* __restrict__ Yt,
    float* __restrict__ Qp1, float* __restrict__ Qp2, float* __restrict__ Qpc) {
  // grid 256 flat. XCD g gets by in [g*4, g*4+4), all bx.
  const int g = blockIdx.x & 7, w = blockIdx.x >> 3;
  const int by = g * 4 + (w & 3);               // 0..31  (M tiles of 128)
  const int bx = w >> 2;                        // 0..7   (N tiles of 128)
  const int lane = threadIdx.x & 63, wave = threadIdx.x >> 6;
  const int wm = wave >> 1, wn = wave & 1;
  const int lr = lane & 31, kh = lane >> 5;
  const int tmB = by * 4, tnB = bx * 4;         // in 32-tiles

  __shared__ __align__(16) short As[2][2][4][2][512];  // [buf][ktl][mt][hl][frag]
  __shared__ __align__(16) short Bs[2][2][4][2][512];  // 32 KiB each, 64 KiB total

  floatx16 acc[2][2];
  #pragma unroll
  for (int i = 0; i < 2; ++i)
    #pragma unroll
    for (int j = 0; j < 2; ++j)
      #pragma unroll
      for (int t = 0; t < 16; ++t) acc[i][j][t] = 0.f;

#define STAGE(SI) do { int buf_ = (SI) & 1, kt0_ = (SI) * 2; \
    _Pragma("unroll") for (int q_ = 0; q_ < 8; ++q_) { \
      int f_ = wave * 8 + q_; \
      int r_ = f_ & 15, hl_ = r_ & 1, mt_ = (r_ >> 1) & 3, ktl_ = r_ >> 3; \
      if (f_ < 16) { \
        const unsigned short* gb_ = (hl_ ? Al : Ah) + \
            (((size_t)(tmB + mt_) * 64 + kt0_ + ktl_) * 64 + lane) * 8; \
        gl2lds16(gb_, &As[buf_][ktl_][mt_][hl_][0]); \
      } else { \
        const unsigned short* gb_ = (hl_ ? Bl : Bh) + \
            (((size_t)(tnB + mt_) * 64 + kt0_ + ktl_) * 64 + lane) * 8; \
        gl2lds16(gb_, &Bs[buf_][ktl_][mt_][hl_][0]); \
      } } } while (0)

  STAGE(0);
  for (int s = 0; s < 32; ++s) {
    __syncthreads();                            // drains stage s loads
    if (s + 1 < 32) STAGE(s + 1);               // prefetch overlaps compute
    const int buf = s & 1;
    #pragma unroll
    for (int ktl = 0; ktl < 2; ++ktl) {
      short8 a[2][2], b[2][2];
      #pragma unroll
      for (int i = 0; i < 2; ++i) {
        a[i][0] = *(const short8*)&As[buf][ktl][wm * 2 + i][0][lane * 8];
        a[i][1] = *(const short8*)&As[buf][ktl][wm * 2 + i][1][lane * 8];
      }
      #pragma unroll
      for (int j = 0; j < 2; ++j) {
        b[j][0] = *(const short8*)&Bs[buf][ktl][wn * 2 + j][0][lane * 8];
        b[j][1] = *(const short8*)&Bs[buf][ktl][wn * 2 + j][1][lane * 8];
      }
      #pragma unroll
      for (int i = 0; i < 2; ++i)
        #pragma unroll
        for (int j = 0; j < 2; ++j) {
          acc[i][j] = __builtin_amdgcn_mfma_f32_32x32x16_bf16(a[i][0], b[j][0], acc[i][j], 0, 0, 0);
          acc[i][j] = __builtin_amdgcn_mfma_f32_32x32x16_bf16(a[i][0], b[j][1], acc[i][j], 0, 0, 0);
          acc[i][j] = __builtin_amdgcn_mfma_f32_32x32x16_bf16(a[i][1], b[j][0], acc[i][j], 0, 0, 0);
        }
    }
  }
#undef STAGE

  // Yt stores (no LDS): Yt[n*4096 + m], float4 over 4 consecutive rows.
  float st1[2] = {0.f, 0.f}, st2[2] = {0.f, 0.f}, stc[2] = {0.f, 0.f};
  #pragma unroll
  for (int i = 0; i < 2; ++i)
    #pragma unroll
    for (int j = 0; j < 2; ++j) {
      int n = (tnB + wn * 2 + j) * 32 + lr;
      int mbase = (tmB + wm * 2 + i) * 32 + 4 * kh;
      #pragma unroll
      for (int rq = 0; rq < 4; ++rq) {
        float4 v4;
        v4.x = acc[i][j][rq * 4 + 0];
        v4.y = acc[i][j][rq * 4 + 1];
        v4.z = acc[i][j][rq * 4 + 2];
        v4.w = acc[i][j][rq * 4 + 3];
        *(float4*)&Yt[(size_t)n * 4096 + mbase + rq * 8] = v4;
        #pragma unroll
        for (int e = 0; e < 4; ++e) {
          float v = (&v4.x)[e];
          st1[j] += v;
          st2[j] = fmaf(v, v, st2[j]);
          stc[j] += (fabsf(v) < 0.1f) ? 1.f : 0.f;
        }
      }
    }

  // Stats reduction: overlay arrays into the (now dead) staging LDS.
  float* sS1 = (float*)&As[0][0][0][0][0];      // 128 floats
  float* sS2 = sS1 + 128;
  float* sC = sS1 + 256;
  __syncthreads();
  if (threadIdx.x < 128) { sS1[threadIdx.x] = 0.f; sS2[threadIdx.x] = 0.f; sC[threadIdx.x] = 0.f; }
  __syncthreads();
  #pragma unroll
  for (int j = 0; j < 2; ++j) {
    int cl = wn * 64 + j * 32 + lr;
    atomicAdd(&sS1[cl], st1[j]);
    atomicAdd(&sS2[cl], st2[j]);
    atomicAdd(&sC[cl], stc[j]);
  }
  __syncthreads();
  if (threadIdx.x < 128) {
    int part = by & 3, k3 = by >> 2;
    size_t qo = ((size_t)part * 8 + k3) * 1024 + bx * 128 + threadIdx.x;
    Qp1[qo] = sS1[threadIdx.x];
    Qp2[qo] = sS2[threadIdx.x];
    Qpc[qo] = sC[threadIdx.x];
  }
}

// ---------------------------------------------------------------------------
// Quality from stats partials + exact top-64 SET (rank counting, jax ties).
__global__ void select64(const float* __restrict__ Qp1, const float* __restrict__ Qp2,
                         const float* __restrict__ Qpc, const float* __restrict__ coeff,
                         int* __restrict__ sel) {
  int b = blockIdx.x;
  __shared__ float q[NPATH];
  __shared__ int cnt;
  int tid = threadIdx.x;                        // 256
  if (tid == 0) cnt = 0;
  float c0 = coeff[b * 4 + 0], c1 = coeff[b * 4 + 1], c2w = coeff[b * 4 + 2];
  for (int p = tid; p < NPATH; p += 256) {
    int k3 = p >> 6, k2 = (p >> 3) & 7, k1 = p & 7;
    int c2 = k2 * 128 + k1 * 16 + b;
    float S1 = 0.f, S2 = 0.f, C = 0.f;
    #pragma unroll
    for (int part = 0; part < 4; ++part) {
      size_t qo = ((size_t)part * 8 + k3) * 1024 + c2;
      S1 += Qp1[qo]; S2 += Qp2[qo]; C += Qpc[qo];
    }
    float strength = sqrtf(S2);
    float sparsity = C * (1.f / 512.f);
    float diversity = (S2 - S1 * S1 * (1.f / 512.f)) * (1.f / 511.f);
    q[p] = c0 * strength + c1 * sparsity + c2w * diversity;
  }
  __syncthreads();
  for (int p = tid; p < NPATH; p += 256) {
    float qp = q[p];
    int rank = 0;
    #pragma unroll 8
    for (int j = 0; j < NPATH; ++j) {
      float qj = q[j];
      rank += (qj > qp) || (qj == qp && j < p);
    }
    if (rank < MAXP) {
      int s = atomicAdd(&cnt, 1);
      sel[b * MAXP + s] = p;
    }
  }
}

// ---------------------------------------------------------------------------
// Collapse over Yt: block = (b, o3-chunk of 64), wave handles 16 paths,
// lane = o3 within chunk -> fully coalesced 256B reads per path.
__global__ __launch_bounds__(256) void collapse2(
    const float* __restrict__ Yt, const int* __restrict__ sel,
    const float* __restrict__ coeff, float* __restrict__ out) {
  int b = blockIdx.x >> 3, chunk = blockIdx.x & 7;
  int lane = threadIdx.x & 63, wv = threadIdx.x >> 6;
  __shared__ int ls[MAXP];
  __shared__ float s_sum[4][64], s_best[4][64], s_ba[4][64];
  if (threadIdx.x < MAXP) ls[threadIdx.x] = sel[b * MAXP + threadIdx.x];
  __syncthreads();
  int o3 = chunk * 64 + lane;
  float sum = 0.f, best = 0.f, besta = -1.f;
  #pragma unroll 4
  for (int j = wv * 16; j < wv * 16 + 16; ++j) {
    int p = ls[j];
    int k3 = p >> 6, k2 = (p >> 3) & 7, k1 = p & 7;
    int col = k2 * 128 + k1 * 16 + b;
    float v = Yt[(size_t)col * 4096 + k3 * 512 + o3];
    sum += v;
    float a = fabsf(v);
    if (a > besta) { besta = a; best = v; }
  }
  s_sum[wv][lane] = sum; s_best[wv][lane] = best; s_ba[wv][lane] = besta;
  __syncthreads();
  if (threadIdx.x < 64) {
    float S = 0.f, B = 0.f, BA = -1.f;
    #pragma unroll
    for (int w = 0; w < 4; ++w) {
      S += s_sum[w][threadIdx.x];
      if (s_ba[w][threadIdx.x] > BA) { BA = s_ba[w][threadIdx.x]; B = s_best[w][threadIdx.x]; }
    }
    float alpha = coeff[b * 4 + 3];
    out[b * 512 + chunk * 64 + threadIdx.x] = (1.f - alpha) * (S * (1.f / 64.f)) + alpha * B;
  }
}

// ---------------------------------------------------------------------------
extern "C" void kernel_launch(void* const* d_in, const int* in_sizes, int n_in,
                              void* d_out, int out_size, void* d_ws, size_t ws_size,
                              hipStream_t stream) {
  const float* x   = (const float*)d_in[0];
  const float* W1  = (const float*)d_in[1];
  const float* W2  = (const float*)d_in[2];
  const float* W3  = (const float*)d_in[3];
  const float* sW1 = (const float*)d_in[4];
  const float* sb1 = (const float*)d_in[5];
  const float* sW2 = (const float*)d_in[6];
  const float* sb2 = (const float*)d_in[7];
  const float* sW3 = (const float*)d_in[8];
  const float* sb3 = (const float*)d_in[9];
  float* out = (float*)d_out;                   // 16*512 outputs + 16*16 sigma

  char* w = (char*)d_ws;
  float* XT = (float*)w;                       w += 65536;     // 1024x16 f32
  unsigned short* W2h = (unsigned short*)w;    w += 16777216;  // 8192x1024 bf16 swz
  unsigned short* W2l = (unsigned short*)w;    w += 16777216;
  unsigned short* W3h = (unsigned short*)w;    w += 8388608;   // 4096x1024 bf16 swz
  unsigned short* W3l = (unsigned short*)w;    w += 8388608;
  unsigned short* X2th = (unsigned short*)w;   w += 262144;    // 128x1024 bf16 swz
  unsigned short* X2tl = (unsigned short*)w;   w += 262144;
  unsigned short* X3th = (unsigned short*)w;   w += 2097152;   // 1024x1024 bf16 swz
  unsigned short* X3tl = (unsigned short*)w;   w += 2097152;
  float* Yt    = (float*)w;                    w += 16777216;  // 1024x4096 f32 (transposed)
  float* coeff = (float*)w;                    w += 256;
  float* Qp1   = (float*)w;                    w += 131072;    // 4x8x1024 f32
  float* Qp2   = (float*)w;                    w += 131072;
  float* Qpc   = (float*)w;                    w += 131072;
  int*   sel   = (int*)w;                      w += 4096;
  float* h1    = (float*)w;                    w += 4096;

  sigma_stage1<<<256, 256, 0, stream>>>(x, sW1, sb1, h1, XT);
  sigma_stage2<<<1, 512, 0, stream>>>(h1, sW2, sb2, sW3, sb3, out + 8192, coeff);

  // One-shot weight split+swizzle (both weights, one launch)
  split_swizzle2<<<6144, 256, 0, stream>>>(W2, W2h, W2l, W3, W3h, W3l);

  // L1: f32 vector GEMM, M=8192, N=16 -> X2t (bf16 hi/lo, swizzled, N=128)
  gemm_l1<<<256, 256, 0, stream>>>(W1, XT, X2th, X2tl);

  // L2: MFMA split-K, 64x64 tile, flat 256 blocks, XCD-swizzled (nby=128)
  mfma_gemm4<2, 2><<<256, 256, 0, stream>>>(
      W2h, W2l, X2th, X2tl, X3th, X3tl, 64, 128);

  // L3: LDS double-buffered MFMA, 128x128 tile, 256 blocks, writes Yt + stats
  mfma_l3<<<256, 256, 0, stream>>>(
      W3h, W3l, X3th, X3tl, Yt, Qp1, Qp2, Qpc);

  select64<<<16, 256, 0, stream>>>(Qp1, Qp2, Qpc, coeff, sel);
  collapse2<<<128, 256, 0, stream>>>(Yt, sel, coeff, out);
}

// Round 9
// 240.619 us; speedup vs baseline: 2.5246x; 1.0141x over previous
//
#include <hip/hip_runtime.h>
#include <hip/hip_bf16.h>
#include <stdint.h>

#define BATCH 16
#define D3 512
#define MAXP 64
#define NPATH 512

typedef short short8 __attribute__((ext_vector_type(8)));
typedef float floatx16 __attribute__((ext_vector_type(16)));
typedef unsigned short ushort4v __attribute__((ext_vector_type(4)));

__device__ __forceinline__ float fast_tanh(float x) {
  float e = __expf(2.f * x);
  return 1.f - 2.f / (e + 1.f);
}

__device__ __forceinline__ unsigned short f32_to_bf16_rn(float f) {
  unsigned u = __float_as_uint(f);
  u += 0x7fffu + ((u >> 16) & 1u);
  return (unsigned short)(u >> 16);
}
__device__ __forceinline__ float bf16_bits_to_f32(unsigned short s) {
  return __uint_as_float(((unsigned)s) << 16);
}

// Swizzled-layout index (in short8 units): matrix (R x 1024),
// tile (tr=r>>5, tk=k>>4), lane = ((k&15)>>3)*32 + (r&31). idx8 = (tr*64+tk)*64+lane.
__device__ __forceinline__ size_t swz_idx8(int r, int k) {
  return ((size_t)((r >> 5) * 64 + (k >> 4)) * 64) + ((k >> 3) & 1) * 32 + (r & 31);
}

// global -> LDS direct DMA, 16 B per lane; lds base wave-uniform, lane lands at +lane*16.
__device__ __forceinline__ void gl2lds16(const void* g, void* l) {
  auto* gp = reinterpret_cast<const __attribute__((address_space(1))) uint32_t*>(
      reinterpret_cast<uintptr_t>(g));
  auto* lp = reinterpret_cast<__attribute__((address_space(3))) uint32_t*>(
      (uint32_t)(uintptr_t)l);
  __builtin_amdgcn_global_load_lds(gp, lp, 16, 0, 0);
}

// ---------------------------------------------------------------------------
// Sigma stage 1 (one wave per h1 output) + fused x-transpose.
__global__ __launch_bounds__(256) void sigma_stage1(
    const float* __restrict__ x, const float* __restrict__ sW1,
    const float* __restrict__ sb1, float* __restrict__ h1,
    float* __restrict__ XT) {
  if (threadIdx.x < 64) {
    int e = blockIdx.x * 64 + threadIdx.x;
    int i = e >> 4, b = e & 15;
    XT[e] = x[b * 1024 + i];
  }
  int wv = threadIdx.x >> 6, lane = threadIdx.x & 63;
  int idx = blockIdx.x * 4 + wv;                // 0..1023
  int b = idx >> 6, u = idx & 63;
  const float* xr = x + b * 1024;
  const float* wr = sW1 + u * 1024;
  float s = 0.f;
  #pragma unroll
  for (int i = 0; i < 4; ++i) {
    int k = i * 256 + lane * 4;
    float4 xv = *(const float4*)(xr + k);
    float4 wv4 = *(const float4*)(wr + k);
    s = fmaf(xv.x, wv4.x, s); s = fmaf(xv.y, wv4.y, s);
    s = fmaf(xv.z, wv4.z, s); s = fmaf(xv.w, wv4.w, s);
  }
  #pragma unroll
  for (int off = 32; off > 0; off >>= 1) s += __shfl_down(s, off);
  if (lane == 0) h1[b * 64 + u] = fmaxf(s + sb1[u], 0.f);
}

// ---------------------------------------------------------------------------
__global__ void sigma_stage2(const float* __restrict__ h1,
                             const float* __restrict__ sW2, const float* __restrict__ sb2,
                             const float* __restrict__ sW3, const float* __restrict__ sb3,
                             float* __restrict__ sigma_out, float* __restrict__ coeff) {
  __shared__ float lh1[BATCH * 64];
  __shared__ float h2[BATCH * 32];
  __shared__ float sg[BATCH * 16];
  int tid = threadIdx.x;                        // 512
  if (tid < BATCH * 64) lh1[tid] = h1[tid];
  if (tid + 512 < BATCH * 64) lh1[tid + 512] = h1[tid + 512];
  __syncthreads();
  {
    int b = tid >> 5, u = tid & 31;
    const float* wr = sW2 + u * 64;
    float s = sb2[u];
    #pragma unroll 8
    for (int i = 0; i < 64; ++i) s = fmaf(lh1[b * 64 + i], wr[i], s);
    h2[b * 32 + u] = fmaxf(s, 0.f);
  }
  __syncthreads();
  if (tid < 256) {
    int b = tid >> 4, u = tid & 15;
    const float* wr = sW3 + u * 32;
    float s = sb3[u];
    #pragma unroll 8
    for (int i = 0; i < 32; ++i) s = fmaf(h2[b * 32 + i], wr[i], s);
    float t = tanhf(s);
    sg[b * 16 + u] = t;
    sigma_out[b * 16 + u] = t;
  }
  __syncthreads();
  if (tid < BATCH) {
    int b = tid;
    float sw = 0.f, pw = 0.f, dw = 0.f;
    for (int i = 0; i < 5; ++i) {
      sw += sg[b * 16 + i];
      pw += sg[b * 16 + 5 + i];
      dw += sg[b * 16 + 10 + i];
    }
    sw *= 0.2f; pw *= 0.2f; dw *= 0.2f;
    float tot = fabsf(sw) + fabsf(pw) + fabsf(dw) + 1e-8f;
    coeff[b * 4 + 0] = sw / tot;
    coeff[b * 4 + 1] = pw / tot;
    coeff[b * 4 + 2] = dw / tot;
    coeff[b * 4 + 3] = (sg[b * 16 + 15] + 1.f) * 0.5f;
  }
}

// ---------------------------------------------------------------------------
// Split W2 (8192x1024) and W3 (4096x1024) into hi/lo bf16 swizzled — one launch.
__global__ __launch_bounds__(256) void split_swizzle2(
    const float* __restrict__ W2, unsigned short* __restrict__ W2h,
    unsigned short* __restrict__ W2l, const float* __restrict__ W3,
    unsigned short* __restrict__ W3h, unsigned short* __restrict__ W3l) {
  int bid = blockIdx.x;
  const float* W; unsigned short *Wh, *Wl; int t;
  if (bid < 4096) { W = W2; Wh = W2h; Wl = W2l; t = bid * 256 + threadIdx.x; }
  else { W = W3; Wh = W3h; Wl = W3l; t = (bid - 4096) * 256 + threadIdx.x; }
  int lane = t & 63;
  int tile = t >> 6;
  int tm = tile >> 6, tk = tile & 63;           // KT = 64
  int m = tm * 32 + (lane & 31);
  int kb = tk * 16 + (lane >> 5) * 8;
  const float* src = W + (size_t)m * 1024 + kb;
  float4 v0 = *(const float4*)src;
  float4 v1 = *(const float4*)(src + 4);
  float f[8] = {v0.x, v0.y, v0.z, v0.w, v1.x, v1.y, v1.z, v1.w};
  short8 h, l;
  #pragma unroll
  for (int e = 0; e < 8; ++e) {
    unsigned short hi = f32_to_bf16_rn(f[e]);
    h[e] = (short)hi;
    l[e] = (short)f32_to_bf16_rn(f[e] - bf16_bits_to_f32(hi));
  }
  ((short8*)Wh)[t] = h;
  ((short8*)Wl)[t] = l;
}

// ---------------------------------------------------------------------------
// L1a: split-K f32 GEMM. Block = (mblk 0..63, kseg 0..3); tile 128m x 16n,
// K range 256. Thread: 8 m x 1 n via ds_read_b128. Writes f32 partials
// Xp[(kseg*16+n)*8192 + m].
__global__ __launch_bounds__(256) void gemm_l1a(
    const float* __restrict__ W1, const float* __restrict__ XT,
    float* __restrict__ Xp) {
  __shared__ float Ast[64][132];                // [k][m], pitch 132 (16B-aligned rows)
  __shared__ float Bs[64][16];
  const int tid = threadIdx.x;
  const int tx = tid & 15, ty = tid >> 4;       // tx: n, ty: m-group (8 rows)
  const int mblk = blockIdx.x >> 2, kseg = blockIdx.x & 3;
  const int m0 = mblk * 128, kb = kseg * 256;
  float acc[8] = {};
  for (int k0 = 0; k0 < 256; k0 += 64) {
    #pragma unroll
    for (int l = 0; l < 8; ++l) {
      int idx = l * 256 + tid;                  // 0..2047
      int i = idx >> 4;                         // row 0..127
      int j4 = (idx & 15) * 4;
      float4 v = *(const float4*)(W1 + (size_t)(m0 + i) * 1024 + kb + k0 + j4);
      Ast[j4 + 0][i] = v.x; Ast[j4 + 1][i] = v.y;
      Ast[j4 + 2][i] = v.z; Ast[j4 + 3][i] = v.w;
    }
    {
      int kk = tid >> 2, j4 = (tid & 3) * 4;
      *(float4*)&Bs[kk][j4] = *(const float4*)(XT + (size_t)(kb + k0 + kk) * 16 + j4);
    }
    __syncthreads();
    #pragma unroll
    for (int kk = 0; kk < 64; ++kk) {
      float b = Bs[kk][tx];
      float4 a0 = *(const float4*)&Ast[kk][ty * 8];
      float4 a1 = *(const float4*)&Ast[kk][ty * 8 + 4];
      acc[0] = fmaf(a0.x, b, acc[0]); acc[1] = fmaf(a0.y, b, acc[1]);
      acc[2] = fmaf(a0.z, b, acc[2]); acc[3] = fmaf(a0.w, b, acc[3]);
      acc[4] = fmaf(a1.x, b, acc[4]); acc[5] = fmaf(a1.y, b, acc[5]);
      acc[6] = fmaf(a1.z, b, acc[6]); acc[7] = fmaf(a1.w, b, acc[7]);
    }
    __syncthreads();
  }
  float* dst = Xp + (size_t)(kseg * 16 + tx) * 8192 + m0 + ty * 8;
  *(float4*)dst = make_float4(acc[0], acc[1], acc[2], acc[3]);
  *(float4*)(dst + 4) = make_float4(acc[4], acc[5], acc[6], acc[7]);
}

// ---------------------------------------------------------------------------
// L1b: reduce 4 K-segments + tanh + split + swizzled X2t write (N=128 rows).
__global__ __launch_bounds__(256) void gemm_l1red(
    const float* __restrict__ Xp, unsigned short* __restrict__ X2th,
    unsigned short* __restrict__ X2tl) {
  int t = blockIdx.x * 256 + threadIdx.x;       // 32768 = 16 n x 2048 m-quads
  int n = t >> 11, mq = t & 2047;
  int m0 = mq * 4;
  float4 s = make_float4(0.f, 0.f, 0.f, 0.f);
  #pragma unroll
  for (int ks = 0; ks < 4; ++ks) {
    float4 v = *(const float4*)&Xp[(size_t)(ks * 16 + n) * 8192 + m0];
    s.x += v.x; s.y += v.y; s.z += v.z; s.w += v.w;
  }
  ushort4v h, l;
  #pragma unroll
  for (int e = 0; e < 4; ++e) {
    float v = fast_tanh((&s.x)[e]);
    unsigned short hi = f32_to_bf16_rn(v);
    h[e] = hi;
    l[e] = f32_to_bf16_rn(v - bf16_bits_to_f32(hi));
  }
  int Bn = ((m0 >> 10) << 4) + n;               // k1*16 + n
  int Bk0 = m0 & 1023;
  size_t o = swz_idx8(Bn, Bk0) * 8 + (Bk0 & 7);
  *(ushort4v*)&X2th[o] = h;
  *(ushort4v*)&X2tl[o] = l;
}

// ---------------------------------------------------------------------------
// L2a: LDS double-buffered split-bf16 MFMA, 128x128 tile, split-K 4-way.
// grid 256 flat: XCD g = bid&7 gets m-tiles [g*8, g*8+8) x all 4 ksegs.
// 8 stages of BK=32. Writes f32 partials Pp[(kseg*128+n)*8192 + m].
__global__ __launch_bounds__(256, 1) void mfma_l2(
    const unsigned short* __restrict__ Ah, const unsigned short* __restrict__ Al,
    const unsigned short* __restrict__ Bh, const unsigned short* __restrict__ Bl,
    float* __restrict__ Pp) {
  const int g = blockIdx.x & 7, w = blockIdx.x >> 3;
  const int my = g * 8 + (w >> 2);              // 0..63 (m-tiles of 128)
  const int kseg = w & 3;
  const int kbase = kseg * 16;                  // in K-tiles of 16
  const int lane = threadIdx.x & 63, wave = threadIdx.x >> 6;
  const int wm = wave >> 1, wn = wave & 1;
  const int lr = lane & 31, kh = lane >> 5;
  const int tmB = my * 4;

  __shared__ __align__(16) short As[2][2][4][2][512];
  __shared__ __align__(16) short Bs[2][2][4][2][512];

  floatx16 acc[2][2];
  #pragma unroll
  for (int i = 0; i < 2; ++i)
    #pragma unroll
    for (int j = 0; j < 2; ++j)
      #pragma unroll
      for (int t = 0; t < 16; ++t) acc[i][j][t] = 0.f;

#define STAGE2(SI) do { int buf_ = (SI) & 1, kt0_ = kbase + (SI) * 2; \
    _Pragma("unroll") for (int q_ = 0; q_ < 8; ++q_) { \
      int f_ = wave * 8 + q_; \
      int r_ = f_ & 15, hl_ = r_ & 1, mt_ = (r_ >> 1) & 3, ktl_ = r_ >> 3; \
      if (f_ < 16) { \
        const unsigned short* gb_ = (hl_ ? Al : Ah) + \
            (((size_t)(tmB + mt_) * 64 + kt0_ + ktl_) * 64 + lane) * 8; \
        gl2lds16(gb_, &As[buf_][ktl_][mt_][hl_][0]); \
      } else { \
        const unsigned short* gb_ = (hl_ ? Bl : Bh) + \
            (((size_t)mt_ * 64 + kt0_ + ktl_) * 64 + lane) * 8; \
        gl2lds16(gb_, &Bs[buf_][ktl_][mt_][hl_][0]); \
      } } } while (0)

  STAGE2(0);
  for (int s = 0; s < 8; ++s) {
    __syncthreads();
    if (s + 1 < 8) STAGE2(s + 1);
    const int buf = s & 1;
    #pragma unroll
    for (int ktl = 0; ktl < 2; ++ktl) {
      short8 a[2][2], b[2][2];
      #pragma unroll
      for (int i = 0; i < 2; ++i) {
        a[i][0] = *(const short8*)&As[buf][ktl][wm * 2 + i][0][lane * 8];
        a[i][1] = *(const short8*)&As[buf][ktl][wm * 2 + i][1][lane * 8];
      }
      #pragma unroll
      for (int j = 0; j < 2; ++j) {
        b[j][0] = *(const short8*)&Bs[buf][ktl][wn * 2 + j][0][lane * 8];
        b[j][1] = *(const short8*)&Bs[buf][ktl][wn * 2 + j][1][lane * 8];
      }
      #pragma unroll
      for (int i = 0; i < 2; ++i)
        #pragma unroll
        for (int j = 0; j < 2; ++j) {
          acc[i][j] = __builtin_amdgcn_mfma_f32_32x32x16_bf16(a[i][0], b[j][0], acc[i][j], 0, 0, 0);
          acc[i][j] = __builtin_amdgcn_mfma_f32_32x32x16_bf16(a[i][0], b[j][1], acc[i][j], 0, 0, 0);
          acc[i][j] = __builtin_amdgcn_mfma_f32_32x32x16_bf16(a[i][1], b[j][0], acc[i][j], 0, 0, 0);
        }
    }
  }
#undef STAGE2

  #pragma unroll
  for (int i = 0; i < 2; ++i)
    #pragma unroll
    for (int j = 0; j < 2; ++j) {
      int n = (wn * 2 + j) * 32 + lr;
      int mbase = (tmB + wm * 2 + i) * 32 + 4 * kh;
      #pragma unroll
      for (int rq = 0; rq < 4; ++rq) {
        float4 v4;
        v4.x = acc[i][j][rq * 4 + 0];
        v4.y = acc[i][j][rq * 4 + 1];
        v4.z = acc[i][j][rq * 4 + 2];
        v4.w = acc[i][j][rq * 4 + 3];
        *(float4*)&Pp[(size_t)(kseg * 128 + n) * 8192 + mbase + rq * 8] = v4;
      }
    }
}

// ---------------------------------------------------------------------------
// L2b: reduce 4 K-segments + tanh + split + swizzled X3t write.
__global__ __launch_bounds__(256) void gemm_l2red(
    const float* __restrict__ Pp, unsigned short* __restrict__ X3th,
    unsigned short* __restrict__ X3tl) {
  int t = blockIdx.x * 256 + threadIdx.x;       // 262144 = 128 n x 2048 m-quads
  int n = t >> 11, mq = t & 2047;
  int m0 = mq * 4;
  float4 s = make_float4(0.f, 0.f, 0.f, 0.f);
  #pragma unroll
  for (int ks = 0; ks < 4; ++ks) {
    float4 v = *(const float4*)&Pp[(size_t)(ks * 128 + n) * 8192 + m0];
    s.x += v.x; s.y += v.y; s.z += v.z; s.w += v.w;
  }
  ushort4v h, l;
  #pragma unroll
  for (int e = 0; e < 4; ++e) {
    float v = fast_tanh((&s.x)[e]);
    unsigned short hi = f32_to_bf16_rn(v);
    h[e] = hi;
    l[e] = f32_to_bf16_rn(v - bf16_bits_to_f32(hi));
  }
  int Bn = ((m0 >> 10) << 7) + n;               // k2*128 + n
  int Bk0 = m0 & 1023;
  size_t o = swz_idx8(Bn, Bk0) * 8 + (Bk0 & 7);
  *(ushort4v*)&X3th[o] = h;
  *(ushort4v*)&X3tl[o] = l;
}

// ---------------------------------------------------------------------------
// L3: LDS double-buffered split-bf16 MFMA GEMM, 128x128 tile, full K.
// Writes Yt[n][m] (transposed) + fused per-column stats partials.
__global__ __launch_bounds__(256, 1) void mfma_l3(
    const unsigned short* __restrict__ Ah, const unsigned short* __restrict__ Al,
    const unsigned short* __restrict__ Bh, const unsigned short* __restrict__ Bl,
    float* __restrict__ Yt,
    float* __restrict__ Qp1, float* __restrict__ Qp2, float* __restrict__ Qpc) {
  const int g = blockIdx.x & 7, w = blockIdx.x >> 3;
  const int by = g * 4 + (w & 3);               // 0..31
  const int bx = w >> 2;                        // 0..7
  const int lane = threadIdx.x & 63, wave = threadIdx.x >> 6;
  const int wm = wave >> 1, wn = wave & 1;
  const int lr = lane & 31, kh = lane >> 5;
  const int tmB = by * 4, tnB = bx * 4;

  __shared__ __align__(16) short As[2][2][4][2][512];
  __shared__ __align__(16) short Bs[2][2][4][2][512];

  floatx16 acc[2][2];
  #pragma unroll
  for (int i = 0; i < 2; ++i)
    #pragma unroll
    for (int j = 0; j < 2; ++j)
      #pragma unroll
      for (int t = 0; t < 16; ++t) acc[i][j][t] = 0.f;

#define STAGE(SI) do { int buf_ = (SI) & 1, kt0_ = (SI) * 2; \
    _Pragma("unroll") for (int q_ = 0; q_ < 8; ++q_) { \
      int f_ = wave * 8 + q_; \
      int r_ = f_ & 15, hl_ = r_ & 1, mt_ = (r_ >> 1) & 3, ktl_ = r_ >> 3; \
      if (f_ < 16) { \
        const unsigned short* gb_ = (hl_ ? Al : Ah) + \
            (((size_t)(tmB + mt_) * 64 + kt0_ + ktl_) * 64 + lane) * 8; \
        gl2lds16(gb_, &As[buf_][ktl_][mt_][hl_][0]); \
      } else { \
        const unsigned short* gb_ = (hl_ ? Bl : Bh) + \
            (((size_t)(tnB + mt_) * 64 + kt0_ + ktl_) * 64 + lane) * 8; \
        gl2lds16(gb_, &Bs[buf_][ktl_][mt_][hl_][0]); \
      } } } while (0)

  STAGE(0);
  for (int s = 0; s < 32; ++s) {
    __syncthreads();
    if (s + 1 < 32) STAGE(s + 1);
    const int buf = s & 1;
    #pragma unroll
    for (int ktl = 0; ktl < 2; ++ktl) {
      short8 a[2][2], b[2][2];
      #pragma unroll
      for (int i = 0; i < 2; ++i) {
        a[i][0] = *(const short8*)&As[buf][ktl][wm * 2 + i][0][lane * 8];
        a[i][1] = *(const short8*)&As[buf][ktl][wm * 2 + i][1][lane * 8];
      }
      #pragma unroll
      for (int j = 0; j < 2; ++j) {
        b[j][0] = *(const short8*)&Bs[buf][ktl][wn * 2 + j][0][lane * 8];
        b[j][1] = *(const short8*)&Bs[buf][ktl][wn * 2 + j][1][lane * 8];
      }
      #pragma unroll
      for (int i = 0; i < 2; ++i)
        #pragma unroll
        for (int j = 0; j < 2; ++j) {
          acc[i][j] = __builtin_amdgcn_mfma_f32_32x32x16_bf16(a[i][0], b[j][0], acc[i][j], 0, 0, 0);
          acc[i][j] = __builtin_amdgcn_mfma_f32_32x32x16_bf16(a[i][0], b[j][1], acc[i][j], 0, 0, 0);
          acc[i][j] = __builtin_amdgcn_mfma_f32_32x32x16_bf16(a[i][1], b[j][0], acc[i][j], 0, 0, 0);
        }
    }
  }
#undef STAGE

  float st1[2] = {0.f, 0.f}, st2[2] = {0.f, 0.f}, stc[2] = {0.f, 0.f};
  #pragma unroll
  for (int i = 0; i < 2; ++i)
    #pragma unroll
    for (int j = 0; j < 2; ++j) {
      int n = (tnB + wn * 2 + j) * 32 + lr;
      int mbase = (tmB + wm * 2 + i) * 32 + 4 * kh;
      #pragma unroll
      for (int rq = 0; rq < 4; ++rq) {
        float4 v4;
        v4.x = acc[i][j][rq * 4 + 0];
        v4.y = acc[i][j][rq * 4 + 1];
        v4.z = acc[i][j][rq * 4 + 2];
        v4.w = acc[i][j][rq * 4 + 3];
        *(float4*)&Yt[(size_t)n * 4096 + mbase + rq * 8] = v4;
        #pragma unroll
        for (int e = 0; e < 4; ++e) {
          float v = (&v4.x)[e];
          st1[j] += v;
          st2[j] = fmaf(v, v, st2[j]);
          stc[j] += (fabsf(v) < 0.1f) ? 1.f : 0.f;
        }
      }
    }

  float* sS1 = (float*)&As[0][0][0][0][0];
  float* sS2 = sS1 + 128;
  float* sC = sS1 + 256;
  __syncthreads();
  if (threadIdx.x < 128) { sS1[threadIdx.x] = 0.f; sS2[threadIdx.x] = 0.f; sC[threadIdx.x] = 0.f; }
  __syncthreads();
  #pragma unroll
  for (int j = 0; j < 2; ++j) {
    int cl = wn * 64 + j * 32 + lr;
    atomicAdd(&sS1[cl], st1[j]);
    atomicAdd(&sS2[cl], st2[j]);
    atomicAdd(&sC[cl], stc[j]);
  }
  __syncthreads();
  if (threadIdx.x < 128) {
    int part = by & 3, k3 = by >> 2;
    size_t qo = ((size_t)part * 8 + k3) * 1024 + bx * 128 + threadIdx.x;
    Qp1[qo] = sS1[threadIdx.x];
    Qp2[qo] = sS2[threadIdx.x];
    Qpc[qo] = sC[threadIdx.x];
  }
}

// ---------------------------------------------------------------------------
__global__ void select64(const float* __restrict__ Qp1, const float* __restrict__ Qp2,
                         const float* __restrict__ Qpc, const float* __restrict__ coeff,
                         int* __restrict__ sel) {
  int b = blockIdx.x;
  __shared__ float q[NPATH];
  __shared__ int cnt;
  int tid = threadIdx.x;                        // 256
  if (tid == 0) cnt = 0;
  float c0 = coeff[b * 4 + 0], c1 = coeff[b * 4 + 1], c2w = coeff[b * 4 + 2];
  for (int p = tid; p < NPATH; p += 256) {
    int k3 = p >> 6, k2 = (p >> 3) & 7, k1 = p & 7;
    int c2 = k2 * 128 + k1 * 16 + b;
    float S1 = 0.f, S2 = 0.f, C = 0.f;
    #pragma unroll
    for (int part = 0; part < 4; ++part) {
      size_t qo = ((size_t)part * 8 + k3) * 1024 + c2;
      S1 += Qp1[qo]; S2 += Qp2[qo]; C += Qpc[qo];
    }
    float strength = sqrtf(S2);
    float sparsity = C * (1.f / 512.f);
    float diversity = (S2 - S1 * S1 * (1.f / 512.f)) * (1.f / 511.f);
    q[p] = c0 * strength + c1 * sparsity + c2w * diversity;
  }
  __syncthreads();
  for (int p = tid; p < NPATH; p += 256) {
    float qp = q[p];
    int rank = 0;
    #pragma unroll 8
    for (int j = 0; j < NPATH; ++j) {
      float qj = q[j];
      rank += (qj > qp) || (qj == qp && j < p);
    }
    if (rank < MAXP) {
      int s = atomicAdd(&cnt, 1);
      sel[b * MAXP + s] = p;
    }
  }
}

// ---------------------------------------------------------------------------
__global__ __launch_bounds__(256) void collapse2(
    const float* __restrict__ Yt, const int* __restrict__ sel,
    const float* __restrict__ coeff, float* __restrict__ out) {
  int b = blockIdx.x >> 3, chunk = blockIdx.x & 7;
  int lane = threadIdx.x & 63, wv = threadIdx.x >> 6;
  __shared__ int ls[MAXP];
  __shared__ float s_sum[4][64], s_best[4][64], s_ba[4][64];
  if (threadIdx.x < MAXP) ls[threadIdx.x] = sel[b * MAXP + threadIdx.x];
  __syncthreads();
  int o3 = chunk * 64 + lane;
  float sum = 0.f, best = 0.f, besta = -1.f;
  #pragma unroll 4
  for (int j = wv * 16; j < wv * 16 + 16; ++j) {
    int p = ls[j];
    int k3 = p >> 6, k2 = (p >> 3) & 7, k1 = p & 7;
    int col = k2 * 128 + k1 * 16 + b;
    float v = Yt[(size_t)col * 4096 + k3 * 512 + o3];
    sum += v;
    float a = fabsf(v);
    if (a > besta) { besta = a; best = v; }
  }
  s_sum[wv][lane] = sum; s_best[wv][lane] = best; s_ba[wv][lane] = besta;
  __syncthreads();
  if (threadIdx.x < 64) {
    float S = 0.f, B = 0.f, BA = -1.f;
    #pragma unroll
    for (int w = 0; w < 4; ++w) {
      S += s_sum[w][threadIdx.x];
      if (s_ba[w][threadIdx.x] > BA) { BA = s_ba[w][threadIdx.x]; B = s_best[w][threadIdx.x]; }
    }
    float alpha = coeff[b * 4 + 3];
    out[b * 512 + chunk * 64 + threadIdx.x] = (1.f - alpha) * (S * (1.f / 64.f)) + alpha * B;
  }
}

// ---------------------------------------------------------------------------
extern "C" void kernel_launch(void* const* d_in, const int* in_sizes, int n_in,
                              void* d_out, int out_size, void* d_ws, size_t ws_size,
                              hipStream_t stream) {
  const float* x   = (const float*)d_in[0];
  const float* W1  = (const float*)d_in[1];
  const float* W2  = (const float*)d_in[2];
  const float* W3  = (const float*)d_in[3];
  const float* sW1 = (const float*)d_in[4];
  const float* sb1 = (const float*)d_in[5];
  const float* sW2 = (const float*)d_in[6];
  const float* sb2 = (const float*)d_in[7];
  const float* sW3 = (const float*)d_in[8];
  const float* sb3 = (const float*)d_in[9];
  float* out = (float*)d_out;                   // 16*512 outputs + 16*16 sigma

  char* w = (char*)d_ws;
  float* XT = (float*)w;                       w += 65536;     // 1024x16 f32
  unsigned short* W2h = (unsigned short*)w;    w += 16777216;  // 8192x1024 bf16 swz
  unsigned short* W2l = (unsigned short*)w;    w += 16777216;
  unsigned short* W3h = (unsigned short*)w;    w += 8388608;   // 4096x1024 bf16 swz
  unsigned short* W3l = (unsigned short*)w;    w += 8388608;
  unsigned short* X2th = (unsigned short*)w;   w += 262144;    // 128x1024 bf16 swz
  unsigned short* X2tl = (unsigned short*)w;   w += 262144;
  unsigned short* X3th = (unsigned short*)w;   w += 2097152;   // 1024x1024 bf16 swz
  unsigned short* X3tl = (unsigned short*)w;   w += 2097152;
  float* Yt    = (float*)w;                    w += 16777216;  // 1024x4096 f32 (transposed)
  float* Pp    = (float*)w;                    w += 16777216;  // 4x128x8192 f32 (L2 partials)
  float* Xp    = (float*)w;                    w += 2097152;   // 4x16x8192 f32 (L1 partials)
  float* coeff = (float*)w;                    w += 256;
  float* Qp1   = (float*)w;                    w += 131072;    // 4x8x1024 f32
  float* Qp2   = (float*)w;                    w += 131072;
  float* Qpc   = (float*)w;                    w += 131072;
  int*   sel   = (int*)w;                      w += 4096;
  float* h1    = (float*)w;                    w += 4096;

  sigma_stage1<<<256, 256, 0, stream>>>(x, sW1, sb1, h1, XT);
  sigma_stage2<<<1, 512, 0, stream>>>(h1, sW2, sb2, sW3, sb3, out + 8192, coeff);

  // One-shot weight split+swizzle (both weights, one launch)
  split_swizzle2<<<6144, 256, 0, stream>>>(W2, W2h, W2l, W3, W3h, W3l);

  // L1: split-K f32 GEMM (256 blocks) + reduce/tanh/split/swizzle
  gemm_l1a<<<256, 256, 0, stream>>>(W1, XT, Xp);
  gemm_l1red<<<128, 256, 0, stream>>>(Xp, X2th, X2tl);

  // L2: LDS-dbuf MFMA split-K (256 blocks) + reduce/tanh/split/swizzle
  mfma_l2<<<256, 256, 0, stream>>>(W2h, W2l, X2th, X2tl, Pp);
  gemm_l2red<<<1024, 256, 0, stream>>>(Pp, X3th, X3tl);

  // L3: LDS-dbuf MFMA, 128x128 tile, 256 blocks, writes Yt + stats
  mfma_l3<<<256, 256, 0, stream>>>(
      W3h, W3l, X3th, X3tl, Yt, Qp1, Qp2, Qpc);

  select64<<<16, 256, 0, stream>>>(Qp1, Qp2, Qpc, coeff, sel);
  collapse2<<<128, 256, 0, stream>>>(Yt, sel, coeff, out);
}

// Round 10
// 239.418 us; speedup vs baseline: 2.5373x; 1.0050x over previous
//
#include <hip/hip_runtime.h>
#include <hip/hip_bf16.h>
#include <stdint.h>

#define BATCH 16
#define D3 512
#define MAXP 64
#define NPATH 512

typedef short short8 __attribute__((ext_vector_type(8)));
typedef float floatx16 __attribute__((ext_vector_type(16)));
typedef unsigned short ushort4v __attribute__((ext_vector_type(4)));

__device__ __forceinline__ float fast_tanh(float x) {
  float e = __expf(2.f * x);
  return 1.f - 2.f / (e + 1.f);
}

__device__ __forceinline__ unsigned short f32_to_bf16_rn(float f) {
  unsigned u = __float_as_uint(f);
  u += 0x7fffu + ((u >> 16) & 1u);
  return (unsigned short)(u >> 16);
}
__device__ __forceinline__ float bf16_bits_to_f32(unsigned short s) {
  return __uint_as_float(((unsigned)s) << 16);
}

// Swizzled-layout index (in short8 units): matrix (R x 1024),
// tile (tr=r>>5, tk=k>>4), lane = ((k&15)>>3)*32 + (r&31). idx8 = (tr*64+tk)*64+lane.
__device__ __forceinline__ size_t swz_idx8(int r, int k) {
  return ((size_t)((r >> 5) * 64 + (k >> 4)) * 64) + ((k >> 3) & 1) * 32 + (r & 31);
}

// global -> LDS direct DMA, 16 B per lane; lds base wave-uniform, lane lands at +lane*16.
__device__ __forceinline__ void gl2lds16(const void* g, void* l) {
  auto* gp = reinterpret_cast<const __attribute__((address_space(1))) uint32_t*>(
      reinterpret_cast<uintptr_t>(g));
  auto* lp = reinterpret_cast<__attribute__((address_space(3))) uint32_t*>(
      (uint32_t)(uintptr_t)l);
  __builtin_amdgcn_global_load_lds(gp, lp, 16, 0, 0);
}

// ---------------------------------------------------------------------------
// Sigma stage 1 (one wave per h1 output) + fused x-transpose.
__global__ __launch_bounds__(256) void sigma_stage1(
    const float* __restrict__ x, const float* __restrict__ sW1,
    const float* __restrict__ sb1, float* __restrict__ h1,
    float* __restrict__ XT) {
  if (threadIdx.x < 64) {
    int e = blockIdx.x * 64 + threadIdx.x;
    int i = e >> 4, b = e & 15;
    XT[e] = x[b * 1024 + i];
  }
  int wv = threadIdx.x >> 6, lane = threadIdx.x & 63;
  int idx = blockIdx.x * 4 + wv;                // 0..1023
  int b = idx >> 6, u = idx & 63;
  const float* xr = x + b * 1024;
  const float* wr = sW1 + u * 1024;
  float s = 0.f;
  #pragma unroll
  for (int i = 0; i < 4; ++i) {
    int k = i * 256 + lane * 4;
    float4 xv = *(const float4*)(xr + k);
    float4 wv4 = *(const float4*)(wr + k);
    s = fmaf(xv.x, wv4.x, s); s = fmaf(xv.y, wv4.y, s);
    s = fmaf(xv.z, wv4.z, s); s = fmaf(xv.w, wv4.w, s);
  }
  #pragma unroll
  for (int off = 32; off > 0; off >>= 1) s += __shfl_down(s, off);
  if (lane == 0) h1[b * 64 + u] = fmaxf(s + sb1[u], 0.f);
}

// ---------------------------------------------------------------------------
__global__ void sigma_stage2(const float* __restrict__ h1,
                             const float* __restrict__ sW2, const float* __restrict__ sb2,
                             const float* __restrict__ sW3, const float* __restrict__ sb3,
                             float* __restrict__ sigma_out, float* __restrict__ coeff) {
  __shared__ float lh1[BATCH * 64];
  __shared__ float h2[BATCH * 32];
  __shared__ float sg[BATCH * 16];
  int tid = threadIdx.x;                        // 512
  if (tid < BATCH * 64) lh1[tid] = h1[tid];
  if (tid + 512 < BATCH * 64) lh1[tid + 512] = h1[tid + 512];
  __syncthreads();
  {
    int b = tid >> 5, u = tid & 31;
    const float* wr = sW2 + u * 64;
    float s = sb2[u];
    #pragma unroll 8
    for (int i = 0; i < 64; ++i) s = fmaf(lh1[b * 64 + i], wr[i], s);
    h2[b * 32 + u] = fmaxf(s, 0.f);
  }
  __syncthreads();
  if (tid < 256) {
    int b = tid >> 4, u = tid & 15;
    const float* wr = sW3 + u * 32;
    float s = sb3[u];
    #pragma unroll 8
    for (int i = 0; i < 32; ++i) s = fmaf(h2[b * 32 + i], wr[i], s);
    float t = tanhf(s);
    sg[b * 16 + u] = t;
    sigma_out[b * 16 + u] = t;
  }
  __syncthreads();
  if (tid < BATCH) {
    int b = tid;
    float sw = 0.f, pw = 0.f, dw = 0.f;
    for (int i = 0; i < 5; ++i) {
      sw += sg[b * 16 + i];
      pw += sg[b * 16 + 5 + i];
      dw += sg[b * 16 + 10 + i];
    }
    sw *= 0.2f; pw *= 0.2f; dw *= 0.2f;
    float tot = fabsf(sw) + fabsf(pw) + fabsf(dw) + 1e-8f;
    coeff[b * 4 + 0] = sw / tot;
    coeff[b * 4 + 1] = pw / tot;
    coeff[b * 4 + 2] = dw / tot;
    coeff[b * 4 + 3] = (sg[b * 16 + 15] + 1.f) * 0.5f;
  }
}

// ---------------------------------------------------------------------------
// Split W2 (8192x1024) and W3 (4096x1024) into hi/lo bf16 swizzled — one launch.
__global__ __launch_bounds__(256) void split_swizzle2(
    const float* __restrict__ W2, unsigned short* __restrict__ W2h,
    unsigned short* __restrict__ W2l, const float* __restrict__ W3,
    unsigned short* __restrict__ W3h, unsigned short* __restrict__ W3l) {
  int bid = blockIdx.x;
  const float* W; unsigned short *Wh, *Wl; int t;
  if (bid < 4096) { W = W2; Wh = W2h; Wl = W2l; t = bid * 256 + threadIdx.x; }
  else { W = W3; Wh = W3h; Wl = W3l; t = (bid - 4096) * 256 + threadIdx.x; }
  int lane = t & 63;
  int tile = t >> 6;
  int tm = tile >> 6, tk = tile & 63;           // KT = 64
  int m = tm * 32 + (lane & 31);
  int kb = tk * 16 + (lane >> 5) * 8;
  const float* src = W + (size_t)m * 1024 + kb;
  float4 v0 = *(const float4*)src;
  float4 v1 = *(const float4*)(src + 4);
  float f[8] = {v0.x, v0.y, v0.z, v0.w, v1.x, v1.y, v1.z, v1.w};
  short8 h, l;
  #pragma unroll
  for (int e = 0; e < 8; ++e) {
    unsigned short hi = f32_to_bf16_rn(f[e]);
    h[e] = (short)hi;
    l[e] = (short)f32_to_bf16_rn(f[e] - bf16_bits_to_f32(hi));
  }
  ((short8*)Wh)[t] = h;
  ((short8*)Wl)[t] = l;
}

// ---------------------------------------------------------------------------
// L1a: split-K f32 GEMM. Block = (mblk 0..63, kseg 0..3); tile 128m x 16n,
// K range 256. Writes f32 partials Xp[(kseg*16+n)*8192 + m].
__global__ __launch_bounds__(256) void gemm_l1a(
    const float* __restrict__ W1, const float* __restrict__ XT,
    float* __restrict__ Xp) {
  __shared__ float Ast[64][132];
  __shared__ float Bs[64][16];
  const int tid = threadIdx.x;
  const int tx = tid & 15, ty = tid >> 4;
  const int mblk = blockIdx.x >> 2, kseg = blockIdx.x & 3;
  const int m0 = mblk * 128, kb = kseg * 256;
  float acc[8] = {};
  for (int k0 = 0; k0 < 256; k0 += 64) {
    #pragma unroll
    for (int l = 0; l < 8; ++l) {
      int idx = l * 256 + tid;
      int i = idx >> 4;
      int j4 = (idx & 15) * 4;
      float4 v = *(const float4*)(W1 + (size_t)(m0 + i) * 1024 + kb + k0 + j4);
      Ast[j4 + 0][i] = v.x; Ast[j4 + 1][i] = v.y;
      Ast[j4 + 2][i] = v.z; Ast[j4 + 3][i] = v.w;
    }
    {
      int kk = tid >> 2, j4 = (tid & 3) * 4;
      *(float4*)&Bs[kk][j4] = *(const float4*)(XT + (size_t)(kb + k0 + kk) * 16 + j4);
    }
    __syncthreads();
    #pragma unroll
    for (int kk = 0; kk < 64; ++kk) {
      float b = Bs[kk][tx];
      float4 a0 = *(const float4*)&Ast[kk][ty * 8];
      float4 a1 = *(const float4*)&Ast[kk][ty * 8 + 4];
      acc[0] = fmaf(a0.x, b, acc[0]); acc[1] = fmaf(a0.y, b, acc[1]);
      acc[2] = fmaf(a0.z, b, acc[2]); acc[3] = fmaf(a0.w, b, acc[3]);
      acc[4] = fmaf(a1.x, b, acc[4]); acc[5] = fmaf(a1.y, b, acc[5]);
      acc[6] = fmaf(a1.z, b, acc[6]); acc[7] = fmaf(a1.w, b, acc[7]);
    }
    __syncthreads();
  }
  float* dst = Xp + (size_t)(kseg * 16 + tx) * 8192 + m0 + ty * 8;
  *(float4*)dst = make_float4(acc[0], acc[1], acc[2], acc[3]);
  *(float4*)(dst + 4) = make_float4(acc[4], acc[5], acc[6], acc[7]);
}

// ---------------------------------------------------------------------------
// L1b: reduce 4 K-segments + tanh + split + swizzled X2t write (N=128 rows).
__global__ __launch_bounds__(256) void gemm_l1red(
    const float* __restrict__ Xp, unsigned short* __restrict__ X2th,
    unsigned short* __restrict__ X2tl) {
  int t = blockIdx.x * 256 + threadIdx.x;       // 32768 = 16 n x 2048 m-quads
  int n = t >> 11, mq = t & 2047;
  int m0 = mq * 4;
  float4 s = make_float4(0.f, 0.f, 0.f, 0.f);
  #pragma unroll
  for (int ks = 0; ks < 4; ++ks) {
    float4 v = *(const float4*)&Xp[(size_t)(ks * 16 + n) * 8192 + m0];
    s.x += v.x; s.y += v.y; s.z += v.z; s.w += v.w;
  }
  ushort4v h, l;
  #pragma unroll
  for (int e = 0; e < 4; ++e) {
    float v = fast_tanh((&s.x)[e]);
    unsigned short hi = f32_to_bf16_rn(v);
    h[e] = hi;
    l[e] = f32_to_bf16_rn(v - bf16_bits_to_f32(hi));
  }
  int Bn = ((m0 >> 10) << 4) + n;               // k1*16 + n
  int Bk0 = m0 & 1023;
  size_t o = swz_idx8(Bn, Bk0) * 8 + (Bk0 & 7);
  *(ushort4v*)&X2th[o] = h;
  *(ushort4v*)&X2tl[o] = l;
}

// ---------------------------------------------------------------------------
// L2a: LDS-dbuf split-bf16 MFMA, 128x64 tile, 4-way split-K, 2 blocks/CU.
// grid 512 flat: g=bid&7 -> by = g*8+(w&7); rest=w>>3: bx=rest&1, kseg=rest>>1.
// 8 stages of BK=32. Waves 2x2; wave tile 64x32. 48 KiB LDS.
// Writes f32 partials Pp[(kseg*128+n)*8192 + m].
__global__ __launch_bounds__(256, 2) void mfma_l2(
    const unsigned short* __restrict__ Ah, const unsigned short* __restrict__ Al,
    const unsigned short* __restrict__ Bh, const unsigned short* __restrict__ Bl,
    float* __restrict__ Pp) {
  const int g = blockIdx.x & 7, w = blockIdx.x >> 3;
  const int by = g * 8 + (w & 7);               // 0..63 (m-tiles of 128)
  const int rest = w >> 3;
  const int bx = rest & 1, kseg = rest >> 1;
  const int kbase = kseg * 16;                  // in K-tiles of 16
  const int lane = threadIdx.x & 63, wave = threadIdx.x >> 6;
  const int wm = wave >> 1, wn = wave & 1;
  const int lr = lane & 31, kh = lane >> 5;

  __shared__ __align__(16) short As[2][2][4][2][512];  // 32 KiB
  __shared__ __align__(16) short Bs[2][2][2][2][512];  // 16 KiB

  floatx16 acc[2];
  #pragma unroll
  for (int i = 0; i < 2; ++i)
    #pragma unroll
    for (int t = 0; t < 16; ++t) acc[i][t] = 0.f;

#define STAGE2(SI) do { int buf_ = (SI) & 1, kt0_ = kbase + (SI) * 2; \
    _Pragma("unroll") for (int q_ = 0; q_ < 6; ++q_) { \
      int f_ = wave * 6 + q_; \
      if (f_ < 16) { \
        int hl_ = f_ & 1, mt_ = (f_ >> 1) & 3, ktl_ = f_ >> 3; \
        const unsigned short* gb_ = (hl_ ? Al : Ah) + \
            (((size_t)(by * 4 + mt_) * 64 + kt0_ + ktl_) * 64 + lane) * 8; \
        gl2lds16(gb_, &As[buf_][ktl_][mt_][hl_][0]); \
      } else { \
        int r_ = f_ - 16, hl_ = r_ & 1, nt_ = (r_ >> 1) & 1, ktl_ = r_ >> 2; \
        const unsigned short* gb_ = (hl_ ? Bl : Bh) + \
            (((size_t)(bx * 2 + nt_) * 64 + kt0_ + ktl_) * 64 + lane) * 8; \
        gl2lds16(gb_, &Bs[buf_][ktl_][nt_][hl_][0]); \
      } } } while (0)

  STAGE2(0);
  for (int s = 0; s < 8; ++s) {
    __syncthreads();
    if (s + 1 < 8) STAGE2(s + 1);
    const int buf = s & 1;
    #pragma unroll
    for (int ktl = 0; ktl < 2; ++ktl) {
      short8 a[2][2], b[2];
      #pragma unroll
      for (int i = 0; i < 2; ++i) {
        a[i][0] = *(const short8*)&As[buf][ktl][wm * 2 + i][0][lane * 8];
        a[i][1] = *(const short8*)&As[buf][ktl][wm * 2 + i][1][lane * 8];
      }
      b[0] = *(const short8*)&Bs[buf][ktl][wn][0][lane * 8];
      b[1] = *(const short8*)&Bs[buf][ktl][wn][1][lane * 8];
      #pragma unroll
      for (int i = 0; i < 2; ++i) {
        acc[i] = __builtin_amdgcn_mfma_f32_32x32x16_bf16(a[i][0], b[0], acc[i], 0, 0, 0);
        acc[i] = __builtin_amdgcn_mfma_f32_32x32x16_bf16(a[i][0], b[1], acc[i], 0, 0, 0);
        acc[i] = __builtin_amdgcn_mfma_f32_32x32x16_bf16(a[i][1], b[0], acc[i], 0, 0, 0);
      }
    }
  }
#undef STAGE2

  #pragma unroll
  for (int i = 0; i < 2; ++i) {
    int n = bx * 64 + wn * 32 + lr;
    int mbase = by * 128 + (wm * 2 + i) * 32 + 4 * kh;
    #pragma unroll
    for (int rq = 0; rq < 4; ++rq) {
      float4 v4;
      v4.x = acc[i][rq * 4 + 0];
      v4.y = acc[i][rq * 4 + 1];
      v4.z = acc[i][rq * 4 + 2];
      v4.w = acc[i][rq * 4 + 3];
      *(float4*)&Pp[(size_t)(kseg * 128 + n) * 8192 + mbase + rq * 8] = v4;
    }
  }
}

// ---------------------------------------------------------------------------
// L2b: reduce 4 K-segments + tanh + split + swizzled X3t write.
__global__ __launch_bounds__(256) void gemm_l2red(
    const float* __restrict__ Pp, unsigned short* __restrict__ X3th,
    unsigned short* __restrict__ X3tl) {
  int t = blockIdx.x * 256 + threadIdx.x;       // 262144 = 128 n x 2048 m-quads
  int n = t >> 11, mq = t & 2047;
  int m0 = mq * 4;
  float4 s = make_float4(0.f, 0.f, 0.f, 0.f);
  #pragma unroll
  for (int ks = 0; ks < 4; ++ks) {
    float4 v = *(const float4*)&Pp[(size_t)(ks * 128 + n) * 8192 + m0];
    s.x += v.x; s.y += v.y; s.z += v.z; s.w += v.w;
  }
  ushort4v h, l;
  #pragma unroll
  for (int e = 0; e < 4; ++e) {
    float v = fast_tanh((&s.x)[e]);
    unsigned short hi = f32_to_bf16_rn(v);
    h[e] = hi;
    l[e] = f32_to_bf16_rn(v - bf16_bits_to_f32(hi));
  }
  int Bn = ((m0 >> 10) << 7) + n;               // k2*128 + n
  int Bk0 = m0 & 1023;
  size_t o = swz_idx8(Bn, Bk0) * 8 + (Bk0 & 7);
  *(ushort4v*)&X3th[o] = h;
  *(ushort4v*)&X3tl[o] = l;
}

// ---------------------------------------------------------------------------
// L3: LDS-dbuf split-bf16 MFMA, 128x64 tile, full K, 2 blocks/CU.
// grid 512 flat: g=bid&7 -> by = g*4+(w&3) (0..31), bx = w>>2 (0..15).
// 32 stages of BK=32. Waves 2x2; wave tile 64x32. 48 KiB LDS.
// Writes Yt[n][m] (transposed) + fused per-column stats partials.
__global__ __launch_bounds__(256, 2) void mfma_l3(
    const unsigned short* __restrict__ Ah, const unsigned short* __restrict__ Al,
    const unsigned short* __restrict__ Bh, const unsigned short* __restrict__ Bl,
    float* __restrict__ Yt,
    float* __restrict__ Qp1, float* __restrict__ Qp2, float* __restrict__ Qpc) {
  const int g = blockIdx.x & 7, w = blockIdx.x >> 3;
  const int by = g * 4 + (w & 3);               // 0..31  (m-tiles of 128)
  const int bx = w >> 2;                        // 0..15  (n-tiles of 64)
  const int lane = threadIdx.x & 63, wave = threadIdx.x >> 6;
  const int wm = wave >> 1, wn = wave & 1;
  const int lr = lane & 31, kh = lane >> 5;

  __shared__ __align__(16) short As[2][2][4][2][512];  // 32 KiB
  __shared__ __align__(16) short Bs[2][2][2][2][512];  // 16 KiB
  __shared__ float sS1[64], sS2[64], sC[64];

  floatx16 acc[2];
  #pragma unroll
  for (int i = 0; i < 2; ++i)
    #pragma unroll
    for (int t = 0; t < 16; ++t) acc[i][t] = 0.f;

#define STAGE(SI) do { int buf_ = (SI) & 1, kt0_ = (SI) * 2; \
    _Pragma("unroll") for (int q_ = 0; q_ < 6; ++q_) { \
      int f_ = wave * 6 + q_; \
      if (f_ < 16) { \
        int hl_ = f_ & 1, mt_ = (f_ >> 1) & 3, ktl_ = f_ >> 3; \
        const unsigned short* gb_ = (hl_ ? Al : Ah) + \
            (((size_t)(by * 4 + mt_) * 64 + kt0_ + ktl_) * 64 + lane) * 8; \
        gl2lds16(gb_, &As[buf_][ktl_][mt_][hl_][0]); \
      } else { \
        int r_ = f_ - 16, hl_ = r_ & 1, nt_ = (r_ >> 1) & 1, ktl_ = r_ >> 2; \
        const unsigned short* gb_ = (hl_ ? Bl : Bh) + \
            (((size_t)(bx * 2 + nt_) * 64 + kt0_ + ktl_) * 64 + lane) * 8; \
        gl2lds16(gb_, &Bs[buf_][ktl_][nt_][hl_][0]); \
      } } } while (0)

  STAGE(0);
  for (int s = 0; s < 32; ++s) {
    __syncthreads();
    if (s + 1 < 32) STAGE(s + 1);
    const int buf = s & 1;
    #pragma unroll
    for (int ktl = 0; ktl < 2; ++ktl) {
      short8 a[2][2], b[2];
      #pragma unroll
      for (int i = 0; i < 2; ++i) {
        a[i][0] = *(const short8*)&As[buf][ktl][wm * 2 + i][0][lane * 8];
        a[i][1] = *(const short8*)&As[buf][ktl][wm * 2 + i][1][lane * 8];
      }
      b[0] = *(const short8*)&Bs[buf][ktl][wn][0][lane * 8];
      b[1] = *(const short8*)&Bs[buf][ktl][wn][1][lane * 8];
      #pragma unroll
      for (int i = 0; i < 2; ++i) {
        acc[i] = __builtin_amdgcn_mfma_f32_32x32x16_bf16(a[i][0], b[0], acc[i], 0, 0, 0);
        acc[i] = __builtin_amdgcn_mfma_f32_32x32x16_bf16(a[i][0], b[1], acc[i], 0, 0, 0);
        acc[i] = __builtin_amdgcn_mfma_f32_32x32x16_bf16(a[i][1], b[0], acc[i], 0, 0, 0);
      }
    }
  }
#undef STAGE

  // Epilogue: Yt[n*4096+m] float4 stores + per-column stats.
  float st1 = 0.f, st2 = 0.f, stc = 0.f;
  int n = bx * 64 + wn * 32 + lr;
  #pragma unroll
  for (int i = 0; i < 2; ++i) {
    int mbase = by * 128 + (wm * 2 + i) * 32 + 4 * kh;
    #pragma unroll
    for (int rq = 0; rq < 4; ++rq) {
      float4 v4;
      v4.x = acc[i][rq * 4 + 0];
      v4.y = acc[i][rq * 4 + 1];
      v4.z = acc[i][rq * 4 + 2];
      v4.w = acc[i][rq * 4 + 3];
      *(float4*)&Yt[(size_t)n * 4096 + mbase + rq * 8] = v4;
      #pragma unroll
      for (int e = 0; e < 4; ++e) {
        float v = (&v4.x)[e];
        st1 += v;
        st2 = fmaf(v, v, st2);
        stc += (fabsf(v) < 0.1f) ? 1.f : 0.f;
      }
    }
  }
  __syncthreads();
  if (threadIdx.x < 64) { sS1[threadIdx.x] = 0.f; sS2[threadIdx.x] = 0.f; sC[threadIdx.x] = 0.f; }
  __syncthreads();
  {
    int cl = wn * 32 + lr;
    atomicAdd(&sS1[cl], st1);
    atomicAdd(&sS2[cl], st2);
    atomicAdd(&sC[cl], stc);
  }
  __syncthreads();
  if (threadIdx.x < 64) {
    int part = by & 3, k3 = by >> 2;
    size_t qo = ((size_t)part * 8 + k3) * 1024 + bx * 64 + threadIdx.x;
    Qp1[qo] = sS1[threadIdx.x];
    Qp2[qo] = sS2[threadIdx.x];
    Qpc[qo] = sC[threadIdx.x];
  }
}

// ---------------------------------------------------------------------------
__global__ void select64(const float* __restrict__ Qp1, const float* __restrict__ Qp2,
                         const float* __restrict__ Qpc, const float* __restrict__ coeff,
                         int* __restrict__ sel) {
  int b = blockIdx.x;
  __shared__ float q[NPATH];
  __shared__ int cnt;
  int tid = threadIdx.x;                        // 256
  if (tid == 0) cnt = 0;
  float c0 = coeff[b * 4 + 0], c1 = coeff[b * 4 + 1], c2w = coeff[b * 4 + 2];
  for (int p = tid; p < NPATH; p += 256) {
    int k3 = p >> 6, k2 = (p >> 3) & 7, k1 = p & 7;
    int c2 = k2 * 128 + k1 * 16 + b;
    float S1 = 0.f, S2 = 0.f, C = 0.f;
    #pragma unroll
    for (int part = 0; part < 4; ++part) {
      size_t qo = ((size_t)part * 8 + k3) * 1024 + c2;
      S1 += Qp1[qo]; S2 += Qp2[qo]; C += Qpc[qo];
    }
    float strength = sqrtf(S2);
    float sparsity = C * (1.f / 512.f);
    float diversity = (S2 - S1 * S1 * (1.f / 512.f)) * (1.f / 511.f);
    q[p] = c0 * strength + c1 * sparsity + c2w * diversity;
  }
  __syncthreads();
  for (int p = tid; p < NPATH; p += 256) {
    float qp = q[p];
    int rank = 0;
    #pragma unroll 8
    for (int j = 0; j < NPATH; ++j) {
      float qj = q[j];
      rank += (qj > qp) || (qj == qp && j < p);
    }
    if (rank < MAXP) {
      int s = atomicAdd(&cnt, 1);
      sel[b * MAXP + s] = p;
    }
  }
}

// ---------------------------------------------------------------------------
__global__ __launch_bounds__(256) void collapse2(
    const float* __restrict__ Yt, const int* __restrict__ sel,
    const float* __restrict__ coeff, float* __restrict__ out) {
  int b = blockIdx.x >> 3, chunk = blockIdx.x & 7;
  int lane = threadIdx.x & 63, wv = threadIdx.x >> 6;
  __shared__ int ls[MAXP];
  __shared__ float s_sum[4][64], s_best[4][64], s_ba[4][64];
  if (threadIdx.x < MAXP) ls[threadIdx.x] = sel[b * MAXP + threadIdx.x];
  __syncthreads();
  int o3 = chunk * 64 + lane;
  float sum = 0.f, best = 0.f, besta = -1.f;
  #pragma unroll 4
  for (int j = wv * 16; j < wv * 16 + 16; ++j) {
    int p = ls[j];
    int k3 = p >> 6, k2 = (p >> 3) & 7, k1 = p & 7;
    int col = k2 * 128 + k1 * 16 + b;
    float v = Yt[(size_t)col * 4096 + k3 * 512 + o3];
    sum += v;
    float a = fabsf(v);
    if (a > besta) { besta = a; best = v; }
  }
  s_sum[wv][lane] = sum; s_best[wv][lane] = best; s_ba[wv][lane] = besta;
  __syncthreads();
  if (threadIdx.x < 64) {
    float S = 0.f, B = 0.f, BA = -1.f;
    #pragma unroll
    for (int w = 0; w < 4; ++w) {
      S += s_sum[w][threadIdx.x];
      if (s_ba[w][threadIdx.x] > BA) { BA = s_ba[w][threadIdx.x]; B = s_best[w][threadIdx.x]; }
    }
    float alpha = coeff[b * 4 + 3];
    out[b * 512 + chunk * 64 + threadIdx.x] = (1.f - alpha) * (S * (1.f / 64.f)) + alpha * B;
  }
}

// ---------------------------------------------------------------------------
extern "C" void kernel_launch(void* const* d_in, const int* in_sizes, int n_in,
                              void* d_out, int out_size, void* d_ws, size_t ws_size,
                              hipStream_t stream) {
  const float* x   = (const float*)d_in[0];
  const float* W1  = (const float*)d_in[1];
  const float* W2  = (const float*)d_in[2];
  const float* W3  = (const float*)d_in[3];
  const float* sW1 = (const float*)d_in[4];
  const float* sb1 = (const float*)d_in[5];
  const float* sW2 = (const float*)d_in[6];
  const float* sb2 = (const float*)d_in[7];
  const float* sW3 = (const float*)d_in[8];
  const float* sb3 = (const float*)d_in[9];
  float* out = (float*)d_out;                   // 16*512 outputs + 16*16 sigma

  char* w = (char*)d_ws;
  float* XT = (float*)w;                       w += 65536;     // 1024x16 f32
  unsigned short* W2h = (unsigned short*)w;    w += 16777216;  // 8192x1024 bf16 swz
  unsigned short* W2l = (unsigned short*)w;    w += 16777216;
  unsigned short* W3h = (unsigned short*)w;    w += 8388608;   // 4096x1024 bf16 swz
  unsigned short* W3l = (unsigned short*)w;    w += 8388608;
  unsigned short* X2th = (unsigned short*)w;   w += 262144;    // 128x1024 bf16 swz
  unsigned short* X2tl = (unsigned short*)w;   w += 262144;
  unsigned short* X3th = (unsigned short*)w;   w += 2097152;   // 1024x1024 bf16 swz
  unsigned short* X3tl = (unsigned short*)w;   w += 2097152;
  float* Yt    = (float*)w;                    w += 16777216;  // 1024x4096 f32 (transposed)
  float* Pp    = (float*)w;                    w += 16777216;  // 4x128x8192 f32 (L2 partials)
  float* Xp    = (float*)w;                    w += 2097152;   // 4x16x8192 f32 (L1 partials)
  float* coeff = (float*)w;                    w += 256;
  float* Qp1   = (float*)w;                    w += 131072;    // 4x8x1024 f32
  float* Qp2   = (float*)w;                    w += 131072;
  float* Qpc   = (float*)w;                    w += 131072;
  int*   sel   = (int*)w;                      w += 4096;
  float* h1    = (float*)w;                    w += 4096;

  sigma_stage1<<<256, 256, 0, stream>>>(x, sW1, sb1, h1, XT);
  sigma_stage2<<<1, 512, 0, stream>>>(h1, sW2, sb2, sW3, sb3, out + 8192, coeff);

  // One-shot weight split+swizzle (both weights, one launch)
  split_swizzle2<<<6144, 256, 0, stream>>>(W2, W2h, W2l, W3, W3h, W3l);

  // L1: split-K f32 GEMM (256 blocks) + reduce/tanh/split/swizzle
  gemm_l1a<<<256, 256, 0, stream>>>(W1, XT, Xp);
  gemm_l1red<<<128, 256, 0, stream>>>(Xp, X2th, X2tl);

  // L2: LDS-dbuf MFMA 128x64, split-K 4 (512 blocks, 2/CU) + reducer
  mfma_l2<<<512, 256, 0, stream>>>(W2h, W2l, X2th, X2tl, Pp);
  gemm_l2red<<<1024, 256, 0, stream>>>(Pp, X3th, X3tl);

  // L3: LDS-dbuf MFMA 128x64, full K (512 blocks, 2/CU), writes Yt + stats
  mfma_l3<<<512, 256, 0, stream>>>(
      W3h, W3l, X3th, X3tl, Yt, Qp1, Qp2, Qpc);

  select64<<<16, 256, 0, stream>>>(Qp1, Qp2, Qpc, coeff, sel);
  collapse2<<<128, 256, 0, stream>>>(Yt, sel, coeff, out);
}